// Round 2
// baseline (26322.058 us; speedup 1.0000x reference)
//
#include <hip/hip_runtime.h>

#define NEG_SLOPE 0.2f

constexpr int N_NODES = 20000;
constexpr int NE      = 320000;
constexpr int H       = 8;
constexpr int D       = 32;
constexpr int HD      = 256;   // H*D
constexpr int FIN     = 256;

// ---- sortable-uint encoding for float atomic max ----
__device__ __forceinline__ unsigned encf(float f) {
    unsigned u = __float_as_uint(f);
    return (u & 0x80000000u) ? ~u : (u | 0x80000000u);
}
__device__ __forceinline__ float decf(unsigned u) {
    return (u & 0x80000000u) ? __uint_as_float(u ^ 0x80000000u)
                             : __uint_as_float(~u);
}
#define ENC_NEG_INF 0x007FFFFFu   // encf(-inf)

// ---- C[M,256] = X[M,256] @ W[256,256], fp32 ----
__global__ __launch_bounds__(256) void gemm_k256(
    const float* __restrict__ X, const float* __restrict__ W,
    float* __restrict__ C, int M)
{
    __shared__ float xs[16][256];
    int row0 = blockIdx.x * 16;
    for (int idx = threadIdx.x; idx < 16 * 256; idx += 256) {
        int r = idx >> 8, k = idx & 255;
        int row = row0 + r;
        xs[r][k] = (row < M) ? X[row * FIN + k] : 0.f;
    }
    __syncthreads();
    int col = threadIdx.x;
    float acc[16];
#pragma unroll
    for (int r = 0; r < 16; r++) acc[r] = 0.f;
#pragma unroll 4
    for (int k = 0; k < 256; k++) {
        float w = W[k * 256 + col];
#pragma unroll
        for (int r = 0; r < 16; r++) acc[r] = fmaf(xs[r][k], w, acc[r]);
    }
#pragma unroll
    for (int r = 0; r < 16; r++) {
        int row = row0 + r;
        if (row < M) C[row * 256 + col] = acc[r];
    }
}

// ---- C[M,256] = X[M,32] @ W[32,256], fp32 ----
__global__ __launch_bounds__(256) void gemm_k32(
    const float* __restrict__ X, const float* __restrict__ W,
    float* __restrict__ C, int M)
{
    __shared__ float xs[16][32];
    int row0 = blockIdx.x * 16;
    for (int idx = threadIdx.x; idx < 16 * 32; idx += 256) {
        int r = idx >> 5, k = idx & 31;
        int row = row0 + r;
        xs[r][k] = (row < M) ? X[row * 32 + k] : 0.f;
    }
    __syncthreads();
    int col = threadIdx.x;
    float acc[16];
#pragma unroll
    for (int r = 0; r < 16; r++) acc[r] = 0.f;
#pragma unroll
    for (int k = 0; k < 32; k++) {
        float w = W[k * 256 + col];
#pragma unroll
        for (int r = 0; r < 16; r++) acc[r] = fmaf(xs[r][k], w, acc[r]);
    }
#pragma unroll
    for (int r = 0; r < 16; r++) {
        int row = row0 + r;
        if (row < M) C[row * 256 + col] = acc[r];
    }
}

// ---- out[n,h] = sum_d F[n, h*32+d] * avec[h*32+d] ----
__global__ __launch_bounds__(256) void rowdot(
    const float* __restrict__ F, const float* __restrict__ avec,
    float* __restrict__ out, int N)
{
    int t = blockIdx.x * 256 + threadIdx.x;
    if (t >= N * H) return;
    int n = t >> 3, h = t & 7;
    const float4* fp = (const float4*)(F + n * HD + h * D);
    const float4* ap = (const float4*)(avec + h * D);
    float s = 0.f;
#pragma unroll
    for (int i = 0; i < 8; i++) {
        float4 f = fp[i], a = ap[i];
        s += f.x * a.x + f.y * a.y + f.z * a.z + f.w * a.w;
    }
    out[t] = s;
}

__global__ __launch_bounds__(256) void init_ms(
    unsigned* __restrict__ menc, float* __restrict__ s, int n)
{
    int t = blockIdx.x * 256 + threadIdx.x;
    if (t < n) { menc[t] = ENC_NEG_INF; s[t] = 0.f; }
}

// pass 1: e = leakyrelu(el[u]+er[v]); store; segment max over v
__global__ __launch_bounds__(256) void edge_pass1(
    const float* __restrict__ el, const float* __restrict__ er,
    const int* __restrict__ u, const int* __restrict__ v,
    float* __restrict__ ebuf, unsigned* __restrict__ menc, int E)
{
    int t = blockIdx.x * 256 + threadIdx.x;
    if (t >= E * H) return;
    int i = t >> 3, h = t & 7;
    int ui = u[i], vi = v[i];
    float e = el[ui * H + h] + er[vi * H + h];
    e = (e >= 0.f) ? e : NEG_SLOPE * e;
    ebuf[t] = e;
    atomicMax(&menc[vi * H + h], encf(e));
}

// pass 2: ex = exp(e - m[v]); store; segment sum over v
__global__ __launch_bounds__(256) void edge_pass2(
    float* __restrict__ ebuf, const unsigned* __restrict__ menc,
    const int* __restrict__ v, float* __restrict__ sbuf, int E)
{
    int t = blockIdx.x * 256 + threadIdx.x;
    if (t >= E * H) return;
    int i = t >> 3, h = t & 7;
    int vi = v[i];
    float m = decf(menc[vi * H + h]);
    float ex = expf(ebuf[t] - m);
    ebuf[t] = ex;
    atomicAdd(&sbuf[vi * H + h], ex);
}

// pass 3: a = ex/s[v]; acc[v,h,:] += a * Fs[u,h,:]
__global__ __launch_bounds__(256) void edge_pass3(
    const float* __restrict__ ebuf, const float* __restrict__ sbuf,
    const int* __restrict__ u, const int* __restrict__ v,
    const float* __restrict__ Fs, float* __restrict__ acc, int E)
{
    int t = blockIdx.x * 256 + threadIdx.x;
    if (t >= E * H) return;
    int i = t >> 3, h = t & 7;
    int ui = u[i], vi = v[i];
    float a = ebuf[t] / sbuf[vi * H + h];
    const float4* f = (const float4*)(Fs + ui * HD + h * D);
    float* o = acc + vi * HD + h * D;
#pragma unroll
    for (int j = 0; j < 8; j++) {
        float4 fv = f[j];
        atomicAdd(o + 4 * j + 0, a * fv.x);
        atomicAdd(o + 4 * j + 1, a * fv.y);
        atomicAdd(o + 4 * j + 2, a * fv.z);
        atomicAdd(o + 4 * j + 3, a * fv.w);
    }
}

// out[n,d] = (sum_h acc[n,h,d] + sum_h(b0+b1)[h,d]) / 8  (+relu)
template <int RELU>
__global__ __launch_bounds__(256) void combine_mean(
    const float* __restrict__ acc, const float* __restrict__ b0,
    const float* __restrict__ b1, float* __restrict__ out, int N)
{
    int t = blockIdx.x * 256 + threadIdx.x;
    if (t >= N * D) return;
    int n = t >> 5, d = t & 31;
    float sum = 0.f;
#pragma unroll
    for (int h = 0; h < H; h++) sum += acc[n * HD + h * D + d];
    float bs = 0.f;
#pragma unroll
    for (int h = 0; h < H; h++) {
        bs += b0[h * D + d];
        if (b1) bs += b1[h * D + d];
    }
    float r = (sum + bs) * 0.125f;
    if (RELU) r = fmaxf(r, 0.f);
    out[t] = r;
}

extern "C" void kernel_launch(void* const* d_in, const int* in_sizes, int n_in,
                              void* d_out, int out_size, void* d_ws, size_t ws_size,
                              hipStream_t stream)
{
    const float* xA  = (const float*)d_in[0];
    const float* xB  = (const float*)d_in[1];
    const float* W1  = (const float*)d_in[2];   // [3][256][256]
    const float* al1 = (const float*)d_in[3];   // [3][256]
    const float* ar1 = (const float*)d_in[4];
    const float* b1  = (const float*)d_in[5];   // [3][256]
    const float* W2  = (const float*)d_in[6];   // [3][32][256]
    const float* al2 = (const float*)d_in[7];
    const float* ar2 = (const float*)d_in[8];
    const float* b2  = (const float*)d_in[9];
    const int* u[3] = { (const int*)d_in[10], (const int*)d_in[12], (const int*)d_in[14] };
    const int* v[3] = { (const int*)d_in[11], (const int*)d_in[13], (const int*)d_in[15] };
    float* out = (float*)d_out;

    // workspace layout (floats)
    float* ws = (float*)d_ws;
    const size_t FSZ = (size_t)N_NODES * HD;        // 5.12M
    float*    Fs   = ws;
    float*    Fd   = Fs + FSZ;
    float*    accA = Fd + FSZ;
    float*    accB = accA + FSZ;
    float*    ebuf = accB + FSZ;                    // NE*H = 2.56M
    float*    el   = ebuf + (size_t)NE * H;
    float*    er   = el + N_NODES * H;
    float*    sbuf = er + N_NODES * H;
    unsigned* menc = (unsigned*)(sbuf + N_NODES * H);
    float*    hA   = (float*)(menc + N_NODES * H);
    float*    hB   = hA + N_NODES * D;

    const int GB_GEMM = N_NODES / 16;       // 1250
    const int GB_ROW  = N_NODES * H / 256;  // 625
    const int GB_EDGE = NE * H / 256;       // 10000
    const int GB_COMB = N_NODES * D / 256;  // 2500

    auto edge_phase = [&](const float* fsrc, const float* fel, const float* fer,
                          int t, float* acc) {
        init_ms<<<GB_ROW, 256, 0, stream>>>(menc, sbuf, N_NODES * H);
        edge_pass1<<<GB_EDGE, 256, 0, stream>>>(fel, fer, u[t], v[t], ebuf, menc, NE);
        edge_pass2<<<GB_EDGE, 256, 0, stream>>>(ebuf, menc, v[t], sbuf, NE);
        edge_pass3<<<GB_EDGE, 256, 0, stream>>>(ebuf, sbuf, u[t], v[t], fsrc, acc, NE);
    };

    // ---------------- layer 1 ----------------
    hipMemsetAsync(accA, 0, FSZ * sizeof(float), stream);
    hipMemsetAsync(accB, 0, FSZ * sizeof(float), stream);

    // etype0: A -> B
    gemm_k256<<<GB_GEMM, 256, 0, stream>>>(xA, W1 + 0 * 65536, Fs, N_NODES);
    gemm_k256<<<GB_GEMM, 256, 0, stream>>>(xB, W1 + 0 * 65536, Fd, N_NODES);
    rowdot<<<GB_ROW, 256, 0, stream>>>(Fs, al1 + 0 * 256, el, N_NODES);
    rowdot<<<GB_ROW, 256, 0, stream>>>(Fd, ar1 + 0 * 256, er, N_NODES);
    edge_phase(Fs, el, er, 0, accB);

    // etype1: B -> A
    gemm_k256<<<GB_GEMM, 256, 0, stream>>>(xB, W1 + 1 * 65536, Fs, N_NODES);
    gemm_k256<<<GB_GEMM, 256, 0, stream>>>(xA, W1 + 1 * 65536, Fd, N_NODES);
    rowdot<<<GB_ROW, 256, 0, stream>>>(Fs, al1 + 1 * 256, el, N_NODES);
    rowdot<<<GB_ROW, 256, 0, stream>>>(Fd, ar1 + 1 * 256, er, N_NODES);
    edge_phase(Fs, el, er, 1, accA);

    // etype2: A -> A (fs == fd)
    gemm_k256<<<GB_GEMM, 256, 0, stream>>>(xA, W1 + 2 * 65536, Fs, N_NODES);
    rowdot<<<GB_ROW, 256, 0, stream>>>(Fs, al1 + 2 * 256, el, N_NODES);
    rowdot<<<GB_ROW, 256, 0, stream>>>(Fs, ar1 + 2 * 256, er, N_NODES);
    edge_phase(Fs, el, er, 2, accA);

    // head-mean + bias + relu
    combine_mean<1><<<GB_COMB, 256, 0, stream>>>(accA, b1 + 1 * 256, b1 + 2 * 256, hA, N_NODES);
    combine_mean<1><<<GB_COMB, 256, 0, stream>>>(accB, b1 + 0 * 256, nullptr, hB, N_NODES);

    // ---------------- layer 2 ----------------
    hipMemsetAsync(accA, 0, FSZ * sizeof(float), stream);
    hipMemsetAsync(accB, 0, FSZ * sizeof(float), stream);

    // etype0: A -> B
    gemm_k32<<<GB_GEMM, 256, 0, stream>>>(hA, W2 + 0 * 8192, Fs, N_NODES);
    gemm_k32<<<GB_GEMM, 256, 0, stream>>>(hB, W2 + 0 * 8192, Fd, N_NODES);
    rowdot<<<GB_ROW, 256, 0, stream>>>(Fs, al2 + 0 * 256, el, N_NODES);
    rowdot<<<GB_ROW, 256, 0, stream>>>(Fd, ar2 + 0 * 256, er, N_NODES);
    edge_phase(Fs, el, er, 0, accB);

    // etype1: B -> A
    gemm_k32<<<GB_GEMM, 256, 0, stream>>>(hB, W2 + 1 * 8192, Fs, N_NODES);
    gemm_k32<<<GB_GEMM, 256, 0, stream>>>(hA, W2 + 1 * 8192, Fd, N_NODES);
    rowdot<<<GB_ROW, 256, 0, stream>>>(Fs, al2 + 1 * 256, el, N_NODES);
    rowdot<<<GB_ROW, 256, 0, stream>>>(Fd, ar2 + 1 * 256, er, N_NODES);
    edge_phase(Fs, el, er, 1, accA);

    // etype2: A -> A
    gemm_k32<<<GB_GEMM, 256, 0, stream>>>(hA, W2 + 2 * 8192, Fs, N_NODES);
    rowdot<<<GB_ROW, 256, 0, stream>>>(Fs, al2 + 2 * 256, el, N_NODES);
    rowdot<<<GB_ROW, 256, 0, stream>>>(Fs, ar2 + 2 * 256, er, N_NODES);
    edge_phase(Fs, el, er, 2, accA);

    // final: mean over heads + bias, no relu; stack [oA, oB]
    combine_mean<0><<<GB_COMB, 256, 0, stream>>>(accA, b2 + 1 * 256, b2 + 2 * 256, out, N_NODES);
    combine_mean<0><<<GB_COMB, 256, 0, stream>>>(accB, b2 + 0 * 256, nullptr, out + N_NODES * D, N_NODES);
}

// Round 3
// 2012.435 us; speedup vs baseline: 13.0797x; 13.0797x over previous
//
#include <hip/hip_runtime.h>

#define NEG_SLOPE 0.2f

constexpr int N_NODES = 20000;
constexpr int NE      = 320000;
constexpr int H       = 8;
constexpr int D       = 32;
constexpr int HD      = 256;   // H*D
constexpr int FIN     = 256;

// ================= feature GEMMs =================

// ---- C[M,256] = X[M,256] @ W[256,256], fp32 ----
__global__ __launch_bounds__(256) void gemm_k256(
    const float* __restrict__ X, const float* __restrict__ W,
    float* __restrict__ C, int M)
{
    __shared__ float xs[16][256];
    int row0 = blockIdx.x * 16;
    for (int idx = threadIdx.x; idx < 16 * 256; idx += 256) {
        int r = idx >> 8, k = idx & 255;
        int row = row0 + r;
        xs[r][k] = (row < M) ? X[row * FIN + k] : 0.f;
    }
    __syncthreads();
    int col = threadIdx.x;
    float acc[16];
#pragma unroll
    for (int r = 0; r < 16; r++) acc[r] = 0.f;
#pragma unroll 4
    for (int k = 0; k < 256; k++) {
        float w = W[k * 256 + col];
#pragma unroll
        for (int r = 0; r < 16; r++) acc[r] = fmaf(xs[r][k], w, acc[r]);
    }
#pragma unroll
    for (int r = 0; r < 16; r++) {
        int row = row0 + r;
        if (row < M) C[row * 256 + col] = acc[r];
    }
}

// ---- C[M,256] = X[M,32] @ W[32,256], fp32 ----
__global__ __launch_bounds__(256) void gemm_k32(
    const float* __restrict__ X, const float* __restrict__ W,
    float* __restrict__ C, int M)
{
    __shared__ float xs[16][32];
    int row0 = blockIdx.x * 16;
    for (int idx = threadIdx.x; idx < 16 * 32; idx += 256) {
        int r = idx >> 5, k = idx & 31;
        int row = row0 + r;
        xs[r][k] = (row < M) ? X[row * 32 + k] : 0.f;
    }
    __syncthreads();
    int col = threadIdx.x;
    float acc[16];
#pragma unroll
    for (int r = 0; r < 16; r++) acc[r] = 0.f;
#pragma unroll
    for (int k = 0; k < 32; k++) {
        float w = W[k * 256 + col];
#pragma unroll
        for (int r = 0; r < 16; r++) acc[r] = fmaf(xs[r][k], w, acc[r]);
    }
#pragma unroll
    for (int r = 0; r < 16; r++) {
        int row = row0 + r;
        if (row < M) C[row * 256 + col] = acc[r];
    }
}

// ---- el[n,h] = sum_d F[n, h*32+d] * avec[h*32+d] ----
__global__ __launch_bounds__(256) void rowdot(
    const float* __restrict__ F, const float* __restrict__ avec,
    float* __restrict__ out, int N)
{
    int t = blockIdx.x * 256 + threadIdx.x;
    if (t >= N * H) return;
    int n = t >> 3, h = t & 7;
    const float4* fp = (const float4*)(F + (size_t)n * HD + h * D);
    const float4* ap = (const float4*)(avec + h * D);
    float s = 0.f;
#pragma unroll
    for (int i = 0; i < 8; i++) {
        float4 f = fp[i], a = ap[i];
        s += f.x * a.x + f.y * a.y + f.z * a.z + f.w * a.w;
    }
    out[t] = s;
}

// ---- wr[k,h] = sum_d W[k, h*32+d] * ar[h,d] ----
__global__ void make_wr(const float* __restrict__ W, const float* __restrict__ ar,
                        float* __restrict__ wr, int K)
{
    int t = blockIdx.x * blockDim.x + threadIdx.x;
    if (t >= K * H) return;
    int k = t / H, h = t % H;
    float s = 0.f;
#pragma unroll
    for (int d = 0; d < D; d++) s += W[k * HD + h * D + d] * ar[h * D + d];
    wr[t] = s;
}

// ---- er[n,h] = sum_k x[n,k] * wr[k,h]  (skinny GEMV) ----
template <int K>
__global__ __launch_bounds__(256) void gemv_er(
    const float* __restrict__ x, const float* __restrict__ wr,
    float* __restrict__ er, int N)
{
    __shared__ float w[K * H];
    for (int i = threadIdx.x; i < K * H; i += 256) w[i] = wr[i];
    __syncthreads();
    int t = blockIdx.x * 256 + threadIdx.x;
    if (t >= N * H) return;
    int n = t >> 3, h = t & 7;
    const float4* xp = (const float4*)(x + (size_t)n * K);
    float s = 0.f;
#pragma unroll 4
    for (int k4 = 0; k4 < K / 4; k4++) {
        float4 xv = xp[k4];
        s += xv.x * w[(4 * k4 + 0) * H + h];
        s += xv.y * w[(4 * k4 + 1) * H + h];
        s += xv.z * w[(4 * k4 + 2) * H + h];
        s += xv.w * w[(4 * k4 + 3) * H + h];
    }
    er[t] = s;
}

// ================= CSR build =================

__global__ void zero_ints(int* __restrict__ p, int n)
{
    int t = blockIdx.x * blockDim.x + threadIdx.x;
    if (t < n) p[t] = 0;
}

__global__ void hist_v(const int* __restrict__ v, int* __restrict__ cnt, int E)
{
    int t = blockIdx.x * blockDim.x + threadIdx.x;
    if (t < E) atomicAdd(&cnt[v[t]], 1);
}

__global__ __launch_bounds__(1024) void scan_off(
    const int* __restrict__ cnt, int* __restrict__ off,
    int* __restrict__ cursor, int N, int E)
{
    __shared__ int part[1024];
    int t = threadIdx.x;
    const int CH = 20;  // 1024*20 >= 20000
    int lo = t * CH, hi = min(lo + CH, N);
    int s = 0;
    for (int i = lo; i < hi; i++) s += cnt[i];
    part[t] = s;
    __syncthreads();
    if (t == 0) {
        int run = 0;
        for (int i = 0; i < 1024; i++) { int x = part[i]; part[i] = run; run += x; }
    }
    __syncthreads();
    int run = part[t];
    for (int i = lo; i < hi; i++) {
        off[i] = run; cursor[i] = run; run += cnt[i];
    }
    if (t == 0) off[N] = E;
}

__global__ void fill_eids(const int* __restrict__ v, int* __restrict__ cursor,
                          int* __restrict__ eids, int E)
{
    int t = blockIdx.x * blockDim.x + threadIdx.x;
    if (t >= E) return;
    int pos = atomicAdd(&cursor[v[t]], 1);
    eids[pos] = t;
}

// ================= edge softmax (gather form) =================

// ebuf[i,h] = leakyrelu(el[u[i],h] + er[v[i],h])
__global__ __launch_bounds__(256) void edge_logits(
    const float* __restrict__ el, const float* __restrict__ er,
    const int* __restrict__ u, const int* __restrict__ v,
    float* __restrict__ ebuf, int E)
{
    int t = blockIdx.x * 256 + threadIdx.x;
    if (t >= E * H) return;
    int i = t >> 3, h = t & 7;
    float e = el[u[i] * H + h] + er[v[i] * H + h];
    ebuf[t] = (e >= 0.f) ? e : NEG_SLOPE * e;
}

// per (v,h): m = max, s = sum exp(e-m) over segment
__global__ __launch_bounds__(256) void seg_softmax_ms(
    const float* __restrict__ ebuf, const int* __restrict__ off,
    const int* __restrict__ eids, float* __restrict__ mbuf,
    float* __restrict__ sinv, int N)
{
    int t = blockIdx.x * 256 + threadIdx.x;
    if (t >= N * H) return;
    int v = t >> 3, h = t & 7;
    int lo = off[v], hi = off[v + 1];
    if (lo == hi) { mbuf[t] = 0.f; sinv[t] = 0.f; return; }
    float m = -INFINITY;
    for (int j = lo; j < hi; j++) m = fmaxf(m, ebuf[eids[j] * H + h]);
    float s = 0.f;
    for (int j = lo; j < hi; j++) s += expf(ebuf[eids[j] * H + h] - m);
    mbuf[t] = m;
    sinv[t] = 1.f / s;
}

// one 32-lane group per (v,h); lane = d. acc[v,h,d] += sum_j a_j * Fs[u_j,h,d]
__global__ __launch_bounds__(256) void seg_gather(
    const float* __restrict__ ebuf, const float* __restrict__ mbuf,
    const float* __restrict__ sinv, const int* __restrict__ off,
    const int* __restrict__ eids, const int* __restrict__ uarr,
    const float* __restrict__ Fs, float* __restrict__ acc, int N)
{
    int gid = blockIdx.x * 8 + (threadIdx.x >> 5);
    int lane = threadIdx.x & 31;
    if (gid >= N * H) return;
    int v = gid >> 3, h = gid & 7;
    int lo = off[v], hi = off[v + 1];
    if (lo == hi) return;
    float m = mbuf[gid], si = sinv[gid];
    float a_acc = 0.f;
    for (int j = lo; j < hi; j++) {
        int eid = eids[j];
        int ui = uarr[eid];
        float a = expf(ebuf[eid * H + h] - m) * si;
        a_acc += a * Fs[(size_t)ui * HD + h * D + lane];
    }
    acc[(size_t)v * HD + h * D + lane] += a_acc;
}

// ================= combine =================

// out[n,d] = (sum_h acc[n,h,d] + sum_h(b0+b1)[h,d]) / 8  (+relu)
template <int RELU>
__global__ __launch_bounds__(256) void combine_mean(
    const float* __restrict__ acc, const float* __restrict__ b0,
    const float* __restrict__ b1, float* __restrict__ out, int N)
{
    int t = blockIdx.x * 256 + threadIdx.x;
    if (t >= N * D) return;
    int n = t >> 5, d = t & 31;
    float sum = 0.f;
#pragma unroll
    for (int h = 0; h < H; h++) sum += acc[(size_t)n * HD + h * D + d];
    float bs = 0.f;
#pragma unroll
    for (int h = 0; h < H; h++) {
        bs += b0[h * D + d];
        if (b1) bs += b1[h * D + d];
    }
    float r = (sum + bs) * 0.125f;
    if (RELU) r = fmaxf(r, 0.f);
    out[t] = r;
}

// ================= host =================

extern "C" void kernel_launch(void* const* d_in, const int* in_sizes, int n_in,
                              void* d_out, int out_size, void* d_ws, size_t ws_size,
                              hipStream_t stream)
{
    const float* xA  = (const float*)d_in[0];
    const float* xB  = (const float*)d_in[1];
    const float* W1  = (const float*)d_in[2];   // [3][256][256]
    const float* al1 = (const float*)d_in[3];   // [3][256]
    const float* ar1 = (const float*)d_in[4];
    const float* b1  = (const float*)d_in[5];   // [3][256]
    const float* W2  = (const float*)d_in[6];   // [3][32][256]
    const float* al2 = (const float*)d_in[7];
    const float* ar2 = (const float*)d_in[8];
    const float* b2  = (const float*)d_in[9];
    const int* u[3] = { (const int*)d_in[10], (const int*)d_in[12], (const int*)d_in[14] };
    const int* v[3] = { (const int*)d_in[11], (const int*)d_in[13], (const int*)d_in[15] };
    float* out = (float*)d_out;

    // workspace layout
    float* ws = (float*)d_ws;
    const size_t FSZ = (size_t)N_NODES * HD;            // 5.12M floats
    float* Fs   = ws;
    float* accA = Fs + FSZ;
    float* accB = accA + FSZ;
    float* ebuf = accB + FSZ;                           // NE*H
    float* el   = ebuf + (size_t)NE * H;
    float* er   = el + N_NODES * H;
    float* mbuf = er + N_NODES * H;
    float* sinv = mbuf + N_NODES * H;
    float* hA   = sinv + N_NODES * H;
    float* hB   = hA + N_NODES * D;
    float* wr   = hB + N_NODES * D;                     // 2048
    int*   offs   = (int*)(wr + FIN * H);               // 3*(N+1)
    int*   eids   = offs + 3 * (N_NODES + 1);           // 3*NE
    int*   cnt    = eids + 3 * NE;                      // N

    const int GB_GEMM = N_NODES / 16;           // 1250
    const int GB_ROW  = N_NODES * H / 256;      // 625
    const int GB_EH   = NE * H / 256;           // 10000
    const int GB_GATH = N_NODES * H * 32 / 256; // 20000
    const int GB_COMB = N_NODES * D / 256;      // 2500
    const int GB_E    = (NE + 255) / 256;       // 1250
    const int GB_N    = (N_NODES + 255) / 256;

    // ---- CSR build (shared by both layers) ----
    for (int t = 0; t < 3; t++) {
        int* off_t  = offs + t * (N_NODES + 1);
        int* eids_t = eids + t * NE;
        zero_ints<<<GB_N, 256, 0, stream>>>(cnt, N_NODES);
        hist_v<<<GB_E, 256, 0, stream>>>(v[t], cnt, NE);
        // cursor reuses cnt's slot? no — scan writes cursor into cnt after reading? keep separate: reuse ebuf as cursor (int) is messy; use dedicated cursor right after cnt
        scan_off<<<1, 1024, 0, stream>>>(cnt, off_t, (int*)(cnt + N_NODES) - N_NODES + N_NODES, N_NODES, NE); // placeholder, replaced below
    }
    // NOTE: the loop above is unrolled properly below; HIP requires actual cursor storage.
    // (We re-run the build correctly here; the placeholder launches above are harmless
    //  rewrites of the same buffers.)
    int* cursor = cnt + N_NODES;  // N ints, directly after cnt
    for (int t = 0; t < 3; t++) {
        int* off_t  = offs + t * (N_NODES + 1);
        int* eids_t = eids + t * NE;
        zero_ints<<<GB_N, 256, 0, stream>>>(cnt, N_NODES);
        hist_v<<<GB_E, 256, 0, stream>>>(v[t], cnt, NE);
        scan_off<<<1, 1024, 0, stream>>>(cnt, off_t, cursor, N_NODES, NE);
        fill_eids<<<GB_E, 256, 0, stream>>>(v[t], cursor, eids_t, NE);
    }

    auto edge_phase = [&](const float* fsrc, int t, float* acc) {
        int* off_t  = offs + t * (N_NODES + 1);
        int* eids_t = eids + t * NE;
        edge_logits<<<GB_EH, 256, 0, stream>>>(el, er, u[t], v[t], ebuf, NE);
        seg_softmax_ms<<<GB_ROW, 256, 0, stream>>>(ebuf, off_t, eids_t, mbuf, sinv, N_NODES);
        seg_gather<<<GB_GATH, 256, 0, stream>>>(ebuf, mbuf, sinv, off_t, eids_t, u[t], fsrc, acc, N_NODES);
    };

    // ---------------- layer 1 ----------------
    hipMemsetAsync(accA, 0, FSZ * sizeof(float), stream);
    hipMemsetAsync(accB, 0, FSZ * sizeof(float), stream);

    // etype0: A -> B
    gemm_k256<<<GB_GEMM, 256, 0, stream>>>(xA, W1 + 0 * 65536, Fs, N_NODES);
    rowdot<<<GB_ROW, 256, 0, stream>>>(Fs, al1 + 0 * 256, el, N_NODES);
    make_wr<<<8, 256, 0, stream>>>(W1 + 0 * 65536, ar1 + 0 * 256, wr, FIN);
    gemv_er<FIN><<<GB_ROW, 256, 0, stream>>>(xB, wr, er, N_NODES);
    edge_phase(Fs, 0, accB);

    // etype1: B -> A
    gemm_k256<<<GB_GEMM, 256, 0, stream>>>(xB, W1 + 1 * 65536, Fs, N_NODES);
    rowdot<<<GB_ROW, 256, 0, stream>>>(Fs, al1 + 1 * 256, el, N_NODES);
    make_wr<<<8, 256, 0, stream>>>(W1 + 1 * 65536, ar1 + 1 * 256, wr, FIN);
    gemv_er<FIN><<<GB_ROW, 256, 0, stream>>>(xA, wr, er, N_NODES);
    edge_phase(Fs, 1, accA);

    // etype2: A -> A
    gemm_k256<<<GB_GEMM, 256, 0, stream>>>(xA, W1 + 2 * 65536, Fs, N_NODES);
    rowdot<<<GB_ROW, 256, 0, stream>>>(Fs, al1 + 2 * 256, el, N_NODES);
    make_wr<<<8, 256, 0, stream>>>(W1 + 2 * 65536, ar1 + 2 * 256, wr, FIN);
    gemv_er<FIN><<<GB_ROW, 256, 0, stream>>>(xA, wr, er, N_NODES);
    edge_phase(Fs, 2, accA);

    // head-mean + bias + relu
    combine_mean<1><<<GB_COMB, 256, 0, stream>>>(accA, b1 + 1 * 256, b1 + 2 * 256, hA, N_NODES);
    combine_mean<1><<<GB_COMB, 256, 0, stream>>>(accB, b1 + 0 * 256, nullptr, hB, N_NODES);

    // ---------------- layer 2 ----------------
    hipMemsetAsync(accA, 0, FSZ * sizeof(float), stream);
    hipMemsetAsync(accB, 0, FSZ * sizeof(float), stream);

    // etype0: A -> B
    gemm_k32<<<GB_GEMM, 256, 0, stream>>>(hA, W2 + 0 * 8192, Fs, N_NODES);
    rowdot<<<GB_ROW, 256, 0, stream>>>(Fs, al2 + 0 * 256, el, N_NODES);
    make_wr<<<1, 256, 0, stream>>>(W2 + 0 * 8192, ar2 + 0 * 256, wr, 32);
    gemv_er<32><<<GB_ROW, 256, 0, stream>>>(hB, wr, er, N_NODES);
    edge_phase(Fs, 0, accB);

    // etype1: B -> A
    gemm_k32<<<GB_GEMM, 256, 0, stream>>>(hB, W2 + 1 * 8192, Fs, N_NODES);
    rowdot<<<GB_ROW, 256, 0, stream>>>(Fs, al2 + 1 * 256, el, N_NODES);
    make_wr<<<1, 256, 0, stream>>>(W2 + 1 * 8192, ar2 + 1 * 256, wr, 32);
    gemv_er<32><<<GB_ROW, 256, 0, stream>>>(hA, wr, er, N_NODES);
    edge_phase(Fs, 1, accA);

    // etype2: A -> A
    gemm_k32<<<GB_GEMM, 256, 0, stream>>>(hA, W2 + 2 * 8192, Fs, N_NODES);
    rowdot<<<GB_ROW, 256, 0, stream>>>(Fs, al2 + 2 * 256, el, N_NODES);
    make_wr<<<1, 256, 0, stream>>>(W2 + 2 * 8192, ar2 + 2 * 256, wr, 32);
    gemv_er<32><<<GB_ROW, 256, 0, stream>>>(hA, wr, er, N_NODES);
    edge_phase(Fs, 2, accA);

    // final: mean over heads + bias, no relu; stack [oA, oB]
    combine_mean<0><<<GB_COMB, 256, 0, stream>>>(accA, b2 + 1 * 256, b2 + 2 * 256, out, N_NODES);
    combine_mean<0><<<GB_COMB, 256, 0, stream>>>(accB, b2 + 0 * 256, nullptr, out + (size_t)N_NODES * D, N_NODES);
}

// Round 4
// 1006.517 us; speedup vs baseline: 26.1516x; 1.9994x over previous
//
#include <hip/hip_runtime.h>
#include <float.h>

#define NEG_SLOPE 0.2f

constexpr int N_NODES = 20000;
constexpr int NE      = 320000;
constexpr int H       = 8;
constexpr int D       = 32;
constexpr int HD      = 256;   // H*D
constexpr int FIN     = 256;

// ================= feature GEMMs =================

// ---- C[M,256] = X[M,256] @ W[256,256], fp32 ----
__global__ __launch_bounds__(256) void gemm_k256(
    const float* __restrict__ X, const float* __restrict__ W,
    float* __restrict__ C, int M)
{
    __shared__ float xs[16][256];
    int row0 = blockIdx.x * 16;
    for (int idx = threadIdx.x; idx < 16 * 256; idx += 256) {
        int r = idx >> 8, k = idx & 255;
        int row = row0 + r;
        xs[r][k] = (row < M) ? X[row * FIN + k] : 0.f;
    }
    __syncthreads();
    int col = threadIdx.x;
    float acc[16];
#pragma unroll
    for (int r = 0; r < 16; r++) acc[r] = 0.f;
#pragma unroll 4
    for (int k = 0; k < 256; k++) {
        float w = W[k * 256 + col];
#pragma unroll
        for (int r = 0; r < 16; r++) acc[r] = fmaf(xs[r][k], w, acc[r]);
    }
#pragma unroll
    for (int r = 0; r < 16; r++) {
        int row = row0 + r;
        if (row < M) C[row * 256 + col] = acc[r];
    }
}

// ---- C[M,256] = X[M,32] @ W[32,256], fp32 ----
__global__ __launch_bounds__(256) void gemm_k32(
    const float* __restrict__ X, const float* __restrict__ W,
    float* __restrict__ C, int M)
{
    __shared__ float xs[16][32];
    int row0 = blockIdx.x * 16;
    for (int idx = threadIdx.x; idx < 16 * 32; idx += 256) {
        int r = idx >> 5, k = idx & 31;
        int row = row0 + r;
        xs[r][k] = (row < M) ? X[row * 32 + k] : 0.f;
    }
    __syncthreads();
    int col = threadIdx.x;
    float acc[16];
#pragma unroll
    for (int r = 0; r < 16; r++) acc[r] = 0.f;
#pragma unroll
    for (int k = 0; k < 32; k++) {
        float w = W[k * 256 + col];
#pragma unroll
        for (int r = 0; r < 16; r++) acc[r] = fmaf(xs[r][k], w, acc[r]);
    }
#pragma unroll
    for (int r = 0; r < 16; r++) {
        int row = row0 + r;
        if (row < M) C[row * 256 + col] = acc[r];
    }
}

// ---- el[n,h] = sum_d F[n, h*32+d] * avec[h*32+d] ----
__global__ __launch_bounds__(256) void rowdot(
    const float* __restrict__ F, const float* __restrict__ avec,
    float* __restrict__ out, int N)
{
    int t = blockIdx.x * 256 + threadIdx.x;
    if (t >= N * H) return;
    int n = t >> 3, h = t & 7;
    const float4* fp = (const float4*)(F + (size_t)n * HD + h * D);
    const float4* ap = (const float4*)(avec + h * D);
    float s = 0.f;
#pragma unroll
    for (int i = 0; i < 8; i++) {
        float4 f = fp[i], a = ap[i];
        s += f.x * a.x + f.y * a.y + f.z * a.z + f.w * a.w;
    }
    out[t] = s;
}

// ---- wr[k,h] = sum_d W[k, h*32+d] * ar[h,d] ----
__global__ void make_wr(const float* __restrict__ W, const float* __restrict__ ar,
                        float* __restrict__ wr, int K)
{
    int t = blockIdx.x * blockDim.x + threadIdx.x;
    if (t >= K * H) return;
    int k = t / H, h = t % H;
    float s = 0.f;
#pragma unroll
    for (int d = 0; d < D; d++) s += W[k * HD + h * D + d] * ar[h * D + d];
    wr[t] = s;
}

// ---- er[n,h] = sum_k x[n,k] * wr[k,h]  (skinny GEMV) ----
template <int K>
__global__ __launch_bounds__(256) void gemv_er(
    const float* __restrict__ x, const float* __restrict__ wr,
    float* __restrict__ er, int N)
{
    __shared__ float w[K * H];
    for (int i = threadIdx.x; i < K * H; i += 256) w[i] = wr[i];
    __syncthreads();
    int t = blockIdx.x * 256 + threadIdx.x;
    if (t >= N * H) return;
    int n = t >> 3, h = t & 7;
    const float4* xp = (const float4*)(x + (size_t)n * K);
    float s = 0.f;
#pragma unroll 4
    for (int k4 = 0; k4 < K / 4; k4++) {
        float4 xv = xp[k4];
        s += xv.x * w[(4 * k4 + 0) * H + h];
        s += xv.y * w[(4 * k4 + 1) * H + h];
        s += xv.z * w[(4 * k4 + 2) * H + h];
        s += xv.w * w[(4 * k4 + 3) * H + h];
    }
    er[t] = s;
}

// ================= CSR build =================

__global__ void zero_ints(int* __restrict__ p, int n)
{
    int t = blockIdx.x * blockDim.x + threadIdx.x;
    if (t < n) p[t] = 0;
}

__global__ void hist_v(const int* __restrict__ v, int* __restrict__ cnt, int E)
{
    int t = blockIdx.x * blockDim.x + threadIdx.x;
    if (t < E) atomicAdd(&cnt[v[t]], 1);
}

__global__ __launch_bounds__(1024) void scan_off(
    const int* __restrict__ cnt, int* __restrict__ off,
    int* __restrict__ cursor, int N, int E)
{
    __shared__ int part[1024];
    int t = threadIdx.x;
    const int CH = 20;  // 1024*20 >= 20000
    int lo = t * CH, hi = min(lo + CH, N);
    int s = 0;
    for (int i = lo; i < hi; i++) s += cnt[i];
    part[t] = s;
    __syncthreads();
    if (t == 0) {
        int run = 0;
        for (int i = 0; i < 1024; i++) { int x = part[i]; part[i] = run; run += x; }
    }
    __syncthreads();
    int run = part[t];
    for (int i = lo; i < hi; i++) {
        off[i] = run; cursor[i] = run; run += cnt[i];
    }
    if (t == 0) off[N] = E;
}

// usort[pos] = u[edge], sorted by dst v
__global__ void fill_usort(const int* __restrict__ u, const int* __restrict__ v,
                           int* __restrict__ cursor, int* __restrict__ usort, int E)
{
    int t = blockIdx.x * blockDim.x + threadIdx.x;
    if (t >= E) return;
    int pos = atomicAdd(&cursor[v[t]], 1);
    usort[pos] = u[t];
}

// ================= edge softmax (fused logits, online m/s) =================
// one 64-lane wave per dst node v; lane = e8*8 + h (8 edges x 8 heads per step)
__global__ __launch_bounds__(256) void seg_ms(
    const float* __restrict__ el, const float* __restrict__ er,
    const int* __restrict__ off, const int* __restrict__ usort,
    float* __restrict__ mbuf, float* __restrict__ sinv, int N)
{
    int wid = blockIdx.x * 4 + (threadIdx.x >> 6);
    if (wid >= N) return;
    int lane = threadIdx.x & 63;
    int e8 = lane >> 3, h = lane & 7;
    int v = wid;
    int lo = off[v], hi = off[v + 1];
    float er_vh = er[v * H + h];
    float m = -FLT_MAX, s = 0.f;
    for (int j = lo + e8; j < hi; j += 8) {
        int u = usort[j];
        float e = el[u * H + h] + er_vh;
        e = (e >= 0.f) ? e : NEG_SLOPE * e;
        float nm = fmaxf(m, e);
        s = s * __expf(m - nm) + __expf(e - nm);
        m = nm;
    }
    // butterfly merge across the 8 e8-groups (same h: lanes h, h+8, ..., h+56)
#pragma unroll
    for (int mask = 8; mask <= 32; mask <<= 1) {
        float om = __shfl_xor(m, mask, 64);
        float os = __shfl_xor(s, mask, 64);
        float M = fmaxf(m, om);
        s = s * __expf(m - M) + os * __expf(om - M);
        m = M;
    }
    if (lane < 8) {
        mbuf[v * H + lane] = (m == -FLT_MAX) ? 0.f : m;
        sinv[v * H + lane] = (s > 0.f) ? 1.f / s : 0.f;
    }
}

// ================= weighted gather =================
// one 64-lane wave per dst node v, all 8 heads; lane covers float4 of the 256-wide row
template <int WRITE>
__global__ __launch_bounds__(256) void seg_gather(
    const float* __restrict__ el, const float* __restrict__ er,
    const float* __restrict__ mbuf, const float* __restrict__ sinv,
    const int* __restrict__ off, const int* __restrict__ usort,
    const float* __restrict__ Fs, float* __restrict__ acc, int N)
{
    int wid = blockIdx.x * 4 + (threadIdx.x >> 6);
    if (wid >= N) return;
    int lane = threadIdx.x & 63;
    int h = lane >> 3;
    int v = wid;
    int lo = off[v], hi = off[v + 1];
    float4 a_acc = make_float4(0.f, 0.f, 0.f, 0.f);
    if (lo < hi) {
        float m = mbuf[v * H + h];
        float si = sinv[v * H + h];
        float er_vh = er[v * H + h];
        int u_cur = usort[lo];
        for (int j = lo; j < hi; j++) {
            int u_nxt = (j + 1 < hi) ? usort[j + 1] : 0;
            float4 f = *(const float4*)(Fs + (size_t)u_cur * HD + lane * 4);
            float e = el[u_cur * H + h] + er_vh;
            e = (e >= 0.f) ? e : NEG_SLOPE * e;
            float a = __expf(e - m) * si;
            a_acc.x = fmaf(a, f.x, a_acc.x);
            a_acc.y = fmaf(a, f.y, a_acc.y);
            a_acc.z = fmaf(a, f.z, a_acc.z);
            a_acc.w = fmaf(a, f.w, a_acc.w);
            u_cur = u_nxt;
        }
    }
    float* o = acc + (size_t)v * HD + lane * 4;
    if (WRITE) {
        *(float4*)o = a_acc;
    } else if (lo < hi) {
        float4 p = *(const float4*)o;
        p.x += a_acc.x; p.y += a_acc.y; p.z += a_acc.z; p.w += a_acc.w;
        *(float4*)o = p;
    }
}

// ================= combine =================

// out[n,d] = (sum_h acc[n,h,d] + sum_h(b0+b1)[h,d]) / 8  (+relu)
template <int RELU>
__global__ __launch_bounds__(256) void combine_mean(
    const float* __restrict__ acc, const float* __restrict__ b0,
    const float* __restrict__ b1, float* __restrict__ out, int N)
{
    int t = blockIdx.x * 256 + threadIdx.x;
    if (t >= N * D) return;
    int n = t >> 5, d = t & 31;
    float sum = 0.f;
#pragma unroll
    for (int h = 0; h < H; h++) sum += acc[(size_t)n * HD + h * D + d];
    float bs = 0.f;
#pragma unroll
    for (int h = 0; h < H; h++) {
        bs += b0[h * D + d];
        if (b1) bs += b1[h * D + d];
    }
    float r = (sum + bs) * 0.125f;
    if (RELU) r = fmaxf(r, 0.f);
    out[t] = r;
}

// ================= host =================

extern "C" void kernel_launch(void* const* d_in, const int* in_sizes, int n_in,
                              void* d_out, int out_size, void* d_ws, size_t ws_size,
                              hipStream_t stream)
{
    const float* xA  = (const float*)d_in[0];
    const float* xB  = (const float*)d_in[1];
    const float* W1  = (const float*)d_in[2];   // [3][256][256]
    const float* al1 = (const float*)d_in[3];   // [3][256]
    const float* ar1 = (const float*)d_in[4];
    const float* b1  = (const float*)d_in[5];   // [3][256]
    const float* W2  = (const float*)d_in[6];   // [3][32][256]
    const float* al2 = (const float*)d_in[7];
    const float* ar2 = (const float*)d_in[8];
    const float* b2  = (const float*)d_in[9];
    const int* u[3] = { (const int*)d_in[10], (const int*)d_in[12], (const int*)d_in[14] };
    const int* v[3] = { (const int*)d_in[11], (const int*)d_in[13], (const int*)d_in[15] };
    float* out = (float*)d_out;

    // workspace layout
    float* ws = (float*)d_ws;
    const size_t FSZ = (size_t)N_NODES * HD;            // 5.12M floats
    float* Fs   = ws;
    float* accA = Fs + FSZ;
    float* accB = accA + FSZ;
    float* el   = accB + FSZ;
    float* er   = el + N_NODES * H;
    float* mbuf = er + N_NODES * H;
    float* sinv = mbuf + N_NODES * H;
    float* hA   = sinv + N_NODES * H;
    float* hB   = hA + N_NODES * D;
    float* wr   = hB + N_NODES * D;                     // 2048
    int*   offs   = (int*)(wr + FIN * H);               // 3*(N+1)
    int*   usort  = offs + 3 * (N_NODES + 1);           // 3*NE
    int*   cnt    = usort + 3 * NE;                     // N
    int*   cursor = cnt + N_NODES;                      // N

    const int GB_GEMM = N_NODES / 16;             // 1250
    const int GB_ROW  = N_NODES * H / 256;        // 625
    const int GB_WAVE = (N_NODES + 3) / 4;        // 5000 (4 waves/block)
    const int GB_COMB = N_NODES * D / 256;        // 2500
    const int GB_E    = (NE + 255) / 256;         // 1250
    const int GB_N    = (N_NODES + 255) / 256;

    // ---- CSR build (shared by both layers) ----
    for (int t = 0; t < 3; t++) {
        int* off_t = offs + t * (N_NODES + 1);
        int* us_t  = usort + t * NE;
        zero_ints<<<GB_N, 256, 0, stream>>>(cnt, N_NODES);
        hist_v<<<GB_E, 256, 0, stream>>>(v[t], cnt, NE);
        scan_off<<<1, 1024, 0, stream>>>(cnt, off_t, cursor, N_NODES, NE);
        fill_usort<<<GB_E, 256, 0, stream>>>(u[t], v[t], cursor, us_t, NE);
    }

    auto edge_phase = [&](int t, float* acc, int write_mode) {
        int* off_t = offs + t * (N_NODES + 1);
        int* us_t  = usort + t * NE;
        seg_ms<<<GB_WAVE, 256, 0, stream>>>(el, er, off_t, us_t, mbuf, sinv, N_NODES);
        if (write_mode)
            seg_gather<1><<<GB_WAVE, 256, 0, stream>>>(el, er, mbuf, sinv, off_t, us_t, Fs, acc, N_NODES);
        else
            seg_gather<0><<<GB_WAVE, 256, 0, stream>>>(el, er, mbuf, sinv, off_t, us_t, Fs, acc, N_NODES);
    };

    // ---------------- layer 1 ----------------
    // etype0: A -> B
    gemm_k256<<<GB_GEMM, 256, 0, stream>>>(xA, W1 + 0 * 65536, Fs, N_NODES);
    rowdot<<<GB_ROW, 256, 0, stream>>>(Fs, al1 + 0 * 256, el, N_NODES);
    make_wr<<<8, 256, 0, stream>>>(W1 + 0 * 65536, ar1 + 0 * 256, wr, FIN);
    gemv_er<FIN><<<GB_ROW, 256, 0, stream>>>(xB, wr, er, N_NODES);
    edge_phase(0, accB, 1);

    // etype1: B -> A
    gemm_k256<<<GB_GEMM, 256, 0, stream>>>(xB, W1 + 1 * 65536, Fs, N_NODES);
    rowdot<<<GB_ROW, 256, 0, stream>>>(Fs, al1 + 1 * 256, el, N_NODES);
    make_wr<<<8, 256, 0, stream>>>(W1 + 1 * 65536, ar1 + 1 * 256, wr, FIN);
    gemv_er<FIN><<<GB_ROW, 256, 0, stream>>>(xA, wr, er, N_NODES);
    edge_phase(1, accA, 1);

    // etype2: A -> A
    gemm_k256<<<GB_GEMM, 256, 0, stream>>>(xA, W1 + 2 * 65536, Fs, N_NODES);
    rowdot<<<GB_ROW, 256, 0, stream>>>(Fs, al1 + 2 * 256, el, N_NODES);
    make_wr<<<8, 256, 0, stream>>>(W1 + 2 * 65536, ar1 + 2 * 256, wr, FIN);
    gemv_er<FIN><<<GB_ROW, 256, 0, stream>>>(xA, wr, er, N_NODES);
    edge_phase(2, accA, 0);

    // head-mean + bias + relu
    combine_mean<1><<<GB_COMB, 256, 0, stream>>>(accA, b1 + 1 * 256, b1 + 2 * 256, hA, N_NODES);
    combine_mean<1><<<GB_COMB, 256, 0, stream>>>(accB, b1 + 0 * 256, nullptr, hB, N_NODES);

    // ---------------- layer 2 ----------------
    // etype0: A -> B
    gemm_k32<<<GB_GEMM, 256, 0, stream>>>(hA, W2 + 0 * 8192, Fs, N_NODES);
    rowdot<<<GB_ROW, 256, 0, stream>>>(Fs, al2 + 0 * 256, el, N_NODES);
    make_wr<<<1, 256, 0, stream>>>(W2 + 0 * 8192, ar2 + 0 * 256, wr, 32);
    gemv_er<32><<<GB_ROW, 256, 0, stream>>>(hB, wr, er, N_NODES);
    edge_phase(0, accB, 1);

    // etype1: B -> A
    gemm_k32<<<GB_GEMM, 256, 0, stream>>>(hB, W2 + 1 * 8192, Fs, N_NODES);
    rowdot<<<GB_ROW, 256, 0, stream>>>(Fs, al2 + 1 * 256, el, N_NODES);
    make_wr<<<1, 256, 0, stream>>>(W2 + 1 * 8192, ar2 + 1 * 256, wr, 32);
    gemv_er<32><<<GB_ROW, 256, 0, stream>>>(hA, wr, er, N_NODES);
    edge_phase(1, accA, 1);

    // etype2: A -> A
    gemm_k32<<<GB_GEMM, 256, 0, stream>>>(hA, W2 + 2 * 8192, Fs, N_NODES);
    rowdot<<<GB_ROW, 256, 0, stream>>>(Fs, al2 + 2 * 256, el, N_NODES);
    make_wr<<<1, 256, 0, stream>>>(W2 + 2 * 8192, ar2 + 2 * 256, wr, 32);
    gemv_er<32><<<GB_ROW, 256, 0, stream>>>(hA, wr, er, N_NODES);
    edge_phase(2, accA, 0);

    // final: mean over heads + bias, no relu; stack [oA, oB]
    combine_mean<0><<<GB_COMB, 256, 0, stream>>>(accA, b2 + 1 * 256, b2 + 2 * 256, out, N_NODES);
    combine_mean<0><<<GB_COMB, 256, 0, stream>>>(accB, b2 + 0 * 256, nullptr, out + (size_t)N_NODES * D, N_NODES);
}

// Round 5
// 879.744 us; speedup vs baseline: 29.9201x; 1.1441x over previous
//
#include <hip/hip_runtime.h>
#include <float.h>

#define NEG_SLOPE 0.2f

constexpr int N_NODES = 20000;
constexpr int NE      = 320000;
constexpr int H       = 8;
constexpr int D       = 32;
constexpr int HD      = 256;   // H*D
constexpr int FIN     = 256;

// ================= feature GEMM: C[M,256] = X[M,K] @ W[K,256] =================
// 128x64 tile, 256 threads; thread (tx,ty): cols c0+tx*4, rows r0+ty+16*r (r=0..7)
template <int K, int BK>
__global__ __launch_bounds__(256) void gemm_tile(
    const float* __restrict__ X, const float* __restrict__ W,
    float* __restrict__ C, int M)
{
    constexpr int XS = BK + 8;            // row stride: %4==0 (b128 align), ty-groups 8 banks apart
    __shared__ float Xs[128][XS];
    __shared__ float Ws[BK][64];
    const int tx = threadIdx.x & 15;
    const int ty = threadIdx.x >> 4;
    const int r0 = blockIdx.x * 128;
    const int c0 = blockIdx.y * 64;
    float4 acc[8];
#pragma unroll
    for (int r = 0; r < 8; r++) acc[r] = make_float4(0.f, 0.f, 0.f, 0.f);

    for (int kc = 0; kc < K; kc += BK) {
        for (int idx = threadIdx.x; idx < 128 * (BK / 4); idx += 256) {
            int row = idx / (BK / 4);
            int kq  = idx % (BK / 4);
            int grow = r0 + row;
            float4 xv = (grow < M) ? *(const float4*)(X + (size_t)grow * K + kc + kq * 4)
                                   : make_float4(0.f, 0.f, 0.f, 0.f);
            *(float4*)&Xs[row][kq * 4] = xv;
        }
        for (int idx = threadIdx.x; idx < BK * 16; idx += 256) {
            int k = idx >> 4, cq = idx & 15;
            *(float4*)&Ws[k][cq * 4] = *(const float4*)(W + (size_t)(kc + k) * 256 + c0 + cq * 4);
        }
        __syncthreads();
#pragma unroll 4
        for (int k = 0; k < BK; k++) {
            float4 wv = *(float4*)&Ws[k][tx * 4];
#pragma unroll
            for (int r = 0; r < 8; r++) {
                float x = Xs[ty + 16 * r][k];
                acc[r].x = fmaf(x, wv.x, acc[r].x);
                acc[r].y = fmaf(x, wv.y, acc[r].y);
                acc[r].z = fmaf(x, wv.z, acc[r].z);
                acc[r].w = fmaf(x, wv.w, acc[r].w);
            }
        }
        __syncthreads();
    }
#pragma unroll
    for (int r = 0; r < 8; r++) {
        int row = r0 + ty + 16 * r;
        if (row < M) *(float4*)(C + (size_t)row * 256 + c0 + tx * 4) = acc[r];
    }
}

// ---- el[n,h] = sum_d F[n, h*32+d] * avec[h*32+d] ----
__global__ __launch_bounds__(256) void rowdot(
    const float* __restrict__ F, const float* __restrict__ avec,
    float* __restrict__ out, int N)
{
    int t = blockIdx.x * 256 + threadIdx.x;
    if (t >= N * H) return;
    int n = t >> 3, h = t & 7;
    const float4* fp = (const float4*)(F + (size_t)n * HD + h * D);
    const float4* ap = (const float4*)(avec + h * D);
    float s = 0.f;
#pragma unroll
    for (int i = 0; i < 8; i++) {
        float4 f = fp[i], a = ap[i];
        s += f.x * a.x + f.y * a.y + f.z * a.z + f.w * a.w;
    }
    out[t] = s;
}

// ---- wr[k,h] = sum_d W[k, h*32+d] * ar[h,d] ----
__global__ void make_wr(const float* __restrict__ W, const float* __restrict__ ar,
                        float* __restrict__ wr, int K)
{
    int t = blockIdx.x * blockDim.x + threadIdx.x;
    if (t >= K * H) return;
    int k = t / H, h = t % H;
    float s = 0.f;
#pragma unroll
    for (int d = 0; d < D; d++) s += W[k * HD + h * D + d] * ar[h * D + d];
    wr[t] = s;
}

// ---- er[n,h] = sum_k x[n,k] * wr[k,h]  (skinny GEMV) ----
template <int K>
__global__ __launch_bounds__(256) void gemv_er(
    const float* __restrict__ x, const float* __restrict__ wr,
    float* __restrict__ er, int N)
{
    __shared__ float w[K * H];
    for (int i = threadIdx.x; i < K * H; i += 256) w[i] = wr[i];
    __syncthreads();
    int t = blockIdx.x * 256 + threadIdx.x;
    if (t >= N * H) return;
    int n = t >> 3, h = t & 7;
    const float4* xp = (const float4*)(x + (size_t)n * K);
    float s = 0.f;
#pragma unroll 4
    for (int k4 = 0; k4 < K / 4; k4++) {
        float4 xv = xp[k4];
        s += xv.x * w[(4 * k4 + 0) * H + h];
        s += xv.y * w[(4 * k4 + 1) * H + h];
        s += xv.z * w[(4 * k4 + 2) * H + h];
        s += xv.w * w[(4 * k4 + 3) * H + h];
    }
    er[t] = s;
}

// ================= CSR build =================

__global__ void zero_ints(int* __restrict__ p, int n)
{
    int t = blockIdx.x * blockDim.x + threadIdx.x;
    if (t < n) p[t] = 0;
}

__global__ void hist_v(const int* __restrict__ v, int* __restrict__ cnt, int E)
{
    int t = blockIdx.x * blockDim.x + threadIdx.x;
    if (t < E) atomicAdd(&cnt[v[t]], 1);
}

__global__ __launch_bounds__(1024) void scan_off(
    const int* __restrict__ cnt, int* __restrict__ off,
    int* __restrict__ cursor, int N, int E)
{
    __shared__ int part[1024];
    int t = threadIdx.x;
    const int CH = 20;  // 1024*20 >= 20000
    int lo = t * CH, hi = min(lo + CH, N);
    int s = 0;
    for (int i = lo; i < hi; i++) s += cnt[i];
    part[t] = s;
    __syncthreads();
    if (t == 0) {
        int run = 0;
        for (int i = 0; i < 1024; i++) { int x = part[i]; part[i] = run; run += x; }
    }
    __syncthreads();
    int run = part[t];
    for (int i = lo; i < hi; i++) {
        off[i] = run; cursor[i] = run; run += cnt[i];
    }
    if (t == 0) off[N] = E;
}

// usort[pos] = u[edge], grouped by dst v
__global__ void fill_usort(const int* __restrict__ u, const int* __restrict__ v,
                           int* __restrict__ cursor, int* __restrict__ usort, int E)
{
    int t = blockIdx.x * blockDim.x + threadIdx.x;
    if (t >= E) return;
    int pos = atomicAdd(&cursor[v[t]], 1);
    usort[pos] = u[t];
}

// ================= fused edge softmax + weighted gather =================
// one 64-lane wave per dst node v.
// phase 1 (lane = e8*8 + h): online max/sum of leakyrelu(el[u]+er[v]) over segment
// phase 2 (lane = h*8 + q):  acc[v,h,:] = sum_j softmax_a * Fs[u_j,h,:]
template <int WRITE>
__global__ __launch_bounds__(256) void seg_att(
    const float* __restrict__ el, const float* __restrict__ er,
    const int* __restrict__ off, const int* __restrict__ usort,
    const float* __restrict__ Fs, float* __restrict__ acc, int N)
{
    int wid = blockIdx.x * 4 + (threadIdx.x >> 6);
    if (wid >= N) return;
    const int lane = threadIdx.x & 63;
    const int v = wid;
    const int lo = off[v], hi = off[v + 1];

    // ---- phase 1 ----
    const int h1 = lane & 7, e8 = lane >> 3;
    float er_vh = er[v * H + h1];
    float m = -FLT_MAX, s = 0.f;
    for (int j = lo + e8; j < hi; j += 8) {
        int u = usort[j];
        float e = el[u * H + h1] + er_vh;
        e = (e >= 0.f) ? e : NEG_SLOPE * e;
        float nm = fmaxf(m, e);
        s = s * __expf(m - nm) + __expf(e - nm);
        m = nm;
    }
#pragma unroll
    for (int mask = 8; mask <= 32; mask <<= 1) {
        float om = __shfl_xor(m, mask, 64);
        float os = __shfl_xor(s, mask, 64);
        float M = fmaxf(m, om);
        s = s * __expf(m - M) + os * __expf(om - M);
        m = M;
    }
    float si = (s > 0.f) ? 1.f / s : 0.f;

    // ---- phase 2 ----
    const int h2 = lane >> 3;
    float mh  = __shfl(m, h2, 64);
    float sih = __shfl(si, h2, 64);
    float erh = __shfl(er_vh, h2, 64);
    float4 a_acc = make_float4(0.f, 0.f, 0.f, 0.f);
    if (lo < hi) {
        int u_cur = usort[lo];
        for (int j = lo; j < hi; j++) {
            int u_nxt = (j + 1 < hi) ? usort[j + 1] : 0;
            float4 f = *(const float4*)(Fs + (size_t)u_cur * HD + lane * 4);
            float e = el[u_cur * H + h2] + erh;
            e = (e >= 0.f) ? e : NEG_SLOPE * e;
            float a = __expf(e - mh) * sih;
            a_acc.x = fmaf(a, f.x, a_acc.x);
            a_acc.y = fmaf(a, f.y, a_acc.y);
            a_acc.z = fmaf(a, f.z, a_acc.z);
            a_acc.w = fmaf(a, f.w, a_acc.w);
            u_cur = u_nxt;
        }
    }
    float* o = acc + (size_t)v * HD + lane * 4;
    if (WRITE) {
        *(float4*)o = a_acc;
    } else if (lo < hi) {
        float4 p = *(const float4*)o;
        p.x += a_acc.x; p.y += a_acc.y; p.z += a_acc.z; p.w += a_acc.w;
        *(float4*)o = p;
    }
}

// ================= combine =================

template <int RELU>
__global__ __launch_bounds__(256) void combine_mean(
    const float* __restrict__ acc, const float* __restrict__ b0,
    const float* __restrict__ b1, float* __restrict__ out, int N)
{
    int t = blockIdx.x * 256 + threadIdx.x;
    if (t >= N * D) return;
    int n = t >> 5, d = t & 31;
    float sum = 0.f;
#pragma unroll
    for (int h = 0; h < H; h++) sum += acc[(size_t)n * HD + h * D + d];
    float bs = 0.f;
#pragma unroll
    for (int h = 0; h < H; h++) {
        bs += b0[h * D + d];
        if (b1) bs += b1[h * D + d];
    }
    float r = (sum + bs) * 0.125f;
    if (RELU) r = fmaxf(r, 0.f);
    out[t] = r;
}

// ================= host =================

extern "C" void kernel_launch(void* const* d_in, const int* in_sizes, int n_in,
                              void* d_out, int out_size, void* d_ws, size_t ws_size,
                              hipStream_t stream)
{
    const float* xA  = (const float*)d_in[0];
    const float* xB  = (const float*)d_in[1];
    const float* W1  = (const float*)d_in[2];   // [3][256][256]
    const float* al1 = (const float*)d_in[3];   // [3][256]
    const float* ar1 = (const float*)d_in[4];
    const float* b1  = (const float*)d_in[5];   // [3][256]
    const float* W2  = (const float*)d_in[6];   // [3][32][256]
    const float* al2 = (const float*)d_in[7];
    const float* ar2 = (const float*)d_in[8];
    const float* b2  = (const float*)d_in[9];
    const int* u[3] = { (const int*)d_in[10], (const int*)d_in[12], (const int*)d_in[14] };
    const int* v[3] = { (const int*)d_in[11], (const int*)d_in[13], (const int*)d_in[15] };
    float* out = (float*)d_out;

    // workspace layout
    float* ws = (float*)d_ws;
    const size_t FSZ = (size_t)N_NODES * HD;            // 5.12M floats
    float* Fs   = ws;
    float* accA = Fs + FSZ;
    float* accB = accA + FSZ;
    float* el   = accB + FSZ;
    float* er   = el + N_NODES * H;
    float* hA   = er + N_NODES * H;
    float* hB   = hA + N_NODES * D;
    float* wr   = hB + N_NODES * D;                     // 2048
    int*   offs   = (int*)(wr + FIN * H);               // 3*(N+1)
    int*   usort  = offs + 3 * (N_NODES + 1);           // 3*NE
    int*   cnt    = usort + 3 * NE;                     // N
    int*   cursor = cnt + N_NODES;                      // N

    const dim3 GB_MM(157, 4);                     // ceil(20000/128) x 256/64
    const int GB_ROW  = N_NODES * H / 256;        // 625
    const int GB_WAVE = (N_NODES + 3) / 4;        // 5000 (4 waves/block)
    const int GB_COMB = N_NODES * D / 256;        // 2500
    const int GB_E    = (NE + 255) / 256;         // 1250
    const int GB_N    = (N_NODES + 255) / 256;

    // ---- CSR build (shared by both layers) ----
    for (int t = 0; t < 3; t++) {
        int* off_t = offs + t * (N_NODES + 1);
        int* us_t  = usort + t * NE;
        zero_ints<<<GB_N, 256, 0, stream>>>(cnt, N_NODES);
        hist_v<<<GB_E, 256, 0, stream>>>(v[t], cnt, NE);
        scan_off<<<1, 1024, 0, stream>>>(cnt, off_t, cursor, N_NODES, NE);
        fill_usort<<<GB_E, 256, 0, stream>>>(u[t], v[t], cursor, us_t, NE);
    }

    auto edge_phase = [&](int t, float* acc, int write_mode) {
        int* off_t = offs + t * (N_NODES + 1);
        int* us_t  = usort + t * NE;
        if (write_mode)
            seg_att<1><<<GB_WAVE, 256, 0, stream>>>(el, er, off_t, us_t, Fs, acc, N_NODES);
        else
            seg_att<0><<<GB_WAVE, 256, 0, stream>>>(el, er, off_t, us_t, Fs, acc, N_NODES);
    };

    // ---------------- layer 1 ----------------
    // etype0: A -> B
    gemm_tile<256, 64><<<GB_MM, 256, 0, stream>>>(xA, W1 + 0 * 65536, Fs, N_NODES);
    rowdot<<<GB_ROW, 256, 0, stream>>>(Fs, al1 + 0 * 256, el, N_NODES);
    make_wr<<<8, 256, 0, stream>>>(W1 + 0 * 65536, ar1 + 0 * 256, wr, FIN);
    gemv_er<FIN><<<GB_ROW, 256, 0, stream>>>(xB, wr, er, N_NODES);
    edge_phase(0, accB, 1);

    // etype1: B -> A
    gemm_tile<256, 64><<<GB_MM, 256, 0, stream>>>(xB, W1 + 1 * 65536, Fs, N_NODES);
    rowdot<<<GB_ROW, 256, 0, stream>>>(Fs, al1 + 1 * 256, el, N_NODES);
    make_wr<<<8, 256, 0, stream>>>(W1 + 1 * 65536, ar1 + 1 * 256, wr, FIN);
    gemv_er<FIN><<<GB_ROW, 256, 0, stream>>>(xA, wr, er, N_NODES);
    edge_phase(1, accA, 1);

    // etype2: A -> A
    gemm_tile<256, 64><<<GB_MM, 256, 0, stream>>>(xA, W1 + 2 * 65536, Fs, N_NODES);
    rowdot<<<GB_ROW, 256, 0, stream>>>(Fs, al1 + 2 * 256, el, N_NODES);
    make_wr<<<8, 256, 0, stream>>>(W1 + 2 * 65536, ar1 + 2 * 256, wr, FIN);
    gemv_er<FIN><<<GB_ROW, 256, 0, stream>>>(xA, wr, er, N_NODES);
    edge_phase(2, accA, 0);

    // head-mean + bias + relu
    combine_mean<1><<<GB_COMB, 256, 0, stream>>>(accA, b1 + 1 * 256, b1 + 2 * 256, hA, N_NODES);
    combine_mean<1><<<GB_COMB, 256, 0, stream>>>(accB, b1 + 0 * 256, nullptr, hB, N_NODES);

    // ---------------- layer 2 ----------------
    // etype0: A -> B
    gemm_tile<32, 32><<<GB_MM, 256, 0, stream>>>(hA, W2 + 0 * 8192, Fs, N_NODES);
    rowdot<<<GB_ROW, 256, 0, stream>>>(Fs, al2 + 0 * 256, el, N_NODES);
    make_wr<<<1, 256, 0, stream>>>(W2 + 0 * 8192, ar2 + 0 * 256, wr, 32);
    gemv_er<32><<<GB_ROW, 256, 0, stream>>>(hB, wr, er, N_NODES);
    edge_phase(0, accB, 1);

    // etype1: B -> A
    gemm_tile<32, 32><<<GB_MM, 256, 0, stream>>>(hB, W2 + 1 * 8192, Fs, N_NODES);
    rowdot<<<GB_ROW, 256, 0, stream>>>(Fs, al2 + 1 * 256, el, N_NODES);
    make_wr<<<1, 256, 0, stream>>>(W2 + 1 * 8192, ar2 + 1 * 256, wr, 32);
    gemv_er<32><<<GB_ROW, 256, 0, stream>>>(hA, wr, er, N_NODES);
    edge_phase(1, accA, 1);

    // etype2: A -> A
    gemm_tile<32, 32><<<GB_MM, 256, 0, stream>>>(hA, W2 + 2 * 8192, Fs, N_NODES);
    rowdot<<<GB_ROW, 256, 0, stream>>>(Fs, al2 + 2 * 256, el, N_NODES);
    make_wr<<<1, 256, 0, stream>>>(W2 + 2 * 8192, ar2 + 2 * 256, wr, 32);
    gemv_er<32><<<GB_ROW, 256, 0, stream>>>(hA, wr, er, N_NODES);
    edge_phase(2, accA, 0);

    // final: mean over heads + bias, no relu; stack [oA, oB]
    combine_mean<0><<<GB_COMB, 256, 0, stream>>>(accA, b2 + 1 * 256, b2 + 2 * 256, out, N_NODES);
    combine_mean<0><<<GB_COMB, 256, 0, stream>>>(accB, b2 + 0 * 256, nullptr, out + (size_t)N_NODES * D, N_NODES);
}

// Round 6
// 769.953 us; speedup vs baseline: 34.1866x; 1.1426x over previous
//
#include <hip/hip_runtime.h>
#include <float.h>

#define NEG_SLOPE 0.2f

constexpr int N_NODES = 20000;
constexpr int NE      = 320000;
constexpr int H       = 8;
constexpr int D       = 32;
constexpr int HD      = 256;   // H*D
constexpr int FIN     = 256;

// ============ feature GEMM + fused el epilogue ============
// C[M,256] = X[M,K] @ W[K,256]; el[row, 2*by + (0|1)] = sum_d C*al over the
// 64-col slice (64 cols = exactly 2 heads).
template <int K, int BK>
__global__ __launch_bounds__(256) void gemm_el(
    const float* __restrict__ X, const float* __restrict__ W,
    const float* __restrict__ al, float* __restrict__ C,
    float* __restrict__ el, int M)
{
    constexpr int XS = BK + 8;   // %4==0 (b128 align), ty rows 8 banks apart
    __shared__ float Xs[128][XS];
    __shared__ float Ws[BK][64];
    const int tx = threadIdx.x & 15;
    const int ty = threadIdx.x >> 4;
    const int r0 = blockIdx.x * 128;
    const int c0 = blockIdx.y * 64;
    float4 acc[8];
#pragma unroll
    for (int r = 0; r < 8; r++) acc[r] = make_float4(0.f, 0.f, 0.f, 0.f);

    for (int kc = 0; kc < K; kc += BK) {
        for (int idx = threadIdx.x; idx < 128 * (BK / 4); idx += 256) {
            int row = idx / (BK / 4);
            int kq  = idx % (BK / 4);
            int grow = r0 + row;
            float4 xv = (grow < M) ? *(const float4*)(X + (size_t)grow * K + kc + kq * 4)
                                   : make_float4(0.f, 0.f, 0.f, 0.f);
            *(float4*)&Xs[row][kq * 4] = xv;
        }
        for (int idx = threadIdx.x; idx < BK * 16; idx += 256) {
            int k = idx >> 4, cq = idx & 15;
            *(float4*)&Ws[k][cq * 4] = *(const float4*)(W + (size_t)(kc + k) * 256 + c0 + cq * 4);
        }
        __syncthreads();
#pragma unroll 4
        for (int k = 0; k < BK; k++) {
            float4 wv = *(float4*)&Ws[k][tx * 4];
#pragma unroll
            for (int r = 0; r < 8; r++) {
                float x = Xs[ty + 16 * r][k];
                acc[r].x = fmaf(x, wv.x, acc[r].x);
                acc[r].y = fmaf(x, wv.y, acc[r].y);
                acc[r].z = fmaf(x, wv.z, acc[r].z);
                acc[r].w = fmaf(x, wv.w, acc[r].w);
            }
        }
        __syncthreads();
    }
    // store C
#pragma unroll
    for (int r = 0; r < 8; r++) {
        int row = r0 + ty + 16 * r;
        if (row < M) *(float4*)(C + (size_t)row * 256 + c0 + tx * 4) = acc[r];
    }
    // el epilogue: this block's 64 cols = heads 2*by, 2*by+1
    float a0 = al[c0 + tx * 4 + 0], a1 = al[c0 + tx * 4 + 1];
    float a2 = al[c0 + tx * 4 + 2], a3 = al[c0 + tx * 4 + 3];
#pragma unroll
    for (int r = 0; r < 8; r++) {
        float p = acc[r].x * a0 + acc[r].y * a1 + acc[r].z * a2 + acc[r].w * a3;
        p += __shfl_xor(p, 1, 64);
        p += __shfl_xor(p, 2, 64);
        p += __shfl_xor(p, 4, 64);   // sum over 8 tx lanes of one head
        int row = r0 + ty + 16 * r;
        if ((tx & 7) == 0 && row < M)
            el[row * H + 2 * blockIdx.y + (tx >> 3)] = p;
    }
}

// ---- wr[et][k,h] = sum_d W[et][k, h*32+d] * ar[et][h,d], 3 etypes ----
__global__ void make_wr3(const float* __restrict__ W, const float* __restrict__ ar,
                         float* __restrict__ wr, int K, int wstride)
{
    int t = blockIdx.x * blockDim.x + threadIdx.x;
    if (t >= 3 * K * H) return;
    int et = t / (K * H), rem = t % (K * H);
    int k = rem / H, h = rem % H;
    const float* Wp  = W + (size_t)et * wstride + k * HD + h * D;
    const float* arp = ar + et * HD + h * D;
    float s = 0.f;
#pragma unroll
    for (int d = 0; d < D; d++) s += Wp[d] * arp[d];
    wr[t] = s;
}

// ---- er[n,h] = sum_k x[n,k] * wr[k,h] ----
template <int K>
__global__ __launch_bounds__(256) void gemv_er(
    const float* __restrict__ x, const float* __restrict__ wr,
    float* __restrict__ er, int N)
{
    __shared__ float w[K * H];
    for (int i = threadIdx.x; i < K * H; i += 256) w[i] = wr[i];
    __syncthreads();
    int t = blockIdx.x * 256 + threadIdx.x;
    if (t >= N * H) return;
    int n = t >> 3, h = t & 7;
    const float4* xp = (const float4*)(x + (size_t)n * K);
    float s = 0.f;
#pragma unroll 4
    for (int k4 = 0; k4 < K / 4; k4++) {
        float4 xv = xp[k4];
        s += xv.x * w[(4 * k4 + 0) * H + h];
        s += xv.y * w[(4 * k4 + 1) * H + h];
        s += xv.z * w[(4 * k4 + 2) * H + h];
        s += xv.w * w[(4 * k4 + 3) * H + h];
    }
    er[t] = s;
}

// ---- two er vectors from the same x (one x read) ----
template <int K>
__global__ __launch_bounds__(256) void gemv_er2(
    const float* __restrict__ x, const float* __restrict__ wrA,
    const float* __restrict__ wrB, float* __restrict__ erA,
    float* __restrict__ erB, int N)
{
    __shared__ float wa[K * H];
    __shared__ float wb[K * H];
    for (int i = threadIdx.x; i < K * H; i += 256) { wa[i] = wrA[i]; wb[i] = wrB[i]; }
    __syncthreads();
    int t = blockIdx.x * 256 + threadIdx.x;
    if (t >= N * H) return;
    int n = t >> 3, h = t & 7;
    const float4* xp = (const float4*)(x + (size_t)n * K);
    float s1 = 0.f, s2 = 0.f;
#pragma unroll 4
    for (int k4 = 0; k4 < K / 4; k4++) {
        float4 xv = xp[k4];
        s1 += xv.x * wa[(4 * k4 + 0) * H + h] + xv.y * wa[(4 * k4 + 1) * H + h]
            + xv.z * wa[(4 * k4 + 2) * H + h] + xv.w * wa[(4 * k4 + 3) * H + h];
        s2 += xv.x * wb[(4 * k4 + 0) * H + h] + xv.y * wb[(4 * k4 + 1) * H + h]
            + xv.z * wb[(4 * k4 + 2) * H + h] + xv.w * wb[(4 * k4 + 3) * H + h];
    }
    erA[t] = s1; erB[t] = s2;
}

// ---- bias head-sums: bs[0]=b1[1]+b1[2], bs[1]=b1[0], bs[2]=b2[1]+b2[2], bs[3]=b2[0] ----
__global__ void bias_sums(const float* __restrict__ b1, const float* __restrict__ b2,
                          float* __restrict__ bs)
{
    int t = threadIdx.x;            // 128
    int which = t >> 5, d = t & 31;
    const float* b = (which < 2) ? b1 : b2;
    float s = 0.f;
    if (which & 1) {
#pragma unroll
        for (int h = 0; h < H; h++) s += b[0 * 256 + h * D + d];
    } else {
#pragma unroll
        for (int h = 0; h < H; h++) s += b[1 * 256 + h * D + d] + b[2 * 256 + h * D + d];
    }
    bs[t] = s;
}

// ============ CSR build (3 etypes, global offsets) ============

__global__ void zero_ints(int* __restrict__ p, int n)
{
    int t = blockIdx.x * blockDim.x + threadIdx.x;
    if (t < n) p[t] = 0;
}

__global__ void hist3(const int* __restrict__ v0, const int* __restrict__ v1,
                      const int* __restrict__ v2, int* __restrict__ cnt)
{
    int t = blockIdx.x * blockDim.x + threadIdx.x;
    if (t >= 3 * NE) return;
    int et = t / NE, i = t - et * NE;
    const int* vp = (et == 0) ? v0 : (et == 1) ? v1 : v2;
    atomicAdd(&cnt[et * N_NODES + vp[i]], 1);
}

__global__ __launch_bounds__(1024) void scan3(
    const int* __restrict__ cnt, int* __restrict__ off, int* __restrict__ cursor)
{
    __shared__ int part[1024];
    const int NT = 3 * N_NODES;
    const int CH = (NT + 1023) / 1024;
    int t = threadIdx.x;
    int lo = t * CH, hi = min(lo + CH, NT);
    int s = 0;
    for (int i = lo; i < hi; i++) s += cnt[i];
    part[t] = s;
    __syncthreads();
    if (t == 0) {
        int run = 0;
        for (int i = 0; i < 1024; i++) { int x = part[i]; part[i] = run; run += x; }
    }
    __syncthreads();
    int run = part[t];
    for (int i = lo; i < hi; i++) {
        off[i] = run; cursor[i] = run; run += cnt[i];
    }
    if (t == 0) off[NT] = 3 * NE;
}

__global__ void fill3(const int* __restrict__ u0, const int* __restrict__ v0,
                      const int* __restrict__ u1, const int* __restrict__ v1,
                      const int* __restrict__ u2, const int* __restrict__ v2,
                      int* __restrict__ cursor, int* __restrict__ usort)
{
    int t = blockIdx.x * blockDim.x + threadIdx.x;
    if (t >= 3 * NE) return;
    int et = t / NE, i = t - et * NE;
    const int* up = (et == 0) ? u0 : (et == 1) ? u1 : u2;
    const int* vp = (et == 0) ? v0 : (et == 1) ? v1 : v2;
    int pos = atomicAdd(&cursor[et * N_NODES + vp[i]], 1);
    usort[pos] = up[i];
}

// ============ fused single-pass edge softmax + gather + head-mean ============
// one 64-lane wave per dst node v; lane covers cols lane*4..lane*4+3 (head = lane>>3).
// a = exp(e)/sum exp(e)  (no max subtraction: logits bounded, exact ratio identical)
// epilogue: reduce over heads via shfl, out[v,0:32] = (sum_h + bias_sum)*0.125 (+relu)

template <int RELU>
__global__ __launch_bounds__(256) void seg_att1(
    const float* __restrict__ el, const float* __restrict__ er,
    const int* __restrict__ off, const int* __restrict__ us,
    const float* __restrict__ Fs, const float* __restrict__ bs,
    float* __restrict__ out, int N)
{
    int wid = blockIdx.x * 4 + (threadIdx.x >> 6);
    if (wid >= N) return;
    const int lane = threadIdx.x & 63;
    const int h = lane >> 3;
    const int v = wid;
    const int lo = off[v], hi = off[v + 1];
    float erh = er[v * H + h];
    float4 aa = make_float4(0.f, 0.f, 0.f, 0.f);
    float s = 0.f;
    int u_cur = (lo < hi) ? us[lo] : 0;
    for (int j = lo; j < hi; j++) {
        int u_nxt = (j + 1 < hi) ? us[j + 1] : 0;
        float4 f = *(const float4*)(Fs + (size_t)u_cur * HD + lane * 4);
        float e = el[u_cur * H + h] + erh;
        e = (e >= 0.f) ? e : NEG_SLOPE * e;
        float w = __expf(e);
        s += w;
        aa.x = fmaf(w, f.x, aa.x);
        aa.y = fmaf(w, f.y, aa.y);
        aa.z = fmaf(w, f.z, aa.z);
        aa.w = fmaf(w, f.w, aa.w);
        u_cur = u_nxt;
    }
    float inv = (s > 0.f) ? 1.f / s : 0.f;
    aa.x *= inv; aa.y *= inv; aa.z *= inv; aa.w *= inv;
    // head reduction: sum lanes {l, l^8, l^16, l^32}
#pragma unroll
    for (int mask = 8; mask <= 32; mask <<= 1) {
        aa.x += __shfl_xor(aa.x, mask, 64);
        aa.y += __shfl_xor(aa.y, mask, 64);
        aa.z += __shfl_xor(aa.z, mask, 64);
        aa.w += __shfl_xor(aa.w, mask, 64);
    }
    if (lane < 8) {
        float4 b = *(const float4*)(bs + lane * 4);
        float4 o;
        o.x = (aa.x + b.x) * 0.125f;
        o.y = (aa.y + b.y) * 0.125f;
        o.z = (aa.z + b.z) * 0.125f;
        o.w = (aa.w + b.w) * 0.125f;
        if (RELU) {
            o.x = fmaxf(o.x, 0.f); o.y = fmaxf(o.y, 0.f);
            o.z = fmaxf(o.z, 0.f); o.w = fmaxf(o.w, 0.f);
        }
        *(float4*)(out + (size_t)v * D + lane * 4) = o;
    }
}

// dual: two etypes with the same dst type, summed (HeteroGraphConv sum)
template <int RELU>
__global__ __launch_bounds__(256) void seg_att2(
    const float* __restrict__ el1, const float* __restrict__ er1,
    const int* __restrict__ off1,
    const float* __restrict__ Fs1,
    const float* __restrict__ el2, const float* __restrict__ er2,
    const int* __restrict__ off2,
    const float* __restrict__ Fs2,
    const int* __restrict__ us, const float* __restrict__ bs,
    float* __restrict__ out, int N)
{
    int wid = blockIdx.x * 4 + (threadIdx.x >> 6);
    if (wid >= N) return;
    const int lane = threadIdx.x & 63;
    const int h = lane >> 3;
    const int v = wid;
    float4 tot = make_float4(0.f, 0.f, 0.f, 0.f);

    // ---- etype 1 ----
    {
        const int lo = off1[v], hi = off1[v + 1];
        float erh = er1[v * H + h];
        float4 aa = make_float4(0.f, 0.f, 0.f, 0.f);
        float s = 0.f;
        int u_cur = (lo < hi) ? us[lo] : 0;
        for (int j = lo; j < hi; j++) {
            int u_nxt = (j + 1 < hi) ? us[j + 1] : 0;
            float4 f = *(const float4*)(Fs1 + (size_t)u_cur * HD + lane * 4);
            float e = el1[u_cur * H + h] + erh;
            e = (e >= 0.f) ? e : NEG_SLOPE * e;
            float w = __expf(e);
            s += w;
            aa.x = fmaf(w, f.x, aa.x);
            aa.y = fmaf(w, f.y, aa.y);
            aa.z = fmaf(w, f.z, aa.z);
            aa.w = fmaf(w, f.w, aa.w);
            u_cur = u_nxt;
        }
        float inv = (s > 0.f) ? 1.f / s : 0.f;
        tot.x = fmaf(aa.x, inv, tot.x);
        tot.y = fmaf(aa.y, inv, tot.y);
        tot.z = fmaf(aa.z, inv, tot.z);
        tot.w = fmaf(aa.w, inv, tot.w);
    }
    // ---- etype 2 ----
    {
        const int lo = off2[v], hi = off2[v + 1];
        float erh = er2[v * H + h];
        float4 aa = make_float4(0.f, 0.f, 0.f, 0.f);
        float s = 0.f;
        int u_cur = (lo < hi) ? us[lo] : 0;
        for (int j = lo; j < hi; j++) {
            int u_nxt = (j + 1 < hi) ? us[j + 1] : 0;
            float4 f = *(const float4*)(Fs2 + (size_t)u_cur * HD + lane * 4);
            float e = el2[u_cur * H + h] + erh;
            e = (e >= 0.f) ? e : NEG_SLOPE * e;
            float w = __expf(e);
            s += w;
            aa.x = fmaf(w, f.x, aa.x);
            aa.y = fmaf(w, f.y, aa.y);
            aa.z = fmaf(w, f.z, aa.z);
            aa.w = fmaf(w, f.w, aa.w);
            u_cur = u_nxt;
        }
        float inv = (s > 0.f) ? 1.f / s : 0.f;
        tot.x = fmaf(aa.x, inv, tot.x);
        tot.y = fmaf(aa.y, inv, tot.y);
        tot.z = fmaf(aa.z, inv, tot.z);
        tot.w = fmaf(aa.w, inv, tot.w);
    }
#pragma unroll
    for (int mask = 8; mask <= 32; mask <<= 1) {
        tot.x += __shfl_xor(tot.x, mask, 64);
        tot.y += __shfl_xor(tot.y, mask, 64);
        tot.z += __shfl_xor(tot.z, mask, 64);
        tot.w += __shfl_xor(tot.w, mask, 64);
    }
    if (lane < 8) {
        float4 b = *(const float4*)(bs + lane * 4);
        float4 o;
        o.x = (tot.x + b.x) * 0.125f;
        o.y = (tot.y + b.y) * 0.125f;
        o.z = (tot.z + b.z) * 0.125f;
        o.w = (tot.w + b.w) * 0.125f;
        if (RELU) {
            o.x = fmaxf(o.x, 0.f); o.y = fmaxf(o.y, 0.f);
            o.z = fmaxf(o.z, 0.f); o.w = fmaxf(o.w, 0.f);
        }
        *(float4*)(out + (size_t)v * D + lane * 4) = o;
    }
}

// ================= host =================

extern "C" void kernel_launch(void* const* d_in, const int* in_sizes, int n_in,
                              void* d_out, int out_size, void* d_ws, size_t ws_size,
                              hipStream_t stream)
{
    const float* xA  = (const float*)d_in[0];
    const float* xB  = (const float*)d_in[1];
    const float* W1  = (const float*)d_in[2];   // [3][256][256]
    const float* al1 = (const float*)d_in[3];   // [3][256]
    const float* ar1 = (const float*)d_in[4];
    const float* b1  = (const float*)d_in[5];   // [3][256]
    const float* W2  = (const float*)d_in[6];   // [3][32][256]
    const float* al2 = (const float*)d_in[7];
    const float* ar2 = (const float*)d_in[8];
    const float* b2  = (const float*)d_in[9];
    const int* u0 = (const int*)d_in[10];
    const int* v0 = (const int*)d_in[11];
    const int* u1 = (const int*)d_in[12];
    const int* v1 = (const int*)d_in[13];
    const int* u2 = (const int*)d_in[14];
    const int* v2 = (const int*)d_in[15];
    float* out = (float*)d_out;

    // workspace layout (floats)
    float* ws = (float*)d_ws;
    const size_t FSZ = (size_t)N_NODES * HD;   // 5.12M floats
    float* F1  = ws;
    float* F2  = F1 + FSZ;
    float* el  = F2 + FSZ;                     // [3][N*H]
    float* er  = el + 3 * N_NODES * H;         // [3][N*H]
    float* hA  = er + 3 * N_NODES * H;         // [N][32]
    float* hB  = hA + (size_t)N_NODES * D;
    float* wr  = hB + (size_t)N_NODES * D;     // [3][256*8] max
    float* bs  = wr + 3 * 2048;                // [4][32]
    int* off    = (int*)(bs + 128);            // 3N+1 (global positions)
    int* cursor = off + 3 * N_NODES + 1;       // 3N
    int* cnt    = cursor + 3 * N_NODES;        // 3N
    int* usort  = cnt + 3 * N_NODES;           // 3NE (concatenated)

    float* el0 = el, *el1 = el + N_NODES * H, *el2 = el + 2 * N_NODES * H;
    float* er0 = er, *er1 = er + N_NODES * H, *er2 = er + 2 * N_NODES * H;
    int* off0 = off, *off1 = off + N_NODES, *off2 = off + 2 * N_NODES;
    float* bsA1 = bs, *bsB1 = bs + 32, *bsA2 = bs + 64, *bsB2 = bs + 96;

    const dim3 GB_MM(157, 4);
    const int GB_ROW  = N_NODES * H / 256;            // 625
    const int GB_WAVE = (N_NODES + 3) / 4;            // 5000
    const int GB_3N   = (3 * N_NODES + 255) / 256;
    const int GB_3E   = (3 * NE + 255) / 256;

    // ---- CSR build (all 3 etypes; offsets global into concatenated usort) ----
    zero_ints<<<GB_3N, 256, 0, stream>>>(cnt, 3 * N_NODES);
    hist3<<<GB_3E, 256, 0, stream>>>(v0, v1, v2, cnt);
    scan3<<<1, 1024, 0, stream>>>(cnt, off, cursor);
    fill3<<<GB_3E, 256, 0, stream>>>(u0, v0, u1, v1, u2, v2, cursor, usort);

    bias_sums<<<1, 128, 0, stream>>>(b1, b2, bs);
    make_wr3<<<24, 256, 0, stream>>>(W1, ar1, wr, 256, 65536);

    // ---------------- layer 1 ----------------
    // etype0: A -> B (dst B, RELU)
    gemm_el<256, 64><<<GB_MM, 256, 0, stream>>>(xA, W1 + 0 * 65536, al1 + 0 * 256, F1, el0, N_NODES);
    gemv_er<256><<<GB_ROW, 256, 0, stream>>>(xB, wr + 0 * 2048, er0, N_NODES);
    seg_att1<1><<<GB_WAVE, 256, 0, stream>>>(el0, er0, off0, usort, F1, bsB1, hB, N_NODES);

    // etype1: B->A, etype2: A->A (dst A, summed, RELU)
    gemm_el<256, 64><<<GB_MM, 256, 0, stream>>>(xB, W1 + 1 * 65536, al1 + 1 * 256, F1, el1, N_NODES);
    gemm_el<256, 64><<<GB_MM, 256, 0, stream>>>(xA, W1 + 2 * 65536, al1 + 2 * 256, F2, el2, N_NODES);
    gemv_er2<256><<<GB_ROW, 256, 0, stream>>>(xA, wr + 1 * 2048, wr + 2 * 2048, er1, er2, N_NODES);
    seg_att2<1><<<GB_WAVE, 256, 0, stream>>>(el1, er1, off1, F1, el2, er2, off2, F2,
                                             usort, bsA1, hA, N_NODES);

    // ---------------- layer 2 ----------------
    make_wr3<<<3, 256, 0, stream>>>(W2, ar2, wr, 32, 8192);

    // etype0: A -> B (dst B = out[N*D:])
    gemm_el<32, 32><<<GB_MM, 256, 0, stream>>>(hA, W2 + 0 * 8192, al2 + 0 * 256, F1, el0, N_NODES);
    gemv_er<32><<<GB_ROW, 256, 0, stream>>>(hB, wr + 0 * 256, er0, N_NODES);
    seg_att1<0><<<GB_WAVE, 256, 0, stream>>>(el0, er0, off0, usort, F1, bsB2,
                                             out + (size_t)N_NODES * D, N_NODES);

    // etype1: B->A, etype2: A->A (dst A = out[0:N*D])
    gemm_el<32, 32><<<GB_MM, 256, 0, stream>>>(hB, W2 + 1 * 8192, al2 + 1 * 256, F1, el1, N_NODES);
    gemm_el<32, 32><<<GB_MM, 256, 0, stream>>>(hA, W2 + 2 * 8192, al2 + 2 * 256, F2, el2, N_NODES);
    gemv_er2<32><<<GB_ROW, 256, 0, stream>>>(hA, wr + 1 * 256, wr + 2 * 256, er1, er2, N_NODES);
    seg_att2<0><<<GB_WAVE, 256, 0, stream>>>(el1, er1, off1, F1, el2, er2, off2, F2,
                                             usort, bsA2, out, N_NODES);
}

// Round 7
// 623.690 us; speedup vs baseline: 42.2038x; 1.2345x over previous
//
#include <hip/hip_runtime.h>
#include <float.h>

#define NEG_SLOPE 0.2f

constexpr int N_NODES = 20000;
constexpr int NE      = 320000;
constexpr int H       = 8;
constexpr int D       = 32;
constexpr int HD      = 256;   // H*D
constexpr int FIN     = 256;
constexpr int SCAN_NT = 3 * N_NODES;          // 60000
constexpr int SCAN_NB = (SCAN_NT + 511) / 512; // 118

// ============ feature GEMM + fused el epilogue ============
// C[M,256] = X[M,K] @ W[K,256]; el[row, 2*by + (0|1)] = sum over the 64-col
// slice (64 cols = exactly 2 heads) of C*al.
template <int K, int BK>
__global__ __launch_bounds__(256) void gemm_el(
    const float* __restrict__ X, const float* __restrict__ W,
    const float* __restrict__ al, float* __restrict__ C,
    float* __restrict__ el, int M)
{
    constexpr int XS = BK + 8;   // %4==0 (b128 align), ty rows 8 banks apart
    __shared__ float Xs[128][XS];
    __shared__ float Ws[BK][64];
    const int tx = threadIdx.x & 15;
    const int ty = threadIdx.x >> 4;
    const int r0 = blockIdx.x * 128;
    const int c0 = blockIdx.y * 64;
    float4 acc[8];
#pragma unroll
    for (int r = 0; r < 8; r++) acc[r] = make_float4(0.f, 0.f, 0.f, 0.f);

    for (int kc = 0; kc < K; kc += BK) {
        for (int idx = threadIdx.x; idx < 128 * (BK / 4); idx += 256) {
            int row = idx / (BK / 4);
            int kq  = idx % (BK / 4);
            int grow = r0 + row;
            float4 xv = (grow < M) ? *(const float4*)(X + (size_t)grow * K + kc + kq * 4)
                                   : make_float4(0.f, 0.f, 0.f, 0.f);
            *(float4*)&Xs[row][kq * 4] = xv;
        }
        for (int idx = threadIdx.x; idx < BK * 16; idx += 256) {
            int k = idx >> 4, cq = idx & 15;
            *(float4*)&Ws[k][cq * 4] = *(const float4*)(W + (size_t)(kc + k) * 256 + c0 + cq * 4);
        }
        __syncthreads();
#pragma unroll 4
        for (int k = 0; k < BK; k++) {
            float4 wv = *(float4*)&Ws[k][tx * 4];
#pragma unroll
            for (int r = 0; r < 8; r++) {
                float x = Xs[ty + 16 * r][k];
                acc[r].x = fmaf(x, wv.x, acc[r].x);
                acc[r].y = fmaf(x, wv.y, acc[r].y);
                acc[r].z = fmaf(x, wv.z, acc[r].z);
                acc[r].w = fmaf(x, wv.w, acc[r].w);
            }
        }
        __syncthreads();
    }
#pragma unroll
    for (int r = 0; r < 8; r++) {
        int row = r0 + ty + 16 * r;
        if (row < M) *(float4*)(C + (size_t)row * 256 + c0 + tx * 4) = acc[r];
    }
    // el epilogue: this block's 64 cols = heads 2*by, 2*by+1
    float a0 = al[c0 + tx * 4 + 0], a1 = al[c0 + tx * 4 + 1];
    float a2 = al[c0 + tx * 4 + 2], a3 = al[c0 + tx * 4 + 3];
#pragma unroll
    for (int r = 0; r < 8; r++) {
        float p = acc[r].x * a0 + acc[r].y * a1 + acc[r].z * a2 + acc[r].w * a3;
        p += __shfl_xor(p, 1, 64);
        p += __shfl_xor(p, 2, 64);
        p += __shfl_xor(p, 4, 64);   // sum over 8 tx lanes of one head
        int row = r0 + ty + 16 * r;
        if ((tx & 7) == 0 && row < M)
            el[row * H + 2 * blockIdx.y + (tx >> 3)] = p;
    }
}

// ---- wr[et][k,h] = sum_d W[et][k, h*32+d] * ar[et][h,d], 3 etypes ----
__global__ void make_wr3(const float* __restrict__ W, const float* __restrict__ ar,
                         float* __restrict__ wr, int K, int wstride)
{
    int t = blockIdx.x * blockDim.x + threadIdx.x;
    if (t >= 3 * K * H) return;
    int et = t / (K * H), rem = t % (K * H);
    int k = rem / H, h = rem % H;
    const float* Wp  = W + (size_t)et * wstride + k * HD + h * D;
    const float* arp = ar + et * HD + h * D;
    float s = 0.f;
#pragma unroll
    for (int d = 0; d < D; d++) s += Wp[d] * arp[d];
    wr[t] = s;
}

// ---- er[n,h] = sum_k x[n,k] * wr[k,h] ----
template <int K>
__global__ __launch_bounds__(256) void gemv_er(
    const float* __restrict__ x, const float* __restrict__ wr,
    float* __restrict__ er, int N)
{
    __shared__ float w[K * H];
    for (int i = threadIdx.x; i < K * H; i += 256) w[i] = wr[i];
    __syncthreads();
    int t = blockIdx.x * 256 + threadIdx.x;
    if (t >= N * H) return;
    int n = t >> 3, h = t & 7;
    const float4* xp = (const float4*)(x + (size_t)n * K);
    float s = 0.f;
#pragma unroll 4
    for (int k4 = 0; k4 < K / 4; k4++) {
        float4 xv = xp[k4];
        s += xv.x * w[(4 * k4 + 0) * H + h];
        s += xv.y * w[(4 * k4 + 1) * H + h];
        s += xv.z * w[(4 * k4 + 2) * H + h];
        s += xv.w * w[(4 * k4 + 3) * H + h];
    }
    er[t] = s;
}

// ---- two er vectors from the same x (one x read) ----
template <int K>
__global__ __launch_bounds__(256) void gemv_er2(
    const float* __restrict__ x, const float* __restrict__ wrA,
    const float* __restrict__ wrB, float* __restrict__ erA,
    float* __restrict__ erB, int N)
{
    __shared__ float wa[K * H];
    __shared__ float wb[K * H];
    for (int i = threadIdx.x; i < K * H; i += 256) { wa[i] = wrA[i]; wb[i] = wrB[i]; }
    __syncthreads();
    int t = blockIdx.x * 256 + threadIdx.x;
    if (t >= N * H) return;
    int n = t >> 3, h = t & 7;
    const float4* xp = (const float4*)(x + (size_t)n * K);
    float s1 = 0.f, s2 = 0.f;
#pragma unroll 4
    for (int k4 = 0; k4 < K / 4; k4++) {
        float4 xv = xp[k4];
        s1 += xv.x * wa[(4 * k4 + 0) * H + h] + xv.y * wa[(4 * k4 + 1) * H + h]
            + xv.z * wa[(4 * k4 + 2) * H + h] + xv.w * wa[(4 * k4 + 3) * H + h];
        s2 += xv.x * wb[(4 * k4 + 0) * H + h] + xv.y * wb[(4 * k4 + 1) * H + h]
            + xv.z * wb[(4 * k4 + 2) * H + h] + xv.w * wb[(4 * k4 + 3) * H + h];
    }
    erA[t] = s1; erB[t] = s2;
}

// ---- bias head-sums ----
__global__ void bias_sums(const float* __restrict__ b1, const float* __restrict__ b2,
                          float* __restrict__ bs)
{
    int t = threadIdx.x;            // 128
    int which = t >> 5, d = t & 31;
    const float* b = (which < 2) ? b1 : b2;
    float s = 0.f;
    if (which & 1) {
#pragma unroll
        for (int h = 0; h < H; h++) s += b[0 * 256 + h * D + d];
    } else {
#pragma unroll
        for (int h = 0; h < H; h++) s += b[1 * 256 + h * D + d] + b[2 * 256 + h * D + d];
    }
    bs[t] = s;
}

// ============ CSR build (3 etypes, global offsets) ============

__global__ void hist3(const int* __restrict__ v0, const int* __restrict__ v1,
                      const int* __restrict__ v2, int* __restrict__ cnt)
{
    int t = blockIdx.x * blockDim.x + threadIdx.x;
    if (t >= 3 * NE) return;
    int et = t / NE, i = t - et * NE;
    const int* vp = (et == 0) ? v0 : (et == 1) ? v1 : v2;
    atomicAdd(&cnt[et * N_NODES + vp[i]], 1);
}

// phase A: per-block (512) exclusive scan; bsum[b] = block total
__global__ __launch_bounds__(512) void scan_blk(
    const int* __restrict__ cnt, int* __restrict__ loc, int* __restrict__ bsum)
{
    int gid = blockIdx.x * 512 + threadIdx.x;
    int x = (gid < SCAN_NT) ? cnt[gid] : 0;
    int lane = threadIdx.x & 63, w = threadIdx.x >> 6;
    int v = x;
#pragma unroll
    for (int d = 1; d < 64; d <<= 1) {
        int y = __shfl_up(v, d, 64);
        if (lane >= d) v += y;
    }
    __shared__ int wsum[8];
    if (lane == 63) wsum[w] = v;
    __syncthreads();
    if (threadIdx.x == 0) {
        int run = 0;
#pragma unroll
        for (int i = 0; i < 8; i++) { int t2 = wsum[i]; wsum[i] = run; run += t2; }
    }
    __syncthreads();
    int excl = v - x + wsum[w];
    if (gid < SCAN_NT) loc[gid] = excl;
    if (threadIdx.x == 511) bsum[blockIdx.x] = excl + x;
}

// phase B: exclusive scan of the <=128 block sums (one block)
__global__ __launch_bounds__(128) void scan_bsum(int* __restrict__ bsum, int nb)
{
    int t = threadIdx.x;
    int x = (t < nb) ? bsum[t] : 0;
    int lane = t & 63, w = t >> 6;
    int v = x;
#pragma unroll
    for (int d = 1; d < 64; d <<= 1) {
        int y = __shfl_up(v, d, 64);
        if (lane >= d) v += y;
    }
    __shared__ int ws2[2];
    if (lane == 63) ws2[w] = v;
    __syncthreads();
    int add = (w == 1) ? ws2[0] : 0;
    if (t < nb) bsum[t] = v + add - x;
}

// phase C: off/cursor = loc + bsum[block]; off[NT] = 3*NE
__global__ __launch_bounds__(512) void scan_add(
    const int* __restrict__ loc, const int* __restrict__ bsum,
    int* __restrict__ off, int* __restrict__ cursor)
{
    int gid = blockIdx.x * 512 + threadIdx.x;
    if (gid < SCAN_NT) {
        int o = loc[gid] + bsum[blockIdx.x];
        off[gid] = o;
        cursor[gid] = o;
    } else if (gid == SCAN_NT) {
        off[gid] = 3 * NE;
    }
}

__global__ void fill3(const int* __restrict__ u0, const int* __restrict__ v0,
                      const int* __restrict__ u1, const int* __restrict__ v1,
                      const int* __restrict__ u2, const int* __restrict__ v2,
                      int* __restrict__ cursor, int* __restrict__ usort)
{
    int t = blockIdx.x * blockDim.x + threadIdx.x;
    if (t >= 3 * NE) return;
    int et = t / NE, i = t - et * NE;
    const int* up = (et == 0) ? u0 : (et == 1) ? u1 : u2;
    const int* vp = (et == 0) ? v0 : (et == 1) ? v1 : v2;
    int pos = atomicAdd(&cursor[et * N_NODES + vp[i]], 1);
    usort[pos] = up[i];
}

// ============ fused single-pass edge softmax + gather + head-mean ============
// one 64-lane wave per dst node v; lane covers cols lane*4..lane*4+3 (head=lane>>3).
// 4-wide edge batching: 4 independent Fs-row loads in flight; tail edges get w=0.

__device__ __forceinline__ float lrelu(float e) {
    return (e >= 0.f) ? e : NEG_SLOPE * e;
}

// one etype's segment accumulation for node v, head h, lane's float4 slice
__device__ __forceinline__ float4 seg_accum(
    const float* __restrict__ el, float erh,
    const int* __restrict__ us, int lo, int hi,
    const float* __restrict__ Fs, int lane, int h)
{
    float4 aa = make_float4(0.f, 0.f, 0.f, 0.f);
    float s = 0.f;
    for (int j = lo; j < hi; j += 4) {
        int u0 = us[j];
        int u1 = (j + 1 < hi) ? us[j + 1] : u0;
        int u2 = (j + 2 < hi) ? us[j + 2] : u0;
        int u3 = (j + 3 < hi) ? us[j + 3] : u0;
        float4 f0 = *(const float4*)(Fs + (size_t)u0 * HD + lane * 4);
        float4 f1 = *(const float4*)(Fs + (size_t)u1 * HD + lane * 4);
        float4 f2 = *(const float4*)(Fs + (size_t)u2 * HD + lane * 4);
        float4 f3 = *(const float4*)(Fs + (size_t)u3 * HD + lane * 4);
        float w0 = __expf(lrelu(el[u0 * H + h] + erh));
        float w1 = (j + 1 < hi) ? __expf(lrelu(el[u1 * H + h] + erh)) : 0.f;
        float w2 = (j + 2 < hi) ? __expf(lrelu(el[u2 * H + h] + erh)) : 0.f;
        float w3 = (j + 3 < hi) ? __expf(lrelu(el[u3 * H + h] + erh)) : 0.f;
        s += w0 + w1 + w2 + w3;
        aa.x = fmaf(w0, f0.x, fmaf(w1, f1.x, fmaf(w2, f2.x, fmaf(w3, f3.x, aa.x))));
        aa.y = fmaf(w0, f0.y, fmaf(w1, f1.y, fmaf(w2, f2.y, fmaf(w3, f3.y, aa.y))));
        aa.z = fmaf(w0, f0.z, fmaf(w1, f1.z, fmaf(w2, f2.z, fmaf(w3, f3.z, aa.z))));
        aa.w = fmaf(w0, f0.w, fmaf(w1, f1.w, fmaf(w2, f2.w, fmaf(w3, f3.w, aa.w))));
    }
    float inv = (s > 0.f) ? 1.f / s : 0.f;
    aa.x *= inv; aa.y *= inv; aa.z *= inv; aa.w *= inv;
    return aa;
}

template <int RELU>
__global__ __launch_bounds__(256) void seg_att1(
    const float* __restrict__ el, const float* __restrict__ er,
    const int* __restrict__ off, const int* __restrict__ us,
    const float* __restrict__ Fs, const float* __restrict__ bs,
    float* __restrict__ out, int N)
{
    int wid = blockIdx.x * 4 + (threadIdx.x >> 6);
    if (wid >= N) return;
    const int lane = threadIdx.x & 63;
    const int h = lane >> 3;
    const int v = wid;
    float4 aa = seg_accum(el, er[v * H + h], us, off[v], off[v + 1], Fs, lane, h);
#pragma unroll
    for (int mask = 8; mask <= 32; mask <<= 1) {
        aa.x += __shfl_xor(aa.x, mask, 64);
        aa.y += __shfl_xor(aa.y, mask, 64);
        aa.z += __shfl_xor(aa.z, mask, 64);
        aa.w += __shfl_xor(aa.w, mask, 64);
    }
    if (lane < 8) {
        float4 b = *(const float4*)(bs + lane * 4);
        float4 o;
        o.x = (aa.x + b.x) * 0.125f;
        o.y = (aa.y + b.y) * 0.125f;
        o.z = (aa.z + b.z) * 0.125f;
        o.w = (aa.w + b.w) * 0.125f;
        if (RELU) {
            o.x = fmaxf(o.x, 0.f); o.y = fmaxf(o.y, 0.f);
            o.z = fmaxf(o.z, 0.f); o.w = fmaxf(o.w, 0.f);
        }
        *(float4*)(out + (size_t)v * D + lane * 4) = o;
    }
}

// dual: two etypes with the same dst type, summed (HeteroGraphConv sum)
template <int RELU>
__global__ __launch_bounds__(256) void seg_att2(
    const float* __restrict__ el1, const float* __restrict__ er1,
    const int* __restrict__ off1, const float* __restrict__ Fs1,
    const float* __restrict__ el2, const float* __restrict__ er2,
    const int* __restrict__ off2, const float* __restrict__ Fs2,
    const int* __restrict__ us, const float* __restrict__ bs,
    float* __restrict__ out, int N)
{
    int wid = blockIdx.x * 4 + (threadIdx.x >> 6);
    if (wid >= N) return;
    const int lane = threadIdx.x & 63;
    const int h = lane >> 3;
    const int v = wid;
    float4 t1 = seg_accum(el1, er1[v * H + h], us, off1[v], off1[v + 1], Fs1, lane, h);
    float4 t2 = seg_accum(el2, er2[v * H + h], us, off2[v], off2[v + 1], Fs2, lane, h);
    float4 tot;
    tot.x = t1.x + t2.x; tot.y = t1.y + t2.y;
    tot.z = t1.z + t2.z; tot.w = t1.w + t2.w;
#pragma unroll
    for (int mask = 8; mask <= 32; mask <<= 1) {
        tot.x += __shfl_xor(tot.x, mask, 64);
        tot.y += __shfl_xor(tot.y, mask, 64);
        tot.z += __shfl_xor(tot.z, mask, 64);
        tot.w += __shfl_xor(tot.w, mask, 64);
    }
    if (lane < 8) {
        float4 b = *(const float4*)(bs + lane * 4);
        float4 o;
        o.x = (tot.x + b.x) * 0.125f;
        o.y = (tot.y + b.y) * 0.125f;
        o.z = (tot.z + b.z) * 0.125f;
        o.w = (tot.w + b.w) * 0.125f;
        if (RELU) {
            o.x = fmaxf(o.x, 0.f); o.y = fmaxf(o.y, 0.f);
            o.z = fmaxf(o.z, 0.f); o.w = fmaxf(o.w, 0.f);
        }
        *(float4*)(out + (size_t)v * D + lane * 4) = o;
    }
}

// ================= host =================

extern "C" void kernel_launch(void* const* d_in, const int* in_sizes, int n_in,
                              void* d_out, int out_size, void* d_ws, size_t ws_size,
                              hipStream_t stream)
{
    const float* xA  = (const float*)d_in[0];
    const float* xB  = (const float*)d_in[1];
    const float* W1  = (const float*)d_in[2];   // [3][256][256]
    const float* al1 = (const float*)d_in[3];   // [3][256]
    const float* ar1 = (const float*)d_in[4];
    const float* b1  = (const float*)d_in[5];   // [3][256]
    const float* W2  = (const float*)d_in[6];   // [3][32][256]
    const float* al2 = (const float*)d_in[7];
    const float* ar2 = (const float*)d_in[8];
    const float* b2  = (const float*)d_in[9];
    const int* u0 = (const int*)d_in[10];
    const int* v0 = (const int*)d_in[11];
    const int* u1 = (const int*)d_in[12];
    const int* v1 = (const int*)d_in[13];
    const int* u2 = (const int*)d_in[14];
    const int* v2 = (const int*)d_in[15];
    float* out = (float*)d_out;

    // workspace layout (floats)
    float* ws = (float*)d_ws;
    const size_t FSZ = (size_t)N_NODES * HD;   // 5.12M floats
    float* F1  = ws;
    float* F2  = F1 + FSZ;
    float* el  = F2 + FSZ;                     // [3][N*H]
    float* er  = el + 3 * N_NODES * H;         // [3][N*H]
    float* hA  = er + 3 * N_NODES * H;         // [N][32]
    float* hB  = hA + (size_t)N_NODES * D;
    float* wr  = hB + (size_t)N_NODES * D;     // [3][256*8] max
    float* bs  = wr + 3 * 2048;                // [4][32]
    int* off    = (int*)(bs + 128);            // 3N+1 (global positions)
    int* cursor = off + 3 * N_NODES + 1;       // 3N
    int* cnt    = cursor + 3 * N_NODES;        // 3N
    int* loc    = cnt + 3 * N_NODES;           // 3N
    int* bsum   = loc + 3 * N_NODES;           // SCAN_NB (<=128)
    int* usort  = bsum + 128;                  // 3NE (concatenated)

    float* el0 = el, *el1 = el + N_NODES * H, *el2 = el + 2 * N_NODES * H;
    float* er0 = er, *er1 = er + N_NODES * H, *er2 = er + 2 * N_NODES * H;
    int* off0 = off, *off1 = off + N_NODES, *off2 = off + 2 * N_NODES;
    float* bsA1 = bs, *bsB1 = bs + 32, *bsA2 = bs + 64, *bsB2 = bs + 96;

    const dim3 GB_MM(157, 4);
    const int GB_ROW  = N_NODES * H / 256;            // 625
    const int GB_WAVE = (N_NODES + 3) / 4;            // 5000
    const int GB_3E   = (3 * NE + 255) / 256;

    // ---- CSR build (all 3 etypes; offsets global into concatenated usort) ----
    hipMemsetAsync(cnt, 0, SCAN_NT * sizeof(int), stream);
    hist3<<<GB_3E, 256, 0, stream>>>(v0, v1, v2, cnt);
    scan_blk<<<SCAN_NB, 512, 0, stream>>>(cnt, loc, bsum);
    scan_bsum<<<1, 128, 0, stream>>>(bsum, SCAN_NB);
    scan_add<<<SCAN_NB, 512, 0, stream>>>(loc, bsum, off, cursor);
    fill3<<<GB_3E, 256, 0, stream>>>(u0, v0, u1, v1, u2, v2, cursor, usort);

    bias_sums<<<1, 128, 0, stream>>>(b1, b2, bs);
    make_wr3<<<24, 256, 0, stream>>>(W1, ar1, wr, 256, 65536);

    // ---------------- layer 1 ----------------
    // etype0: A -> B (dst B, RELU)
    gemm_el<256, 64><<<GB_MM, 256, 0, stream>>>(xA, W1 + 0 * 65536, al1 + 0 * 256, F1, el0, N_NODES);
    gemv_er<256><<<GB_ROW, 256, 0, stream>>>(xB, wr + 0 * 2048, er0, N_NODES);
    seg_att1<1><<<GB_WAVE, 256, 0, stream>>>(el0, er0, off0, usort, F1, bsB1, hB, N_NODES);

    // etype1: B->A, etype2: A->A (dst A, summed, RELU)
    gemm_el<256, 64><<<GB_MM, 256, 0, stream>>>(xB, W1 + 1 * 65536, al1 + 1 * 256, F1, el1, N_NODES);
    gemm_el<256, 64><<<GB_MM, 256, 0, stream>>>(xA, W1 + 2 * 65536, al1 + 2 * 256, F2, el2, N_NODES);
    gemv_er2<256><<<GB_ROW, 256, 0, stream>>>(xA, wr + 1 * 2048, wr + 2 * 2048, er1, er2, N_NODES);
    seg_att2<1><<<GB_WAVE, 256, 0, stream>>>(el1, er1, off1, F1, el2, er2, off2, F2,
                                             usort, bsA1, hA, N_NODES);

    // ---------------- layer 2 ----------------
    make_wr3<<<3, 256, 0, stream>>>(W2, ar2, wr, 32, 8192);

    // etype0: A -> B (dst B = out[N*D:])
    gemm_el<32, 32><<<GB_MM, 256, 0, stream>>>(hA, W2 + 0 * 8192, al2 + 0 * 256, F1, el0, N_NODES);
    gemv_er<32><<<GB_ROW, 256, 0, stream>>>(hB, wr + 0 * 256, er0, N_NODES);
    seg_att1<0><<<GB_WAVE, 256, 0, stream>>>(el0, er0, off0, usort, F1, bsB2,
                                             out + (size_t)N_NODES * D, N_NODES);

    // etype1: B->A, etype2: A->A (dst A = out[0:N*D])
    gemm_el<32, 32><<<GB_MM, 256, 0, stream>>>(hB, W2 + 1 * 8192, al2 + 1 * 256, F1, el1, N_NODES);
    gemm_el<32, 32><<<GB_MM, 256, 0, stream>>>(hA, W2 + 2 * 8192, al2 + 2 * 256, F2, el2, N_NODES);
    gemv_er2<32><<<GB_ROW, 256, 0, stream>>>(hA, wr + 1 * 256, wr + 2 * 256, er1, er2, N_NODES);
    seg_att2<0><<<GB_WAVE, 256, 0, stream>>>(el1, er1, off1, F1, el2, er2, off2, F2,
                                             usort, bsA2, out, N_NODES);
}

// Round 8
// 609.899 us; speedup vs baseline: 43.1581x; 1.0226x over previous
//
#include <hip/hip_runtime.h>
#include <float.h>

#define NEG_SLOPE 0.2f

constexpr int N_NODES = 20000;
constexpr int NE      = 320000;
constexpr int H       = 8;
constexpr int D       = 32;
constexpr int HD      = 256;   // H*D
constexpr int FIN     = 256;
constexpr int SCAN_NT = 3 * N_NODES;          // 60000
constexpr int SCAN_NB = (SCAN_NT + 511) / 512; // 118

// ============ feature GEMM + fused el epilogue ============
template <int K, int BK>
__global__ __launch_bounds__(256) void gemm_el(
    const float* __restrict__ X, const float* __restrict__ W,
    const float* __restrict__ al, float* __restrict__ C,
    float* __restrict__ el, int M)
{
    constexpr int XS = BK + 8;   // %4==0 (b128 align), ty rows 8 banks apart
    __shared__ float Xs[128][XS];
    __shared__ float Ws[BK][64];
    const int tx = threadIdx.x & 15;
    const int ty = threadIdx.x >> 4;
    const int r0 = blockIdx.x * 128;
    const int c0 = blockIdx.y * 64;
    float4 acc[8];
#pragma unroll
    for (int r = 0; r < 8; r++) acc[r] = make_float4(0.f, 0.f, 0.f, 0.f);

    for (int kc = 0; kc < K; kc += BK) {
        for (int idx = threadIdx.x; idx < 128 * (BK / 4); idx += 256) {
            int row = idx / (BK / 4);
            int kq  = idx % (BK / 4);
            int grow = r0 + row;
            float4 xv = (grow < M) ? *(const float4*)(X + (size_t)grow * K + kc + kq * 4)
                                   : make_float4(0.f, 0.f, 0.f, 0.f);
            *(float4*)&Xs[row][kq * 4] = xv;
        }
        for (int idx = threadIdx.x; idx < BK * 16; idx += 256) {
            int k = idx >> 4, cq = idx & 15;
            *(float4*)&Ws[k][cq * 4] = *(const float4*)(W + (size_t)(kc + k) * 256 + c0 + cq * 4);
        }
        __syncthreads();
#pragma unroll 4
        for (int k = 0; k < BK; k++) {
            float4 wv = *(float4*)&Ws[k][tx * 4];
#pragma unroll
            for (int r = 0; r < 8; r++) {
                float x = Xs[ty + 16 * r][k];
                acc[r].x = fmaf(x, wv.x, acc[r].x);
                acc[r].y = fmaf(x, wv.y, acc[r].y);
                acc[r].z = fmaf(x, wv.z, acc[r].z);
                acc[r].w = fmaf(x, wv.w, acc[r].w);
            }
        }
        __syncthreads();
    }
#pragma unroll
    for (int r = 0; r < 8; r++) {
        int row = r0 + ty + 16 * r;
        if (row < M) *(float4*)(C + (size_t)row * 256 + c0 + tx * 4) = acc[r];
    }
    float a0 = al[c0 + tx * 4 + 0], a1 = al[c0 + tx * 4 + 1];
    float a2 = al[c0 + tx * 4 + 2], a3 = al[c0 + tx * 4 + 3];
#pragma unroll
    for (int r = 0; r < 8; r++) {
        float p = acc[r].x * a0 + acc[r].y * a1 + acc[r].z * a2 + acc[r].w * a3;
        p += __shfl_xor(p, 1, 64);
        p += __shfl_xor(p, 2, 64);
        p += __shfl_xor(p, 4, 64);
        int row = r0 + ty + 16 * r;
        if ((tx & 7) == 0 && row < M)
            el[row * H + 2 * blockIdx.y + (tx >> 3)] = p;
    }
}

// ---- wr[et][k,h] = sum_d W[et][k, h*32+d] * ar[et][h,d], 3 etypes ----
__global__ void make_wr3(const float* __restrict__ W, const float* __restrict__ ar,
                         float* __restrict__ wr, int K, int wstride)
{
    int t = blockIdx.x * blockDim.x + threadIdx.x;
    if (t >= 3 * K * H) return;
    int et = t / (K * H), rem = t % (K * H);
    int k = rem / H, h = rem % H;
    const float* Wp  = W + (size_t)et * wstride + k * HD + h * D;
    const float* arp = ar + et * HD + h * D;
    float s = 0.f;
#pragma unroll
    for (int d = 0; d < D; d++) s += Wp[d] * arp[d];
    wr[t] = s;
}

// ---- er[n,h] = sum_k x[n,k] * wr[k,h] ----
template <int K>
__global__ __launch_bounds__(256) void gemv_er(
    const float* __restrict__ x, const float* __restrict__ wr,
    float* __restrict__ er, int N)
{
    __shared__ float w[K * H];
    for (int i = threadIdx.x; i < K * H; i += 256) w[i] = wr[i];
    __syncthreads();
    int t = blockIdx.x * 256 + threadIdx.x;
    if (t >= N * H) return;
    int n = t >> 3, h = t & 7;
    const float4* xp = (const float4*)(x + (size_t)n * K);
    float s = 0.f;
#pragma unroll 4
    for (int k4 = 0; k4 < K / 4; k4++) {
        float4 xv = xp[k4];
        s += xv.x * w[(4 * k4 + 0) * H + h];
        s += xv.y * w[(4 * k4 + 1) * H + h];
        s += xv.z * w[(4 * k4 + 2) * H + h];
        s += xv.w * w[(4 * k4 + 3) * H + h];
    }
    er[t] = s;
}

// ---- two er vectors from the same x (one x read) ----
template <int K>
__global__ __launch_bounds__(256) void gemv_er2(
    const float* __restrict__ x, const float* __restrict__ wrA,
    const float* __restrict__ wrB, float* __restrict__ erA,
    float* __restrict__ erB, int N)
{
    __shared__ float wa[K * H];
    __shared__ float wb[K * H];
    for (int i = threadIdx.x; i < K * H; i += 256) { wa[i] = wrA[i]; wb[i] = wrB[i]; }
    __syncthreads();
    int t = blockIdx.x * 256 + threadIdx.x;
    if (t >= N * H) return;
    int n = t >> 3, h = t & 7;
    const float4* xp = (const float4*)(x + (size_t)n * K);
    float s1 = 0.f, s2 = 0.f;
#pragma unroll 4
    for (int k4 = 0; k4 < K / 4; k4++) {
        float4 xv = xp[k4];
        s1 += xv.x * wa[(4 * k4 + 0) * H + h] + xv.y * wa[(4 * k4 + 1) * H + h]
            + xv.z * wa[(4 * k4 + 2) * H + h] + xv.w * wa[(4 * k4 + 3) * H + h];
        s2 += xv.x * wb[(4 * k4 + 0) * H + h] + xv.y * wb[(4 * k4 + 1) * H + h]
            + xv.z * wb[(4 * k4 + 2) * H + h] + xv.w * wb[(4 * k4 + 3) * H + h];
    }
    erA[t] = s1; erB[t] = s2;
}

// ---- bias head-sums ----
__global__ void bias_sums(const float* __restrict__ b1, const float* __restrict__ b2,
                          float* __restrict__ bs)
{
    int t = threadIdx.x;            // 128
    int which = t >> 5, d = t & 31;
    const float* b = (which < 2) ? b1 : b2;
    float s = 0.f;
    if (which & 1) {
#pragma unroll
        for (int h = 0; h < H; h++) s += b[0 * 256 + h * D + d];
    } else {
#pragma unroll
        for (int h = 0; h < H; h++) s += b[1 * 256 + h * D + d] + b[2 * 256 + h * D + d];
    }
    bs[t] = s;
}

// ============ CSR build (3 etypes, global offsets) ============

__global__ void hist3(const int* __restrict__ v0, const int* __restrict__ v1,
                      const int* __restrict__ v2, int* __restrict__ cnt)
{
    int t = blockIdx.x * blockDim.x + threadIdx.x;
    if (t >= 3 * NE) return;
    int et = t / NE, i = t - et * NE;
    const int* vp = (et == 0) ? v0 : (et == 1) ? v1 : v2;
    atomicAdd(&cnt[et * N_NODES + vp[i]], 1);
}

__global__ __launch_bounds__(512) void scan_blk(
    const int* __restrict__ cnt, int* __restrict__ loc, int* __restrict__ bsum)
{
    int gid = blockIdx.x * 512 + threadIdx.x;
    int x = (gid < SCAN_NT) ? cnt[gid] : 0;
    int lane = threadIdx.x & 63, w = threadIdx.x >> 6;
    int v = x;
#pragma unroll
    for (int d = 1; d < 64; d <<= 1) {
        int y = __shfl_up(v, d, 64);
        if (lane >= d) v += y;
    }
    __shared__ int wsum[8];
    if (lane == 63) wsum[w] = v;
    __syncthreads();
    if (threadIdx.x == 0) {
        int run = 0;
#pragma unroll
        for (int i = 0; i < 8; i++) { int t2 = wsum[i]; wsum[i] = run; run += t2; }
    }
    __syncthreads();
    int excl = v - x + wsum[w];
    if (gid < SCAN_NT) loc[gid] = excl;
    if (threadIdx.x == 511) bsum[blockIdx.x] = excl + x;
}

__global__ __launch_bounds__(128) void scan_bsum(int* __restrict__ bsum, int nb)
{
    int t = threadIdx.x;
    int x = (t < nb) ? bsum[t] : 0;
    int lane = t & 63, w = t >> 6;
    int v = x;
#pragma unroll
    for (int d = 1; d < 64; d <<= 1) {
        int y = __shfl_up(v, d, 64);
        if (lane >= d) v += y;
    }
    __shared__ int ws2[2];
    if (lane == 63) ws2[w] = v;
    __syncthreads();
    int add = (w == 1) ? ws2[0] : 0;
    if (t < nb) bsum[t] = v + add - x;
}

__global__ __launch_bounds__(512) void scan_add(
    const int* __restrict__ loc, const int* __restrict__ bsum,
    int* __restrict__ off, int* __restrict__ cursor)
{
    int gid = blockIdx.x * 512 + threadIdx.x;
    if (gid < SCAN_NT) {
        int o = loc[gid] + bsum[blockIdx.x];
        off[gid] = o;
        cursor[gid] = o;
    } else if (gid == SCAN_NT) {
        off[gid] = 3 * NE;
    }
}

__global__ void fill3(const int* __restrict__ u0, const int* __restrict__ v0,
                      const int* __restrict__ u1, const int* __restrict__ v1,
                      const int* __restrict__ u2, const int* __restrict__ v2,
                      int* __restrict__ cursor, int* __restrict__ usort)
{
    int t = blockIdx.x * blockDim.x + threadIdx.x;
    if (t >= 3 * NE) return;
    int et = t / NE, i = t - et * NE;
    const int* up = (et == 0) ? u0 : (et == 1) ? u1 : u2;
    const int* vp = (et == 0) ? v0 : (et == 1) ? v1 : v2;
    int pos = atomicAdd(&cursor[et * N_NODES + vp[i]], 1);
    usort[pos] = up[i];
}

// ============ fused single-pass edge softmax + gather + head-mean ============
// one 64-lane wave per dst node v; lane covers cols lane*4..+3 (head=lane>>3).
// 8-wide edge batching: 8 independent Fs-row loads in flight per wave.

__device__ __forceinline__ float lrelu(float e) {
    return (e >= 0.f) ? e : NEG_SLOPE * e;
}

__device__ __forceinline__ float4 seg_accum(
    const float* __restrict__ el, float erh,
    const int* __restrict__ us, int lo, int hi,
    const float* __restrict__ Fs, int lane, int h)
{
    float4 aa = make_float4(0.f, 0.f, 0.f, 0.f);
    float s = 0.f;
    int j = lo;
    for (; j + 8 <= hi; j += 8) {
        int u[8];
#pragma unroll
        for (int q = 0; q < 8; q++) u[q] = us[j + q];
        float4 f[8];
#pragma unroll
        for (int q = 0; q < 8; q++)
            f[q] = *(const float4*)(Fs + (size_t)u[q] * HD + lane * 4);
        float w[8];
#pragma unroll
        for (int q = 0; q < 8; q++)
            w[q] = __expf(lrelu(el[u[q] * H + h] + erh));
#pragma unroll
        for (int q = 0; q < 8; q++) {
            s += w[q];
            aa.x = fmaf(w[q], f[q].x, aa.x);
            aa.y = fmaf(w[q], f[q].y, aa.y);
            aa.z = fmaf(w[q], f[q].z, aa.z);
            aa.w = fmaf(w[q], f[q].w, aa.w);
        }
    }
    for (; j < hi; j++) {
        int u = us[j];
        float4 f = *(const float4*)(Fs + (size_t)u * HD + lane * 4);
        float w = __expf(lrelu(el[u * H + h] + erh));
        s += w;
        aa.x = fmaf(w, f.x, aa.x);
        aa.y = fmaf(w, f.y, aa.y);
        aa.z = fmaf(w, f.z, aa.z);
        aa.w = fmaf(w, f.w, aa.w);
    }
    float inv = (s > 0.f) ? 1.f / s : 0.f;
    aa.x *= inv; aa.y *= inv; aa.z *= inv; aa.w *= inv;
    return aa;
}

template <int RELU>
__global__ __launch_bounds__(256) void seg_att1(
    const float* __restrict__ el, const float* __restrict__ er,
    const int* __restrict__ off, const int* __restrict__ us,
    const float* __restrict__ Fs, const float* __restrict__ bs,
    float* __restrict__ out, int N)
{
    int wid = blockIdx.x * 4 + (threadIdx.x >> 6);
    if (wid >= N) return;
    const int lane = threadIdx.x & 63;
    const int h = lane >> 3;
    const int v = wid;
    float4 aa = seg_accum(el, er[v * H + h], us, off[v], off[v + 1], Fs, lane, h);
#pragma unroll
    for (int mask = 8; mask <= 32; mask <<= 1) {
        aa.x += __shfl_xor(aa.x, mask, 64);
        aa.y += __shfl_xor(aa.y, mask, 64);
        aa.z += __shfl_xor(aa.z, mask, 64);
        aa.w += __shfl_xor(aa.w, mask, 64);
    }
    if (lane < 8) {
        float4 b = *(const float4*)(bs + lane * 4);
        float4 o;
        o.x = (aa.x + b.x) * 0.125f;
        o.y = (aa.y + b.y) * 0.125f;
        o.z = (aa.z + b.z) * 0.125f;
        o.w = (aa.w + b.w) * 0.125f;
        if (RELU) {
            o.x = fmaxf(o.x, 0.f); o.y = fmaxf(o.y, 0.f);
            o.z = fmaxf(o.z, 0.f); o.w = fmaxf(o.w, 0.f);
        }
        *(float4*)(out + (size_t)v * D + lane * 4) = o;
    }
}

template <int RELU>
__global__ __launch_bounds__(256) void seg_att2(
    const float* __restrict__ el1, const float* __restrict__ er1,
    const int* __restrict__ off1, const float* __restrict__ Fs1,
    const float* __restrict__ el2, const float* __restrict__ er2,
    const int* __restrict__ off2, const float* __restrict__ Fs2,
    const int* __restrict__ us, const float* __restrict__ bs,
    float* __restrict__ out, int N)
{
    int wid = blockIdx.x * 4 + (threadIdx.x >> 6);
    if (wid >= N) return;
    const int lane = threadIdx.x & 63;
    const int h = lane >> 3;
    const int v = wid;
    float4 t1 = seg_accum(el1, er1[v * H + h], us, off1[v], off1[v + 1], Fs1, lane, h);
    float4 t2 = seg_accum(el2, er2[v * H + h], us, off2[v], off2[v + 1], Fs2, lane, h);
    float4 tot;
    tot.x = t1.x + t2.x; tot.y = t1.y + t2.y;
    tot.z = t1.z + t2.z; tot.w = t1.w + t2.w;
#pragma unroll
    for (int mask = 8; mask <= 32; mask <<= 1) {
        tot.x += __shfl_xor(tot.x, mask, 64);
        tot.y += __shfl_xor(tot.y, mask, 64);
        tot.z += __shfl_xor(tot.z, mask, 64);
        tot.w += __shfl_xor(tot.w, mask, 64);
    }
    if (lane < 8) {
        float4 b = *(const float4*)(bs + lane * 4);
        float4 o;
        o.x = (tot.x + b.x) * 0.125f;
        o.y = (tot.y + b.y) * 0.125f;
        o.z = (tot.z + b.z) * 0.125f;
        o.w = (tot.w + b.w) * 0.125f;
        if (RELU) {
            o.x = fmaxf(o.x, 0.f); o.y = fmaxf(o.y, 0.f);
            o.z = fmaxf(o.z, 0.f); o.w = fmaxf(o.w, 0.f);
        }
        *(float4*)(out + (size_t)v * D + lane * 4) = o;
    }
}

// ================= host =================

extern "C" void kernel_launch(void* const* d_in, const int* in_sizes, int n_in,
                              void* d_out, int out_size, void* d_ws, size_t ws_size,
                              hipStream_t stream)
{
    const float* xA  = (const float*)d_in[0];
    const float* xB  = (const float*)d_in[1];
    const float* W1  = (const float*)d_in[2];   // [3][256][256]
    const float* al1 = (const float*)d_in[3];   // [3][256]
    const float* ar1 = (const float*)d_in[4];
    const float* b1  = (const float*)d_in[5];   // [3][256]
    const float* W2  = (const float*)d_in[6];   // [3][32][256]
    const float* al2 = (const float*)d_in[7];
    const float* ar2 = (const float*)d_in[8];
    const float* b2  = (const float*)d_in[9];
    const int* u0 = (const int*)d_in[10];
    const int* v0 = (const int*)d_in[11];
    const int* u1 = (const int*)d_in[12];
    const int* v1 = (const int*)d_in[13];
    const int* u2 = (const int*)d_in[14];
    const int* v2 = (const int*)d_in[15];
    float* out = (float*)d_out;

    // workspace layout (floats)
    float* ws = (float*)d_ws;
    const size_t FSZ = (size_t)N_NODES * HD;   // 5.12M floats
    float* F1  = ws;
    float* F2  = F1 + FSZ;
    float* el  = F2 + FSZ;                     // [3][N*H]
    float* er  = el + 3 * N_NODES * H;         // [3][N*H]
    float* hA  = er + 3 * N_NODES * H;         // [N][32]
    float* hB  = hA + (size_t)N_NODES * D;
    float* wr  = hB + (size_t)N_NODES * D;     // [3][256*8] max
    float* bs  = wr + 3 * 2048;                // [4][32]
    int* off    = (int*)(bs + 128);            // 3N+1 (global positions)
    int* cursor = off + 3 * N_NODES + 1;       // 3N
    int* cnt    = cursor + 3 * N_NODES;        // 3N
    int* loc    = cnt + 3 * N_NODES;           // 3N
    int* bsum   = loc + 3 * N_NODES;           // SCAN_NB (<=128)
    int* usort  = bsum + 128;                  // 3NE (concatenated)

    float* el0 = el, *el1 = el + N_NODES * H, *el2 = el + 2 * N_NODES * H;
    float* er0 = er, *er1 = er + N_NODES * H, *er2 = er + 2 * N_NODES * H;
    int* off0 = off, *off1 = off + N_NODES, *off2 = off + 2 * N_NODES;
    float* bsA1 = bs, *bsB1 = bs + 32, *bsA2 = bs + 64, *bsB2 = bs + 96;

    const dim3 GB_MM(157, 4);
    const int GB_ROW  = N_NODES * H / 256;            // 625
    const int GB_WAVE = (N_NODES + 3) / 4;            // 5000
    const int GB_3E   = (3 * NE + 255) / 256;

    // ---- CSR build ----
    hipMemsetAsync(cnt, 0, SCAN_NT * sizeof(int), stream);
    hist3<<<GB_3E, 256, 0, stream>>>(v0, v1, v2, cnt);
    scan_blk<<<SCAN_NB, 512, 0, stream>>>(cnt, loc, bsum);
    scan_bsum<<<1, 128, 0, stream>>>(bsum, SCAN_NB);
    scan_add<<<SCAN_NB, 512, 0, stream>>>(loc, bsum, off, cursor);
    fill3<<<GB_3E, 256, 0, stream>>>(u0, v0, u1, v1, u2, v2, cursor, usort);

    bias_sums<<<1, 128, 0, stream>>>(b1, b2, bs);
    make_wr3<<<24, 256, 0, stream>>>(W1, ar1, wr, 256, 65536);

    // ---------------- layer 1 ----------------
    gemm_el<256, 64><<<GB_MM, 256, 0, stream>>>(xA, W1 + 0 * 65536, al1 + 0 * 256, F1, el0, N_NODES);
    gemv_er<256><<<GB_ROW, 256, 0, stream>>>(xB, wr + 0 * 2048, er0, N_NODES);
    seg_att1<1><<<GB_WAVE, 256, 0, stream>>>(el0, er0, off0, usort, F1, bsB1, hB, N_NODES);

    gemm_el<256, 64><<<GB_MM, 256, 0, stream>>>(xB, W1 + 1 * 65536, al1 + 1 * 256, F1, el1, N_NODES);
    gemm_el<256, 64><<<GB_MM, 256, 0, stream>>>(xA, W1 + 2 * 65536, al1 + 2 * 256, F2, el2, N_NODES);
    gemv_er2<256><<<GB_ROW, 256, 0, stream>>>(xA, wr + 1 * 2048, wr + 2 * 2048, er1, er2, N_NODES);
    seg_att2<1><<<GB_WAVE, 256, 0, stream>>>(el1, er1, off1, F1, el2, er2, off2, F2,
                                             usort, bsA1, hA, N_NODES);

    // ---------------- layer 2 ----------------
    make_wr3<<<3, 256, 0, stream>>>(W2, ar2, wr, 32, 8192);

    gemm_el<32, 32><<<GB_MM, 256, 0, stream>>>(hA, W2 + 0 * 8192, al2 + 0 * 256, F1, el0, N_NODES);
    gemv_er<32><<<GB_ROW, 256, 0, stream>>>(hB, wr + 0 * 256, er0, N_NODES);
    seg_att1<0><<<GB_WAVE, 256, 0, stream>>>(el0, er0, off0, usort, F1, bsB2,
                                             out + (size_t)N_NODES * D, N_NODES);

    gemm_el<32, 32><<<GB_MM, 256, 0, stream>>>(hB, W2 + 1 * 8192, al2 + 1 * 256, F1, el1, N_NODES);
    gemm_el<32, 32><<<GB_MM, 256, 0, stream>>>(hA, W2 + 2 * 8192, al2 + 2 * 256, F2, el2, N_NODES);
    gemv_er2<32><<<GB_ROW, 256, 0, stream>>>(hA, wr + 1 * 256, wr + 2 * 256, er1, er2, N_NODES);
    seg_att2<0><<<GB_WAVE, 256, 0, stream>>>(el1, er1, off1, F1, el2, er2, off2, F2,
                                             usort, bsA2, out, N_NODES);
}

// Round 9
// 481.932 us; speedup vs baseline: 54.6177x; 1.2655x over previous
//
#include <hip/hip_runtime.h>
#include <float.h>

#define NEG_SLOPE 0.2f

constexpr int N_NODES = 20000;
constexpr int NE      = 320000;
constexpr int H       = 8;
constexpr int D       = 32;
constexpr int HD      = 256;   // H*D
constexpr int FIN     = 256;
constexpr int SCAN_NT = 3 * N_NODES;          // 60000
constexpr int SCAN_NB = (SCAN_NT + 511) / 512; // 118

// ---- bf16 helpers (RNE) ----
__device__ __forceinline__ unsigned short f2bf(float x) {
    unsigned u = __float_as_uint(x);
    unsigned r = 0x7FFFu + ((u >> 16) & 1u);
    return (unsigned short)((u + r) >> 16);
}
__device__ __forceinline__ float bf2f(unsigned short h) {
    return __uint_as_float(((unsigned)h) << 16);
}

// ============ feature GEMM + fused el epilogue, bf16 C ============
// Cb[M,256] (bf16) = X[M,K] @ W[K,256]; el[row, 2*by+(0|1)] from fp32 acc.
template <int K, int BK>
__global__ __launch_bounds__(256) void gemm_el(
    const float* __restrict__ X, const float* __restrict__ W,
    const float* __restrict__ al, unsigned short* __restrict__ Cb,
    float* __restrict__ el, int M)
{
    constexpr int XS = BK + 8;   // %4==0 (b128 align), ty rows 8 banks apart
    __shared__ float Xs[128][XS];
    __shared__ float Ws[BK][64];
    const int tx = threadIdx.x & 15;
    const int ty = threadIdx.x >> 4;
    const int r0 = blockIdx.x * 128;
    const int c0 = blockIdx.y * 64;
    float4 acc[8];
#pragma unroll
    for (int r = 0; r < 8; r++) acc[r] = make_float4(0.f, 0.f, 0.f, 0.f);

    for (int kc = 0; kc < K; kc += BK) {
        for (int idx = threadIdx.x; idx < 128 * (BK / 4); idx += 256) {
            int row = idx / (BK / 4);
            int kq  = idx % (BK / 4);
            int grow = r0 + row;
            float4 xv = (grow < M) ? *(const float4*)(X + (size_t)grow * K + kc + kq * 4)
                                   : make_float4(0.f, 0.f, 0.f, 0.f);
            *(float4*)&Xs[row][kq * 4] = xv;
        }
        for (int idx = threadIdx.x; idx < BK * 16; idx += 256) {
            int k = idx >> 4, cq = idx & 15;
            *(float4*)&Ws[k][cq * 4] = *(const float4*)(W + (size_t)(kc + k) * 256 + c0 + cq * 4);
        }
        __syncthreads();
#pragma unroll 4
        for (int k = 0; k < BK; k++) {
            float4 wv = *(float4*)&Ws[k][tx * 4];
#pragma unroll
            for (int r = 0; r < 8; r++) {
                float x = Xs[ty + 16 * r][k];
                acc[r].x = fmaf(x, wv.x, acc[r].x);
                acc[r].y = fmaf(x, wv.y, acc[r].y);
                acc[r].z = fmaf(x, wv.z, acc[r].z);
                acc[r].w = fmaf(x, wv.w, acc[r].w);
            }
        }
        __syncthreads();
    }
#pragma unroll
    for (int r = 0; r < 8; r++) {
        int row = r0 + ty + 16 * r;
        if (row < M) {
            ushort4 cb;
            cb.x = f2bf(acc[r].x); cb.y = f2bf(acc[r].y);
            cb.z = f2bf(acc[r].z); cb.w = f2bf(acc[r].w);
            *(ushort4*)(Cb + (size_t)row * 256 + c0 + tx * 4) = cb;
        }
    }
    float a0 = al[c0 + tx * 4 + 0], a1 = al[c0 + tx * 4 + 1];
    float a2 = al[c0 + tx * 4 + 2], a3 = al[c0 + tx * 4 + 3];
#pragma unroll
    for (int r = 0; r < 8; r++) {
        float p = acc[r].x * a0 + acc[r].y * a1 + acc[r].z * a2 + acc[r].w * a3;
        p += __shfl_xor(p, 1, 64);
        p += __shfl_xor(p, 2, 64);
        p += __shfl_xor(p, 4, 64);
        int row = r0 + ty + 16 * r;
        if ((tx & 7) == 0 && row < M)
            el[row * H + 2 * blockIdx.y + (tx >> 3)] = p;
    }
}

// ---- wr[et][k,h] = sum_d W[et][k, h*32+d] * ar[et][h,d], 3 etypes ----
__global__ void make_wr3(const float* __restrict__ W, const float* __restrict__ ar,
                         float* __restrict__ wr, int K, int wstride)
{
    int t = blockIdx.x * blockDim.x + threadIdx.x;
    if (t >= 3 * K * H) return;
    int et = t / (K * H), rem = t % (K * H);
    int k = rem / H, h = rem % H;
    const float* Wp  = W + (size_t)et * wstride + k * HD + h * D;
    const float* arp = ar + et * HD + h * D;
    float s = 0.f;
#pragma unroll
    for (int d = 0; d < D; d++) s += Wp[d] * arp[d];
    wr[t] = s;
}

// ---- er[n,h] = sum_k x[n,k] * wr[k,h] ----
template <int K>
__global__ __launch_bounds__(256) void gemv_er(
    const float* __restrict__ x, const float* __restrict__ wr,
    float* __restrict__ er, int N)
{
    __shared__ float w[K * H];
    for (int i = threadIdx.x; i < K * H; i += 256) w[i] = wr[i];
    __syncthreads();
    int t = blockIdx.x * 256 + threadIdx.x;
    if (t >= N * H) return;
    int n = t >> 3, h = t & 7;
    const float4* xp = (const float4*)(x + (size_t)n * K);
    float s = 0.f;
#pragma unroll 4
    for (int k4 = 0; k4 < K / 4; k4++) {
        float4 xv = xp[k4];
        s += xv.x * w[(4 * k4 + 0) * H + h];
        s += xv.y * w[(4 * k4 + 1) * H + h];
        s += xv.z * w[(4 * k4 + 2) * H + h];
        s += xv.w * w[(4 * k4 + 3) * H + h];
    }
    er[t] = s;
}

template <int K>
__global__ __launch_bounds__(256) void gemv_er2(
    const float* __restrict__ x, const float* __restrict__ wrA,
    const float* __restrict__ wrB, float* __restrict__ erA,
    float* __restrict__ erB, int N)
{
    __shared__ float wa[K * H];
    __shared__ float wb[K * H];
    for (int i = threadIdx.x; i < K * H; i += 256) { wa[i] = wrA[i]; wb[i] = wrB[i]; }
    __syncthreads();
    int t = blockIdx.x * 256 + threadIdx.x;
    if (t >= N * H) return;
    int n = t >> 3, h = t & 7;
    const float4* xp = (const float4*)(x + (size_t)n * K);
    float s1 = 0.f, s2 = 0.f;
#pragma unroll 4
    for (int k4 = 0; k4 < K / 4; k4++) {
        float4 xv = xp[k4];
        s1 += xv.x * wa[(4 * k4 + 0) * H + h] + xv.y * wa[(4 * k4 + 1) * H + h]
            + xv.z * wa[(4 * k4 + 2) * H + h] + xv.w * wa[(4 * k4 + 3) * H + h];
        s2 += xv.x * wb[(4 * k4 + 0) * H + h] + xv.y * wb[(4 * k4 + 1) * H + h]
            + xv.z * wb[(4 * k4 + 2) * H + h] + xv.w * wb[(4 * k4 + 3) * H + h];
    }
    erA[t] = s1; erB[t] = s2;
}

// ---- bias head-sums ----
__global__ void bias_sums(const float* __restrict__ b1, const float* __restrict__ b2,
                          float* __restrict__ bs)
{
    int t = threadIdx.x;            // 128
    int which = t >> 5, d = t & 31;
    const float* b = (which < 2) ? b1 : b2;
    float s = 0.f;
    if (which & 1) {
#pragma unroll
        for (int h = 0; h < H; h++) s += b[0 * 256 + h * D + d];
    } else {
#pragma unroll
        for (int h = 0; h < H; h++) s += b[1 * 256 + h * D + d] + b[2 * 256 + h * D + d];
    }
    bs[t] = s;
}

// ============ CSR build ============

__global__ void hist3(const int* __restrict__ v0, const int* __restrict__ v1,
                      const int* __restrict__ v2, int* __restrict__ cnt)
{
    int t = blockIdx.x * blockDim.x + threadIdx.x;
    if (t >= 3 * NE) return;
    int et = t / NE, i = t - et * NE;
    const int* vp = (et == 0) ? v0 : (et == 1) ? v1 : v2;
    atomicAdd(&cnt[et * N_NODES + vp[i]], 1);
}

__global__ __launch_bounds__(512) void scan_blk(
    const int* __restrict__ cnt, int* __restrict__ loc, int* __restrict__ bsum)
{
    int gid = blockIdx.x * 512 + threadIdx.x;
    int x = (gid < SCAN_NT) ? cnt[gid] : 0;
    int lane = threadIdx.x & 63, w = threadIdx.x >> 6;
    int v = x;
#pragma unroll
    for (int d = 1; d < 64; d <<= 1) {
        int y = __shfl_up(v, d, 64);
        if (lane >= d) v += y;
    }
    __shared__ int wsum[8];
    if (lane == 63) wsum[w] = v;
    __syncthreads();
    if (threadIdx.x == 0) {
        int run = 0;
#pragma unroll
        for (int i = 0; i < 8; i++) { int t2 = wsum[i]; wsum[i] = run; run += t2; }
    }
    __syncthreads();
    int excl = v - x + wsum[w];
    if (gid < SCAN_NT) loc[gid] = excl;
    if (threadIdx.x == 511) bsum[blockIdx.x] = excl + x;
}

__global__ __launch_bounds__(128) void scan_bsum(int* __restrict__ bsum, int nb)
{
    int t = threadIdx.x;
    int x = (t < nb) ? bsum[t] : 0;
    int lane = t & 63, w = t >> 6;
    int v = x;
#pragma unroll
    for (int d = 1; d < 64; d <<= 1) {
        int y = __shfl_up(v, d, 64);
        if (lane >= d) v += y;
    }
    __shared__ int ws2[2];
    if (lane == 63) ws2[w] = v;
    __syncthreads();
    int add = (w == 1) ? ws2[0] : 0;
    if (t < nb) bsum[t] = v + add - x;
}

__global__ __launch_bounds__(512) void scan_add(
    const int* __restrict__ loc, const int* __restrict__ bsum,
    int* __restrict__ off, int* __restrict__ cursor)
{
    int gid = blockIdx.x * 512 + threadIdx.x;
    if (gid < SCAN_NT) {
        int o = loc[gid] + bsum[blockIdx.x];
        off[gid] = o;
        cursor[gid] = o;
    } else if (gid == SCAN_NT) {
        off[gid] = 3 * NE;
    }
}

__global__ void fill3(const int* __restrict__ u0, const int* __restrict__ v0,
                      const int* __restrict__ u1, const int* __restrict__ v1,
                      const int* __restrict__ u2, const int* __restrict__ v2,
                      int* __restrict__ cursor, int* __restrict__ usort)
{
    int t = blockIdx.x * blockDim.x + threadIdx.x;
    if (t >= 3 * NE) return;
    int et = t / NE, i = t - et * NE;
    const int* up = (et == 0) ? u0 : (et == 1) ? u1 : u2;
    const int* vp = (et == 0) ? v0 : (et == 1) ? v1 : v2;
    int pos = atomicAdd(&cursor[et * N_NODES + vp[i]], 1);
    usort[pos] = up[i];
}

// ============ fused edge softmax + gather + head-mean (bf16 F) ============

__device__ __forceinline__ float lrelu(float e) {
    return (e >= 0.f) ? e : NEG_SLOPE * e;
}

__device__ __forceinline__ float4 seg_accum(
    const float* __restrict__ el, float erh,
    const int* __restrict__ us, int lo, int hi,
    const unsigned short* __restrict__ Fs, int lane, int h)
{
    float4 aa = make_float4(0.f, 0.f, 0.f, 0.f);
    float s = 0.f;
    int j = lo;
    for (; j + 8 <= hi; j += 8) {
        int u[8];
#pragma unroll
        for (int q = 0; q < 8; q++) u[q] = us[j + q];
        ushort4 fb[8];
#pragma unroll
        for (int q = 0; q < 8; q++)
            fb[q] = *(const ushort4*)(Fs + (size_t)u[q] * HD + lane * 4);
        float w[8];
#pragma unroll
        for (int q = 0; q < 8; q++)
            w[q] = __expf(lrelu(el[u[q] * H + h] + erh));
#pragma unroll
        for (int q = 0; q < 8; q++) {
            s += w[q];
            aa.x = fmaf(w[q], bf2f(fb[q].x), aa.x);
            aa.y = fmaf(w[q], bf2f(fb[q].y), aa.y);
            aa.z = fmaf(w[q], bf2f(fb[q].z), aa.z);
            aa.w = fmaf(w[q], bf2f(fb[q].w), aa.w);
        }
    }
    for (; j < hi; j++) {
        int u = us[j];
        ushort4 fb = *(const ushort4*)(Fs + (size_t)u * HD + lane * 4);
        float w = __expf(lrelu(el[u * H + h] + erh));
        s += w;
        aa.x = fmaf(w, bf2f(fb.x), aa.x);
        aa.y = fmaf(w, bf2f(fb.y), aa.y);
        aa.z = fmaf(w, bf2f(fb.z), aa.z);
        aa.w = fmaf(w, bf2f(fb.w), aa.w);
    }
    float inv = (s > 0.f) ? 1.f / s : 0.f;
    aa.x *= inv; aa.y *= inv; aa.z *= inv; aa.w *= inv;
    return aa;
}

// merged per-layer gather: waves [0,N) -> dst B (etype0); waves [N,2N) -> dst A (etype1+2)
template <int RELU>
__global__ __launch_bounds__(256) void seg_att_all(
    const float* __restrict__ el0, const float* __restrict__ er0,
    const int* __restrict__ off0, const unsigned short* __restrict__ F0,
    const float* __restrict__ el1, const float* __restrict__ er1,
    const int* __restrict__ off1, const unsigned short* __restrict__ F1,
    const float* __restrict__ el2, const float* __restrict__ er2,
    const int* __restrict__ off2, const unsigned short* __restrict__ F2,
    const int* __restrict__ us, const float* __restrict__ bsB,
    const float* __restrict__ bsA, float* __restrict__ outB,
    float* __restrict__ outA, int N)
{
    int wid = blockIdx.x * 4 + (threadIdx.x >> 6);
    if (wid >= 2 * N) return;
    const int lane = threadIdx.x & 63;
    const int h = lane >> 3;
    float4 tot;
    const float* bs;
    float* out;
    int v;
    if (wid < N) {
        v = wid;
        tot = seg_accum(el0, er0[v * H + h], us, off0[v], off0[v + 1], F0, lane, h);
        bs = bsB; out = outB;
    } else {
        v = wid - N;
        float4 t1 = seg_accum(el1, er1[v * H + h], us, off1[v], off1[v + 1], F1, lane, h);
        float4 t2 = seg_accum(el2, er2[v * H + h], us, off2[v], off2[v + 1], F2, lane, h);
        tot.x = t1.x + t2.x; tot.y = t1.y + t2.y;
        tot.z = t1.z + t2.z; tot.w = t1.w + t2.w;
        bs = bsA; out = outA;
    }
#pragma unroll
    for (int mask = 8; mask <= 32; mask <<= 1) {
        tot.x += __shfl_xor(tot.x, mask, 64);
        tot.y += __shfl_xor(tot.y, mask, 64);
        tot.z += __shfl_xor(tot.z, mask, 64);
        tot.w += __shfl_xor(tot.w, mask, 64);
    }
    if (lane < 8) {
        float4 b = *(const float4*)(bs + lane * 4);
        float4 o;
        o.x = (tot.x + b.x) * 0.125f;
        o.y = (tot.y + b.y) * 0.125f;
        o.z = (tot.z + b.z) * 0.125f;
        o.w = (tot.w + b.w) * 0.125f;
        if (RELU) {
            o.x = fmaxf(o.x, 0.f); o.y = fmaxf(o.y, 0.f);
            o.z = fmaxf(o.z, 0.f); o.w = fmaxf(o.w, 0.f);
        }
        *(float4*)(out + (size_t)v * D + lane * 4) = o;
    }
}

// ================= host =================

extern "C" void kernel_launch(void* const* d_in, const int* in_sizes, int n_in,
                              void* d_out, int out_size, void* d_ws, size_t ws_size,
                              hipStream_t stream)
{
    const float* xA  = (const float*)d_in[0];
    const float* xB  = (const float*)d_in[1];
    const float* W1  = (const float*)d_in[2];   // [3][256][256]
    const float* al1 = (const float*)d_in[3];   // [3][256]
    const float* ar1 = (const float*)d_in[4];
    const float* b1  = (const float*)d_in[5];   // [3][256]
    const float* W2  = (const float*)d_in[6];   // [3][32][256]
    const float* al2 = (const float*)d_in[7];
    const float* ar2 = (const float*)d_in[8];
    const float* b2  = (const float*)d_in[9];
    const int* u0 = (const int*)d_in[10];
    const int* v0 = (const int*)d_in[11];
    const int* u1 = (const int*)d_in[12];
    const int* v1 = (const int*)d_in[13];
    const int* u2 = (const int*)d_in[14];
    const int* v2 = (const int*)d_in[15];
    float* out = (float*)d_out;

    // workspace layout
    float* ws = (float*)d_ws;
    const size_t FSZ = (size_t)N_NODES * HD;       // 5.12M elements
    unsigned short* F0b = (unsigned short*)ws;     // bf16 tables
    unsigned short* F1b = F0b + FSZ;
    unsigned short* F2b = F1b + FSZ;
    float* el  = (float*)(F2b + FSZ);              // [3][N*H]
    float* er  = el + 3 * N_NODES * H;
    float* hA  = er + 3 * N_NODES * H;             // [N][32] fp32
    float* hB  = hA + (size_t)N_NODES * D;
    float* wr  = hB + (size_t)N_NODES * D;         // [3][2048] max
    float* bs  = wr + 3 * 2048;                    // [4][32]
    int* off    = (int*)(bs + 128);                // 3N+1
    int* cursor = off + 3 * N_NODES + 1;
    int* cnt    = cursor + 3 * N_NODES;
    int* loc    = cnt + 3 * N_NODES;
    int* bsum   = loc + 3 * N_NODES;
    int* usort  = bsum + 128;                      // 3NE

    float* el0 = el, *el1 = el + N_NODES * H, *el2 = el + 2 * N_NODES * H;
    float* er0 = er, *er1 = er + N_NODES * H, *er2 = er + 2 * N_NODES * H;
    int* off0 = off, *off1 = off + N_NODES, *off2 = off + 2 * N_NODES;
    float* bsA1 = bs, *bsB1 = bs + 32, *bsA2 = bs + 64, *bsB2 = bs + 96;

    const dim3 GB_MM(157, 4);
    const int GB_ROW  = N_NODES * H / 256;            // 625
    const int GB_ALL  = (2 * N_NODES + 3) / 4;        // 10000
    const int GB_3E   = (3 * NE + 255) / 256;

    // ---- CSR build ----
    hipMemsetAsync(cnt, 0, SCAN_NT * sizeof(int), stream);
    hist3<<<GB_3E, 256, 0, stream>>>(v0, v1, v2, cnt);
    scan_blk<<<SCAN_NB, 512, 0, stream>>>(cnt, loc, bsum);
    scan_bsum<<<1, 128, 0, stream>>>(bsum, SCAN_NB);
    scan_add<<<SCAN_NB, 512, 0, stream>>>(loc, bsum, off, cursor);
    fill3<<<GB_3E, 256, 0, stream>>>(u0, v0, u1, v1, u2, v2, cursor, usort);

    bias_sums<<<1, 128, 0, stream>>>(b1, b2, bs);
    make_wr3<<<24, 256, 0, stream>>>(W1, ar1, wr, 256, 65536);

    // ---------------- layer 1 ----------------
    gemm_el<256, 64><<<GB_MM, 256, 0, stream>>>(xA, W1 + 0 * 65536, al1 + 0 * 256, F0b, el0, N_NODES);
    gemm_el<256, 64><<<GB_MM, 256, 0, stream>>>(xB, W1 + 1 * 65536, al1 + 1 * 256, F1b, el1, N_NODES);
    gemm_el<256, 64><<<GB_MM, 256, 0, stream>>>(xA, W1 + 2 * 65536, al1 + 2 * 256, F2b, el2, N_NODES);
    gemv_er<256><<<GB_ROW, 256, 0, stream>>>(xB, wr + 0 * 2048, er0, N_NODES);
    gemv_er2<256><<<GB_ROW, 256, 0, stream>>>(xA, wr + 1 * 2048, wr + 2 * 2048, er1, er2, N_NODES);
    seg_att_all<1><<<GB_ALL, 256, 0, stream>>>(el0, er0, off0, F0b,
                                               el1, er1, off1, F1b,
                                               el2, er2, off2, F2b,
                                               usort, bsB1, bsA1, hB, hA, N_NODES);

    // ---------------- layer 2 ----------------
    make_wr3<<<3, 256, 0, stream>>>(W2, ar2, wr, 32, 8192);

    gemm_el<32, 32><<<GB_MM, 256, 0, stream>>>(hA, W2 + 0 * 8192, al2 + 0 * 256, F0b, el0, N_NODES);
    gemm_el<32, 32><<<GB_MM, 256, 0, stream>>>(hB, W2 + 1 * 8192, al2 + 1 * 256, F1b, el1, N_NODES);
    gemm_el<32, 32><<<GB_MM, 256, 0, stream>>>(hA, W2 + 2 * 8192, al2 + 2 * 256, F2b, el2, N_NODES);
    gemv_er<32><<<GB_ROW, 256, 0, stream>>>(hB, wr + 0 * 256, er0, N_NODES);
    gemv_er2<32><<<GB_ROW, 256, 0, stream>>>(hA, wr + 1 * 256, wr + 2 * 256, er1, er2, N_NODES);
    seg_att_all<0><<<GB_ALL, 256, 0, stream>>>(el0, er0, off0, F0b,
                                               el1, er1, off1, F1b,
                                               el2, er2, off2, F2b,
                                               usort, bsB2, bsA2,
                                               out + (size_t)N_NODES * D, out, N_NODES);
}

// Round 10
// 468.701 us; speedup vs baseline: 56.1596x; 1.0282x over previous
//
#include <hip/hip_runtime.h>
#include <float.h>

#define NEG_SLOPE 0.2f

constexpr int N_NODES = 20000;
constexpr int NE      = 320000;
constexpr int H       = 8;
constexpr int D       = 32;
constexpr int HD      = 256;   // H*D
constexpr int FIN     = 256;
constexpr int SCAN_NT = 3 * N_NODES;           // 60000
constexpr int SCAN_NB = (SCAN_NT + 511) / 512; // 118

typedef __attribute__((ext_vector_type(8))) short bf16x8;
typedef __attribute__((ext_vector_type(4))) float f32x4;

// ---- bf16 helpers (RNE) ----
__device__ __forceinline__ unsigned short f2bf(float x) {
    unsigned u = __float_as_uint(x);
    unsigned r = 0x7FFFu + ((u >> 16) & 1u);
    return (unsigned short)((u + r) >> 16);
}
__device__ __forceinline__ float bf2f(unsigned short h) {
    return __uint_as_float(((unsigned)h) << 16);
}

// ---- fp32 -> bf16 conversion (n multiple of 4) ----
__global__ __launch_bounds__(256) void cvt_bf16(
    const float* __restrict__ in, unsigned short* __restrict__ out, int n)
{
    int t = (blockIdx.x * 256 + threadIdx.x) * 4;
    if (t >= n) return;
    float4 v = *(const float4*)(in + t);
    ushort4 o;
    o.x = f2bf(v.x); o.y = f2bf(v.y); o.z = f2bf(v.z); o.w = f2bf(v.w);
    *(ushort4*)(out + t) = o;
}

// ============ MFMA GEMM: F[M,256](bf16) = Xb[M,256](bf16) @ Wb[256,256](bf16) ============
// tile 128x64, BK=32, 4 waves; wave w: rows [w*32, w*32+32). fp32 accumulate.
__global__ __launch_bounds__(256) void mfma_gemm(
    const unsigned short* __restrict__ Xb, const unsigned short* __restrict__ Wb,
    unsigned short* __restrict__ F, int M)
{
    __shared__ unsigned short Xs[128][40];   // pad 40: b128 reads 2-way max
    __shared__ unsigned short WsT[64][40];   // W transposed: WsT[n][k]
    const int tid = threadIdx.x;
    const int wid = tid >> 6, lane = tid & 63;
    const int r0 = blockIdx.x * 128;
    const int c0 = blockIdx.y * 64;
    const int l15 = lane & 15, lg = lane >> 4;

    f32x4 acc[2][4];
#pragma unroll
    for (int i = 0; i < 2; i++)
#pragma unroll
        for (int j = 0; j < 4; j++) acc[i][j] = (f32x4){0.f, 0.f, 0.f, 0.f};

    for (int kc = 0; kc < FIN; kc += 32) {
        // stage X tile: 128 rows x 32 bf16 (4x 16B groups per row)
        for (int i = tid; i < 128 * 4; i += 256) {
            int row = i >> 2, q = i & 3;
            int grow = r0 + row;
            int4 xv = (grow < M) ? *(const int4*)(Xb + (size_t)grow * FIN + kc + q * 8)
                                 : make_int4(0, 0, 0, 0);
            *(int4*)&Xs[row][q * 8] = xv;
        }
        // stage W tile transposed: 32 k x 64 n  (thread: one k, 8 n)
        {
            int k = tid >> 3, n8 = (tid & 7) * 8;
            int4 wv = *(const int4*)(Wb + (size_t)(kc + k) * 256 + c0 + n8);
            const unsigned short* wp = (const unsigned short*)&wv;
#pragma unroll
            for (int j = 0; j < 8; j++) WsT[n8 + j][k] = wp[j];
        }
        __syncthreads();
        const int rm = wid * 32;
        bf16x8 a0 = *(const bf16x8*)&Xs[rm + l15][lg * 8];
        bf16x8 a1 = *(const bf16x8*)&Xs[rm + 16 + l15][lg * 8];
#pragma unroll
        for (int j = 0; j < 4; j++) {
            bf16x8 b = *(const bf16x8*)&WsT[j * 16 + l15][lg * 8];
            acc[0][j] = __builtin_amdgcn_mfma_f32_16x16x32_bf16(a0, b, acc[0][j], 0, 0, 0);
            acc[1][j] = __builtin_amdgcn_mfma_f32_16x16x32_bf16(a1, b, acc[1][j], 0, 0, 0);
        }
        __syncthreads();
    }
    // C store: row=(lane>>4)*4+r (within 16), col=lane&15
    const int rm = wid * 32;
#pragma unroll
    for (int i = 0; i < 2; i++)
#pragma unroll
        for (int j = 0; j < 4; j++)
#pragma unroll
            for (int r = 0; r < 4; r++) {
                int row = r0 + rm + i * 16 + lg * 4 + r;
                if (row < M)
                    F[(size_t)row * 256 + c0 + j * 16 + l15] = f2bf(acc[i][j][r]);
            }
}

// ============ layer-2 vector GEMM: F[M,256](bf16) = X[M,32] @ W[32,256] ============
__global__ __launch_bounds__(256) void gemm32(
    const float* __restrict__ X, const float* __restrict__ W,
    unsigned short* __restrict__ F, int M)
{
    __shared__ float Xs[128][40];
    __shared__ float Ws[32][64];
    const int tx = threadIdx.x & 15;
    const int ty = threadIdx.x >> 4;
    const int r0 = blockIdx.x * 128;
    const int c0 = blockIdx.y * 64;
    for (int idx = threadIdx.x; idx < 128 * 8; idx += 256) {
        int row = idx >> 3, kq = idx & 7;
        int grow = r0 + row;
        float4 xv = (grow < M) ? *(const float4*)(X + (size_t)grow * 32 + kq * 4)
                               : make_float4(0.f, 0.f, 0.f, 0.f);
        *(float4*)&Xs[row][kq * 4] = xv;
    }
    for (int idx = threadIdx.x; idx < 32 * 16; idx += 256) {
        int k = idx >> 4, cq = idx & 15;
        *(float4*)&Ws[k][cq * 4] = *(const float4*)(W + (size_t)k * 256 + c0 + cq * 4);
    }
    __syncthreads();
    float4 acc[8];
#pragma unroll
    for (int r = 0; r < 8; r++) acc[r] = make_float4(0.f, 0.f, 0.f, 0.f);
#pragma unroll 4
    for (int k = 0; k < 32; k++) {
        float4 wv = *(float4*)&Ws[k][tx * 4];
#pragma unroll
        for (int r = 0; r < 8; r++) {
            float x = Xs[ty + 16 * r][k];
            acc[r].x = fmaf(x, wv.x, acc[r].x);
            acc[r].y = fmaf(x, wv.y, acc[r].y);
            acc[r].z = fmaf(x, wv.z, acc[r].z);
            acc[r].w = fmaf(x, wv.w, acc[r].w);
        }
    }
#pragma unroll
    for (int r = 0; r < 8; r++) {
        int row = r0 + ty + 16 * r;
        if (row < M) {
            ushort4 cb;
            cb.x = f2bf(acc[r].x); cb.y = f2bf(acc[r].y);
            cb.z = f2bf(acc[r].z); cb.w = f2bf(acc[r].w);
            *(ushort4*)(F + (size_t)row * 256 + c0 + tx * 4) = cb;
        }
    }
}

// ---- wlr[half][et][k][h]: half0 = W·al, half1 = W·ar ----
__global__ void make_wlr3(const float* __restrict__ W, const float* __restrict__ al,
                          const float* __restrict__ ar, float* __restrict__ wlr,
                          int K, int wstride)
{
    int t = blockIdx.x * blockDim.x + threadIdx.x;
    if (t >= 6 * K * H) return;
    int half = t / (3 * K * H);
    int rem  = t % (3 * K * H);
    int et = rem / (K * H);
    int rem2 = rem % (K * H);
    int k = rem2 / H, h = rem2 % H;
    const float* av = (half ? ar : al) + et * HD + h * D;
    const float* Wp = W + (size_t)et * wstride + k * HD + h * D;
    float s = 0.f;
#pragma unroll
    for (int d = 0; d < D; d++) s += Wp[d] * av[d];
    wlr[t] = s;
}

// ---- 4 GEMVs from one x read: o_m[n,h] = sum_k x[n,k]*w_m[k*H+h] ----
template <int K>
__global__ __launch_bounds__(256) void gemv4(
    const float* __restrict__ x,
    const float* __restrict__ w0, const float* __restrict__ w1,
    const float* __restrict__ w2, const float* __restrict__ w3,
    float* __restrict__ o0, float* __restrict__ o1,
    float* __restrict__ o2, float* __restrict__ o3, int N)
{
    __shared__ float w[4][K * H];
    for (int i = threadIdx.x; i < K * H; i += 256) {
        w[0][i] = w0[i]; w[1][i] = w1[i]; w[2][i] = w2[i]; w[3][i] = w3[i];
    }
    __syncthreads();
    int t = blockIdx.x * 256 + threadIdx.x;
    if (t >= N * H) return;
    int n = t >> 3, h = t & 7;
    const float4* xp = (const float4*)(x + (size_t)n * K);
    float s0 = 0.f, s1 = 0.f, s2 = 0.f, s3 = 0.f;
#pragma unroll 2
    for (int k4 = 0; k4 < K / 4; k4++) {
        float4 xv = xp[k4];
        const float* xe = &xv.x;
#pragma unroll
        for (int e = 0; e < 4; e++) {
            int idx = (4 * k4 + e) * H + h;
            float xx = xe[e];
            s0 = fmaf(xx, w[0][idx], s0);
            s1 = fmaf(xx, w[1][idx], s1);
            s2 = fmaf(xx, w[2][idx], s2);
            s3 = fmaf(xx, w[3][idx], s3);
        }
    }
    o0[t] = s0; o1[t] = s1; o2[t] = s2; o3[t] = s3;
}

template <int K>
__global__ __launch_bounds__(256) void gemv2(
    const float* __restrict__ x,
    const float* __restrict__ w0, const float* __restrict__ w1,
    float* __restrict__ o0, float* __restrict__ o1, int N)
{
    __shared__ float w[2][K * H];
    for (int i = threadIdx.x; i < K * H; i += 256) { w[0][i] = w0[i]; w[1][i] = w1[i]; }
    __syncthreads();
    int t = blockIdx.x * 256 + threadIdx.x;
    if (t >= N * H) return;
    int n = t >> 3, h = t & 7;
    const float4* xp = (const float4*)(x + (size_t)n * K);
    float s0 = 0.f, s1 = 0.f;
#pragma unroll 2
    for (int k4 = 0; k4 < K / 4; k4++) {
        float4 xv = xp[k4];
        const float* xe = &xv.x;
#pragma unroll
        for (int e = 0; e < 4; e++) {
            int idx = (4 * k4 + e) * H + h;
            float xx = xe[e];
            s0 = fmaf(xx, w[0][idx], s0);
            s1 = fmaf(xx, w[1][idx], s1);
        }
    }
    o0[t] = s0; o1[t] = s1;
}

// ---- bias head-sums ----
__global__ void bias_sums(const float* __restrict__ b1, const float* __restrict__ b2,
                          float* __restrict__ bs)
{
    int t = threadIdx.x;            // 128
    int which = t >> 5, d = t & 31;
    const float* b = (which < 2) ? b1 : b2;
    float s = 0.f;
    if (which & 1) {
#pragma unroll
        for (int h = 0; h < H; h++) s += b[0 * 256 + h * D + d];
    } else {
#pragma unroll
        for (int h = 0; h < H; h++) s += b[1 * 256 + h * D + d] + b[2 * 256 + h * D + d];
    }
    bs[t] = s;
}

// ============ CSR build ============

__global__ void hist3(const int* __restrict__ v0, const int* __restrict__ v1,
                      const int* __restrict__ v2, int* __restrict__ cnt)
{
    int t = blockIdx.x * blockDim.x + threadIdx.x;
    if (t >= 3 * NE) return;
    int et = t / NE, i = t - et * NE;
    const int* vp = (et == 0) ? v0 : (et == 1) ? v1 : v2;
    atomicAdd(&cnt[et * N_NODES + vp[i]], 1);
}

__global__ __launch_bounds__(512) void scan_blk(
    const int* __restrict__ cnt, int* __restrict__ loc, int* __restrict__ bsum)
{
    int gid = blockIdx.x * 512 + threadIdx.x;
    int x = (gid < SCAN_NT) ? cnt[gid] : 0;
    int lane = threadIdx.x & 63, w = threadIdx.x >> 6;
    int v = x;
#pragma unroll
    for (int d = 1; d < 64; d <<= 1) {
        int y = __shfl_up(v, d, 64);
        if (lane >= d) v += y;
    }
    __shared__ int wsum[8];
    if (lane == 63) wsum[w] = v;
    __syncthreads();
    if (threadIdx.x == 0) {
        int run = 0;
#pragma unroll
        for (int i = 0; i < 8; i++) { int t2 = wsum[i]; wsum[i] = run; run += t2; }
    }
    __syncthreads();
    int excl = v - x + wsum[w];
    if (gid < SCAN_NT) loc[gid] = excl;
    if (threadIdx.x == 511) bsum[blockIdx.x] = excl + x;
}

__global__ __launch_bounds__(128) void scan_bsum(int* __restrict__ bsum, int nb)
{
    int t = threadIdx.x;
    int x = (t < nb) ? bsum[t] : 0;
    int lane = t & 63, w = t >> 6;
    int v = x;
#pragma unroll
    for (int d = 1; d < 64; d <<= 1) {
        int y = __shfl_up(v, d, 64);
        if (lane >= d) v += y;
    }
    __shared__ int ws2[2];
    if (lane == 63) ws2[w] = v;
    __syncthreads();
    int add = (w == 1) ? ws2[0] : 0;
    if (t < nb) bsum[t] = v + add - x;
}

__global__ __launch_bounds__(512) void scan_add(
    const int* __restrict__ loc, const int* __restrict__ bsum,
    int* __restrict__ off, int* __restrict__ cursor)
{
    int gid = blockIdx.x * 512 + threadIdx.x;
    if (gid < SCAN_NT) {
        int o = loc[gid] + bsum[blockIdx.x];
        off[gid] = o;
        cursor[gid] = o;
    } else if (gid == SCAN_NT) {
        off[gid] = 3 * NE;
    }
}

__global__ void fill3(const int* __restrict__ u0, const int* __restrict__ v0,
                      const int* __restrict__ u1, const int* __restrict__ v1,
                      const int* __restrict__ u2, const int* __restrict__ v2,
                      int* __restrict__ cursor, int* __restrict__ usort)
{
    int t = blockIdx.x * blockDim.x + threadIdx.x;
    if (t >= 3 * NE) return;
    int et = t / NE, i = t - et * NE;
    const int* up = (et == 0) ? u0 : (et == 1) ? u1 : u2;
    const int* vp = (et == 0) ? v0 : (et == 1) ? v1 : v2;
    int pos = atomicAdd(&cursor[et * N_NODES + vp[i]], 1);
    usort[pos] = up[i];
}

// ============ fused edge softmax + gather + head-mean (bf16 F, masked 8-wide) ============

__device__ __forceinline__ float lrelu(float e) {
    return (e >= 0.f) ? e : NEG_SLOPE * e;
}

__device__ __forceinline__ float4 seg_accum(
    const float* __restrict__ el, float erh,
    const int* __restrict__ us, int lo, int hi,
    const unsigned short* __restrict__ Fs, int lane, int h)
{
    float4 aa = make_float4(0.f, 0.f, 0.f, 0.f);
    if (lo >= hi) return aa;
    float s = 0.f;
    for (int j = lo; j < hi; j += 8) {
        int u[8];
#pragma unroll
        for (int q = 0; q < 8; q++) u[q] = us[(j + q < hi) ? j + q : hi - 1];
        ushort4 fb[8];
#pragma unroll
        for (int q = 0; q < 8; q++)
            fb[q] = *(const ushort4*)(Fs + ((size_t)u[q] << 8) + lane * 4);
        float wv[8];
#pragma unroll
        for (int q = 0; q < 8; q++) {
            float e = el[u[q] * H + h] + erh;
            wv[q] = (j + q < hi) ? __expf(lrelu(e)) : 0.f;
        }
#pragma unroll
        for (int q = 0; q < 8; q++) {
            s += wv[q];
            aa.x = fmaf(wv[q], bf2f(fb[q].x), aa.x);
            aa.y = fmaf(wv[q], bf2f(fb[q].y), aa.y);
            aa.z = fmaf(wv[q], bf2f(fb[q].z), aa.z);
            aa.w = fmaf(wv[q], bf2f(fb[q].w), aa.w);
        }
    }
    float inv = (s > 0.f) ? 1.f / s : 0.f;
    aa.x *= inv; aa.y *= inv; aa.z *= inv; aa.w *= inv;
    return aa;
}

template <int RELU>
__global__ __launch_bounds__(256) void seg_att_all(
    const float* __restrict__ el0, const float* __restrict__ er0,
    const int* __restrict__ off0, const unsigned short* __restrict__ F0,
    const float* __restrict__ el1, const float* __restrict__ er1,
    const int* __restrict__ off1, const unsigned short* __restrict__ F1,
    const float* __restrict__ el2, const float* __restrict__ er2,
    const int* __restrict__ off2, const unsigned short* __restrict__ F2,
    const int* __restrict__ us, const float* __restrict__ bsB,
    const float* __restrict__ bsA, float* __restrict__ outB,
    float* __restrict__ outA, int N)
{
    int wid = blockIdx.x * 4 + (threadIdx.x >> 6);
    if (wid >= 2 * N) return;
    const int lane = threadIdx.x & 63;
    const int h = lane >> 3;
    float4 tot;
    const float* bs;
    float* out;
    int v;
    if (wid < N) {
        v = wid;
        tot = seg_accum(el0, er0[v * H + h], us, off0[v], off0[v + 1], F0, lane, h);
        bs = bsB; out = outB;
    } else {
        v = wid - N;
        float4 t1 = seg_accum(el1, er1[v * H + h], us, off1[v], off1[v + 1], F1, lane, h);
        float4 t2 = seg_accum(el2, er2[v * H + h], us, off2[v], off2[v + 1], F2, lane, h);
        tot.x = t1.x + t2.x; tot.y = t1.y + t2.y;
        tot.z = t1.z + t2.z; tot.w = t1.w + t2.w;
        bs = bsA; out = outA;
    }
#pragma unroll
    for (int mask = 8; mask <= 32; mask <<= 1) {
        tot.x += __shfl_xor(tot.x, mask, 64);
        tot.y += __shfl_xor(tot.y, mask, 64);
        tot.z += __shfl_xor(tot.z, mask, 64);
        tot.w += __shfl_xor(tot.w, mask, 64);
    }
    if (lane < 8) {
        float4 b = *(const float4*)(bs + lane * 4);
        float4 o;
        o.x = (tot.x + b.x) * 0.125f;
        o.y = (tot.y + b.y) * 0.125f;
        o.z = (tot.z + b.z) * 0.125f;
        o.w = (tot.w + b.w) * 0.125f;
        if (RELU) {
            o.x = fmaxf(o.x, 0.f); o.y = fmaxf(o.y, 0.f);
            o.z = fmaxf(o.z, 0.f); o.w = fmaxf(o.w, 0.f);
        }
        *(float4*)(out + (size_t)v * D + lane * 4) = o;
    }
}

// ================= host =================

extern "C" void kernel_launch(void* const* d_in, const int* in_sizes, int n_in,
                              void* d_out, int out_size, void* d_ws, size_t ws_size,
                              hipStream_t stream)
{
    const float* xA  = (const float*)d_in[0];
    const float* xB  = (const float*)d_in[1];
    const float* W1  = (const float*)d_in[2];   // [3][256][256]
    const float* al1 = (const float*)d_in[3];
    const float* ar1 = (const float*)d_in[4];
    const float* b1  = (const float*)d_in[5];
    const float* W2  = (const float*)d_in[6];   // [3][32][256]
    const float* al2 = (const float*)d_in[7];
    const float* ar2 = (const float*)d_in[8];
    const float* b2  = (const float*)d_in[9];
    const int* u0 = (const int*)d_in[10];
    const int* v0 = (const int*)d_in[11];
    const int* u1 = (const int*)d_in[12];
    const int* v1 = (const int*)d_in[13];
    const int* u2 = (const int*)d_in[14];
    const int* v2 = (const int*)d_in[15];
    float* out = (float*)d_out;

    // workspace layout: bf16 region first (16B-aligned blocks), then fp32, then int
    const size_t FSZ = (size_t)N_NODES * HD;       // 5.12M elements
    unsigned short* xAb = (unsigned short*)d_ws;
    unsigned short* xBb = xAb + FSZ;
    unsigned short* F0b = xBb + FSZ;
    unsigned short* F1b = F0b + FSZ;
    unsigned short* F2b = F1b + FSZ;
    unsigned short* W1b = F2b + FSZ;               // 196608
    float* el  = (float*)(W1b + 3 * 65536);        // [3][N*H]
    float* er  = el + 3 * N_NODES * H;
    float* hA  = er + 3 * N_NODES * H;             // [N][32]
    float* hB  = hA + (size_t)N_NODES * D;
    float* wlr = hB + (size_t)N_NODES * D;         // [6][2048] max
    float* bs  = wlr + 6 * 2048;                   // [4][32]
    int* off    = (int*)(bs + 128);                // 3N+1
    int* cursor = off + 3 * N_NODES + 1;
    int* cnt    = cursor + 3 * N_NODES;
    int* loc    = cnt + 3 * N_NODES;
    int* bsum   = loc + 3 * N_NODES;
    int* usort  = bsum + 128;                      // 3NE

    float* el0 = el, *el1 = el + N_NODES * H, *el2 = el + 2 * N_NODES * H;
    float* er0 = er, *er1 = er + N_NODES * H, *er2 = er + 2 * N_NODES * H;
    int* off0 = off, *off1 = off + N_NODES, *off2 = off + 2 * N_NODES;
    float* bsA1 = bs, *bsB1 = bs + 32, *bsA2 = bs + 64, *bsB2 = bs + 96;

    const dim3 GB_MM(157, 4);
    const int GB_ROW = N_NODES * H / 256;          // 625
    const int GB_ALL = (2 * N_NODES + 3) / 4;      // 10000
    const int GB_3E  = (3 * NE + 255) / 256;

    // ---- CSR build ----
    hipMemsetAsync(cnt, 0, SCAN_NT * sizeof(int), stream);
    hist3<<<GB_3E, 256, 0, stream>>>(v0, v1, v2, cnt);
    scan_blk<<<SCAN_NB, 512, 0, stream>>>(cnt, loc, bsum);
    scan_bsum<<<1, 128, 0, stream>>>(bsum, SCAN_NB);
    scan_add<<<SCAN_NB, 512, 0, stream>>>(loc, bsum, off, cursor);
    fill3<<<GB_3E, 256, 0, stream>>>(u0, v0, u1, v1, u2, v2, cursor, usort);

    bias_sums<<<1, 128, 0, stream>>>(b1, b2, bs);

    // ---- bf16 conversions ----
    cvt_bf16<<<(int)(FSZ / 1024), 256, 0, stream>>>(xA, xAb, (int)FSZ);
    cvt_bf16<<<(int)(FSZ / 1024), 256, 0, stream>>>(xB, xBb, (int)FSZ);
    cvt_bf16<<<3 * 65536 / 1024, 256, 0, stream>>>(W1, W1b, 3 * 65536);

    // ---------------- layer 1 ----------------
    make_wlr3<<<48, 256, 0, stream>>>(W1, al1, ar1, wlr, 256, 65536);
    mfma_gemm<<<GB_MM, 256, 0, stream>>>(xAb, W1b + 0 * 65536, F0b, N_NODES);
    mfma_gemm<<<GB_MM, 256, 0, stream>>>(xBb, W1b + 1 * 65536, F1b, N_NODES);
    mfma_gemm<<<GB_MM, 256, 0, stream>>>(xAb, W1b + 2 * 65536, F2b, N_NODES);
    // xA -> el0(wl0), er1(wr1), el2(wl2), er2(wr2); xB -> el1(wl1), er0(wr0)
    gemv4<256><<<GB_ROW, 256, 0, stream>>>(xA, wlr + 0 * 2048, wlr + 4 * 2048,
                                           wlr + 2 * 2048, wlr + 5 * 2048,
                                           el0, er1, el2, er2, N_NODES);
    gemv2<256><<<GB_ROW, 256, 0, stream>>>(xB, wlr + 1 * 2048, wlr + 3 * 2048,
                                           el1, er0, N_NODES);
    seg_att_all<1><<<GB_ALL, 256, 0, stream>>>(el0, er0, off0, F0b,
                                               el1, er1, off1, F1b,
                                               el2, er2, off2, F2b,
                                               usort, bsB1, bsA1, hB, hA, N_NODES);

    // ---------------- layer 2 ----------------
    make_wlr3<<<6, 256, 0, stream>>>(W2, al2, ar2, wlr, 32, 8192);
    gemm32<<<GB_MM, 256, 0, stream>>>(hA, W2 + 0 * 8192, F0b, N_NODES);
    gemm32<<<GB_MM, 256, 0, stream>>>(hB, W2 + 1 * 8192, F1b, N_NODES);
    gemm32<<<GB_MM, 256, 0, stream>>>(hA, W2 + 2 * 8192, F2b, N_NODES);
    gemv4<32><<<GB_ROW, 256, 0, stream>>>(hA, wlr + 0 * 256, wlr + 4 * 256,
                                          wlr + 2 * 256, wlr + 5 * 256,
                                          el0, er1, el2, er2, N_NODES);
    gemv2<32><<<GB_ROW, 256, 0, stream>>>(hB, wlr + 1 * 256, wlr + 3 * 256,
                                          el1, er0, N_NODES);
    seg_att_all<0><<<GB_ALL, 256, 0, stream>>>(el0, er0, off0, F0b,
                                               el1, er1, off1, F1b,
                                               el2, er2, off2, F2b,
                                               usort, bsB2, bsA2,
                                               out + (size_t)N_NODES * D, out, N_NODES);
}

// Round 11
// 382.317 us; speedup vs baseline: 68.8488x; 1.2259x over previous
//
#include <hip/hip_runtime.h>
#include <float.h>

#define NEG_SLOPE 0.2f

constexpr int N_NODES = 20000;
constexpr int NE      = 320000;
constexpr int H       = 8;
constexpr int D       = 32;
constexpr int HD      = 256;   // H*D
constexpr int FIN     = 256;
constexpr int SCAN_NT = 3 * N_NODES;           // 60000
constexpr int SCAN_NB = (SCAN_NT + 511) / 512; // 118

typedef __attribute__((ext_vector_type(8))) short bf16x8;
typedef __attribute__((ext_vector_type(4))) float f32x4;

// ---- bf16 helpers (RNE) ----
__device__ __forceinline__ unsigned short f2bf(float x) {
    unsigned u = __float_as_uint(x);
    unsigned r = 0x7FFFu + ((u >> 16) & 1u);
    return (unsigned short)((u + r) >> 16);
}
__device__ __forceinline__ float bf2f(unsigned short h) {
    return __uint_as_float(((unsigned)h) << 16);
}

// ---- fp32 -> bf16 conversion (n multiple of 4) ----
__global__ __launch_bounds__(256) void cvt_bf16(
    const float* __restrict__ in, unsigned short* __restrict__ out, int n)
{
    int t = (blockIdx.x * 256 + threadIdx.x) * 4;
    if (t >= n) return;
    float4 v = *(const float4*)(in + t);
    ushort4 o;
    o.x = f2bf(v.x); o.y = f2bf(v.y); o.z = f2bf(v.z); o.w = f2bf(v.w);
    *(ushort4*)(out + t) = o;
}

// ============ MFMA GEMM (z-batched): F_z[M,256] = X_z[M,256] @ W_z[256,256] ============
__global__ __launch_bounds__(256) void mfma_gemm3(
    const unsigned short* __restrict__ xAb, const unsigned short* __restrict__ xBb,
    const unsigned short* __restrict__ Wb, unsigned short* __restrict__ Fb, int M)
{
    const int z = blockIdx.z;
    const unsigned short* Xb = (z == 1) ? xBb : xAb;
    const unsigned short* Wz = Wb + (size_t)z * 65536;
    unsigned short* F = Fb + (size_t)z * N_NODES * HD;

    __shared__ unsigned short Xs[128][40];
    __shared__ unsigned short WsT[64][40];
    const int tid = threadIdx.x;
    const int wid = tid >> 6, lane = tid & 63;
    const int r0 = blockIdx.x * 128;
    const int c0 = blockIdx.y * 64;
    const int l15 = lane & 15, lg = lane >> 4;

    f32x4 acc[2][4];
#pragma unroll
    for (int i = 0; i < 2; i++)
#pragma unroll
        for (int j = 0; j < 4; j++) acc[i][j] = (f32x4){0.f, 0.f, 0.f, 0.f};

    for (int kc = 0; kc < FIN; kc += 32) {
        for (int i = tid; i < 128 * 4; i += 256) {
            int row = i >> 2, q = i & 3;
            int grow = r0 + row;
            int4 xv = (grow < M) ? *(const int4*)(Xb + (size_t)grow * FIN + kc + q * 8)
                                 : make_int4(0, 0, 0, 0);
            *(int4*)&Xs[row][q * 8] = xv;
        }
        {
            int k = tid >> 3, n8 = (tid & 7) * 8;
            int4 wv = *(const int4*)(Wz + (size_t)(kc + k) * 256 + c0 + n8);
            const unsigned short* wp = (const unsigned short*)&wv;
#pragma unroll
            for (int j = 0; j < 8; j++) WsT[n8 + j][k] = wp[j];
        }
        __syncthreads();
        const int rm = wid * 32;
        bf16x8 a0 = *(const bf16x8*)&Xs[rm + l15][lg * 8];
        bf16x8 a1 = *(const bf16x8*)&Xs[rm + 16 + l15][lg * 8];
#pragma unroll
        for (int j = 0; j < 4; j++) {
            bf16x8 b = *(const bf16x8*)&WsT[j * 16 + l15][lg * 8];
            acc[0][j] = __builtin_amdgcn_mfma_f32_16x16x32_bf16(a0, b, acc[0][j], 0, 0, 0);
            acc[1][j] = __builtin_amdgcn_mfma_f32_16x16x32_bf16(a1, b, acc[1][j], 0, 0, 0);
        }
        __syncthreads();
    }
    const int rm = wid * 32;
#pragma unroll
    for (int i = 0; i < 2; i++)
#pragma unroll
        for (int j = 0; j < 4; j++)
#pragma unroll
            for (int r = 0; r < 4; r++) {
                int row = r0 + rm + i * 16 + lg * 4 + r;
                if (row < M)
                    F[(size_t)row * 256 + c0 + j * 16 + l15] = f2bf(acc[i][j][r]);
            }
}

// ============ layer-2 vector GEMM (z-batched): F_z = X_z[M,32] @ W_z[32,256] ============
__global__ __launch_bounds__(256) void gemm32_3(
    const float* __restrict__ hA, const float* __restrict__ hB,
    const float* __restrict__ W2, unsigned short* __restrict__ Fb, int M)
{
    const int z = blockIdx.z;
    const float* X = (z == 1) ? hB : hA;
    const float* W = W2 + (size_t)z * 8192;
    unsigned short* F = Fb + (size_t)z * N_NODES * HD;

    __shared__ float Xs[128][40];
    __shared__ float Ws[32][64];
    const int tx = threadIdx.x & 15;
    const int ty = threadIdx.x >> 4;
    const int r0 = blockIdx.x * 128;
    const int c0 = blockIdx.y * 64;
    for (int idx = threadIdx.x; idx < 128 * 8; idx += 256) {
        int row = idx >> 3, kq = idx & 7;
        int grow = r0 + row;
        float4 xv = (grow < M) ? *(const float4*)(X + (size_t)grow * 32 + kq * 4)
                               : make_float4(0.f, 0.f, 0.f, 0.f);
        *(float4*)&Xs[row][kq * 4] = xv;
    }
    for (int idx = threadIdx.x; idx < 32 * 16; idx += 256) {
        int k = idx >> 4, cq = idx & 15;
        *(float4*)&Ws[k][cq * 4] = *(const float4*)(W + (size_t)k * 256 + c0 + cq * 4);
    }
    __syncthreads();
    float4 acc[8];
#pragma unroll
    for (int r = 0; r < 8; r++) acc[r] = make_float4(0.f, 0.f, 0.f, 0.f);
#pragma unroll 4
    for (int k = 0; k < 32; k++) {
        float4 wv = *(float4*)&Ws[k][tx * 4];
#pragma unroll
        for (int r = 0; r < 8; r++) {
            float x = Xs[ty + 16 * r][k];
            acc[r].x = fmaf(x, wv.x, acc[r].x);
            acc[r].y = fmaf(x, wv.y, acc[r].y);
            acc[r].z = fmaf(x, wv.z, acc[r].z);
            acc[r].w = fmaf(x, wv.w, acc[r].w);
        }
    }
#pragma unroll
    for (int r = 0; r < 8; r++) {
        int row = r0 + ty + 16 * r;
        if (row < M) {
            ushort4 cb;
            cb.x = f2bf(acc[r].x); cb.y = f2bf(acc[r].y);
            cb.z = f2bf(acc[r].z); cb.w = f2bf(acc[r].w);
            *(ushort4*)(F + (size_t)row * 256 + c0 + tx * 4) = cb;
        }
    }
}

// ---- wlr[half][et][k][h]: half0 = W·al, half1 = W·ar ----
__global__ void make_wlr3(const float* __restrict__ W, const float* __restrict__ al,
                          const float* __restrict__ ar, float* __restrict__ wlr,
                          int K, int wstride)
{
    int t = blockIdx.x * blockDim.x + threadIdx.x;
    if (t >= 6 * K * H) return;
    int half = t / (3 * K * H);
    int rem  = t % (3 * K * H);
    int et = rem / (K * H);
    int rem2 = rem % (K * H);
    int k = rem2 / H, h = rem2 % H;
    const float* av = (half ? ar : al) + et * HD + h * D;
    const float* Wp = W + (size_t)et * wstride + k * HD + h * D;
    float s = 0.f;
#pragma unroll
    for (int d = 0; d < D; d++) s += Wp[d] * av[d];
    wlr[t] = s;
}

// ---- 4 GEMVs from one x read ----
template <int K>
__global__ __launch_bounds__(256) void gemv4(
    const float* __restrict__ x,
    const float* __restrict__ w0, const float* __restrict__ w1,
    const float* __restrict__ w2, const float* __restrict__ w3,
    float* __restrict__ o0, float* __restrict__ o1,
    float* __restrict__ o2, float* __restrict__ o3, int N)
{
    __shared__ float w[4][K * H];
    for (int i = threadIdx.x; i < K * H; i += 256) {
        w[0][i] = w0[i]; w[1][i] = w1[i]; w[2][i] = w2[i]; w[3][i] = w3[i];
    }
    __syncthreads();
    int t = blockIdx.x * 256 + threadIdx.x;
    if (t >= N * H) return;
    int n = t >> 3, h = t & 7;
    const float4* xp = (const float4*)(x + (size_t)n * K);
    float s0 = 0.f, s1 = 0.f, s2 = 0.f, s3 = 0.f;
#pragma unroll 2
    for (int k4 = 0; k4 < K / 4; k4++) {
        float4 xv = xp[k4];
        const float* xe = &xv.x;
#pragma unroll
        for (int e = 0; e < 4; e++) {
            int idx = (4 * k4 + e) * H + h;
            float xx = xe[e];
            s0 = fmaf(xx, w[0][idx], s0);
            s1 = fmaf(xx, w[1][idx], s1);
            s2 = fmaf(xx, w[2][idx], s2);
            s3 = fmaf(xx, w[3][idx], s3);
        }
    }
    o0[t] = s0; o1[t] = s1; o2[t] = s2; o3[t] = s3;
}

template <int K>
__global__ __launch_bounds__(256) void gemv2(
    const float* __restrict__ x,
    const float* __restrict__ w0, const float* __restrict__ w1,
    float* __restrict__ o0, float* __restrict__ o1, int N)
{
    __shared__ float w[2][K * H];
    for (int i = threadIdx.x; i < K * H; i += 256) { w[0][i] = w0[i]; w[1][i] = w1[i]; }
    __syncthreads();
    int t = blockIdx.x * 256 + threadIdx.x;
    if (t >= N * H) return;
    int n = t >> 3, h = t & 7;
    const float4* xp = (const float4*)(x + (size_t)n * K);
    float s0 = 0.f, s1 = 0.f;
#pragma unroll 2
    for (int k4 = 0; k4 < K / 4; k4++) {
        float4 xv = xp[k4];
        const float* xe = &xv.x;
#pragma unroll
        for (int e = 0; e < 4; e++) {
            int idx = (4 * k4 + e) * H + h;
            float xx = xe[e];
            s0 = fmaf(xx, w[0][idx], s0);
            s1 = fmaf(xx, w[1][idx], s1);
        }
    }
    o0[t] = s0; o1[t] = s1;
}

// ---- bias head-sums ----
__global__ void bias_sums(const float* __restrict__ b1, const float* __restrict__ b2,
                          float* __restrict__ bs)
{
    int t = threadIdx.x;            // 128
    int which = t >> 5, d = t & 31;
    const float* b = (which < 2) ? b1 : b2;
    float s = 0.f;
    if (which & 1) {
#pragma unroll
        for (int h = 0; h < H; h++) s += b[0 * 256 + h * D + d];
    } else {
#pragma unroll
        for (int h = 0; h < H; h++) s += b[1 * 256 + h * D + d] + b[2 * 256 + h * D + d];
    }
    bs[t] = s;
}

// ============ CSR build ============

__global__ void hist3(const int* __restrict__ v0, const int* __restrict__ v1,
                      const int* __restrict__ v2, int* __restrict__ cnt)
{
    int t = blockIdx.x * blockDim.x + threadIdx.x;
    if (t >= 3 * NE) return;
    int et = t / NE, i = t - et * NE;
    const int* vp = (et == 0) ? v0 : (et == 1) ? v1 : v2;
    atomicAdd(&cnt[et * N_NODES + vp[i]], 1);
}

__global__ __launch_bounds__(512) void scan_blk(
    const int* __restrict__ cnt, int* __restrict__ loc, int* __restrict__ bsum)
{
    int gid = blockIdx.x * 512 + threadIdx.x;
    int x = (gid < SCAN_NT) ? cnt[gid] : 0;
    int lane = threadIdx.x & 63, w = threadIdx.x >> 6;
    int v = x;
#pragma unroll
    for (int d = 1; d < 64; d <<= 1) {
        int y = __shfl_up(v, d, 64);
        if (lane >= d) v += y;
    }
    __shared__ int wsum[8];
    if (lane == 63) wsum[w] = v;
    __syncthreads();
    if (threadIdx.x == 0) {
        int run = 0;
#pragma unroll
        for (int i = 0; i < 8; i++) { int t2 = wsum[i]; wsum[i] = run; run += t2; }
    }
    __syncthreads();
    int excl = v - x + wsum[w];
    if (gid < SCAN_NT) loc[gid] = excl;
    if (threadIdx.x == 511) bsum[blockIdx.x] = excl + x;
}

__global__ __launch_bounds__(128) void scan_bsum(int* __restrict__ bsum, int nb)
{
    int t = threadIdx.x;
    int x = (t < nb) ? bsum[t] : 0;
    int lane = t & 63, w = t >> 6;
    int v = x;
#pragma unroll
    for (int d = 1; d < 64; d <<= 1) {
        int y = __shfl_up(v, d, 64);
        if (lane >= d) v += y;
    }
    __shared__ int ws2[2];
    if (lane == 63) ws2[w] = v;
    __syncthreads();
    int add = (w == 1) ? ws2[0] : 0;
    if (t < nb) bsum[t] = v + add - x;
}

__global__ __launch_bounds__(512) void scan_add(
    const int* __restrict__ loc, const int* __restrict__ bsum,
    int* __restrict__ off, int* __restrict__ cursor)
{
    int gid = blockIdx.x * 512 + threadIdx.x;
    if (gid < SCAN_NT) {
        int o = loc[gid] + bsum[blockIdx.x];
        off[gid] = o;
        cursor[gid] = o;
    } else if (gid == SCAN_NT) {
        off[gid] = 3 * NE;
    }
}

__global__ void fill3(const int* __restrict__ u0, const int* __restrict__ v0,
                      const int* __restrict__ u1, const int* __restrict__ v1,
                      const int* __restrict__ u2, const int* __restrict__ v2,
                      int* __restrict__ cursor, int* __restrict__ usort)
{
    int t = blockIdx.x * blockDim.x + threadIdx.x;
    if (t >= 3 * NE) return;
    int et = t / NE, i = t - et * NE;
    const int* up = (et == 0) ? u0 : (et == 1) ? u1 : u2;
    const int* vp = (et == 0) ? v0 : (et == 1) ? v1 : v2;
    int pos = atomicAdd(&cursor[et * N_NODES + vp[i]], 1);
    usort[pos] = up[i];
}

// ============ fused edge softmax + gather + head-mean (bf16 F) ============
// clean unpredicated 8-wide main loop + ONE masked batch for the tail.

__device__ __forceinline__ float lrelu(float e) {
    return (e >= 0.f) ? e : NEG_SLOPE * e;
}

__device__ __forceinline__ float4 seg_accum(
    const float* __restrict__ el, float erh,
    const int* __restrict__ us, int lo, int hi,
    const unsigned short* __restrict__ Fs, int lane, int h)
{
    float4 aa = make_float4(0.f, 0.f, 0.f, 0.f);
    if (lo >= hi) return aa;
    float s = 0.f;
    int j = lo;
    for (; j + 8 <= hi; j += 8) {
        int u[8];
#pragma unroll
        for (int q = 0; q < 8; q++) u[q] = us[j + q];
        ushort4 fb[8];
#pragma unroll
        for (int q = 0; q < 8; q++)
            fb[q] = *(const ushort4*)(Fs + ((size_t)u[q] << 8) + lane * 4);
        float wv[8];
#pragma unroll
        for (int q = 0; q < 8; q++)
            wv[q] = __expf(lrelu(el[u[q] * H + h] + erh));
#pragma unroll
        for (int q = 0; q < 8; q++) {
            s += wv[q];
            aa.x = fmaf(wv[q], bf2f(fb[q].x), aa.x);
            aa.y = fmaf(wv[q], bf2f(fb[q].y), aa.y);
            aa.z = fmaf(wv[q], bf2f(fb[q].z), aa.z);
            aa.w = fmaf(wv[q], bf2f(fb[q].w), aa.w);
        }
    }
    if (j < hi) {   // one masked batch
        int u[8];
#pragma unroll
        for (int q = 0; q < 8; q++) u[q] = us[(j + q < hi) ? j + q : hi - 1];
        ushort4 fb[8];
#pragma unroll
        for (int q = 0; q < 8; q++)
            fb[q] = *(const ushort4*)(Fs + ((size_t)u[q] << 8) + lane * 4);
        float wv[8];
#pragma unroll
        for (int q = 0; q < 8; q++) {
            float e = el[u[q] * H + h] + erh;
            wv[q] = (j + q < hi) ? __expf(lrelu(e)) : 0.f;
        }
#pragma unroll
        for (int q = 0; q < 8; q++) {
            s += wv[q];
            aa.x = fmaf(wv[q], bf2f(fb[q].x), aa.x);
            aa.y = fmaf(wv[q], bf2f(fb[q].y), aa.y);
            aa.z = fmaf(wv[q], bf2f(fb[q].z), aa.z);
            aa.w = fmaf(wv[q], bf2f(fb[q].w), aa.w);
        }
    }
    float inv = (s > 0.f) ? 1.f / s : 0.f;
    aa.x *= inv; aa.y *= inv; aa.z *= inv; aa.w *= inv;
    return aa;
}

template <int RELU>
__global__ __launch_bounds__(256) void seg_att_all(
    const float* __restrict__ el0, const float* __restrict__ er0,
    const int* __restrict__ off0, const unsigned short* __restrict__ F0,
    const float* __restrict__ el1, const float* __restrict__ er1,
    const int* __restrict__ off1, const unsigned short* __restrict__ F1,
    const float* __restrict__ el2, const float* __restrict__ er2,
    const int* __restrict__ off2, const unsigned short* __restrict__ F2,
    const int* __restrict__ us, const float* __restrict__ bsB,
    const float* __restrict__ bsA, float* __restrict__ outB,
    float* __restrict__ outA, int N)
{
    int wid = blockIdx.x * 4 + (threadIdx.x >> 6);
    if (wid >= 2 * N) return;
    const int lane = threadIdx.x & 63;
    const int h = lane >> 3;
    float4 tot;
    const float* bs;
    float* out;
    int v;
    if (wid < N) {
        v = wid;
        tot = seg_accum(el0, er0[v * H + h], us, off0[v], off0[v + 1], F0, lane, h);
        bs = bsB; out = outB;
    } else {
        v = wid - N;
        float4 t1 = seg_accum(el1, er1[v * H + h], us, off1[v], off1[v + 1], F1, lane, h);
        float4 t2 = seg_accum(el2, er2[v * H + h], us, off2[v], off2[v + 1], F2, lane, h);
        tot.x = t1.x + t2.x; tot.y = t1.y + t2.y;
        tot.z = t1.z + t2.z; tot.w = t1.w + t2.w;
        bs = bsA; out = outA;
    }
#pragma unroll
    for (int mask = 8; mask <= 32; mask <<= 1) {
        tot.x += __shfl_xor(tot.x, mask, 64);
        tot.y += __shfl_xor(tot.y, mask, 64);
        tot.z += __shfl_xor(tot.z, mask, 64);
        tot.w += __shfl_xor(tot.w, mask, 64);
    }
    if (lane < 8) {
        float4 b = *(const float4*)(bs + lane * 4);
        float4 o;
        o.x = (tot.x + b.x) * 0.125f;
        o.y = (tot.y + b.y) * 0.125f;
        o.z = (tot.z + b.z) * 0.125f;
        o.w = (tot.w + b.w) * 0.125f;
        if (RELU) {
            o.x = fmaxf(o.x, 0.f); o.y = fmaxf(o.y, 0.f);
            o.z = fmaxf(o.z, 0.f); o.w = fmaxf(o.w, 0.f);
        }
        *(float4*)(out + (size_t)v * D + lane * 4) = o;
    }
}

// ================= host =================

extern "C" void kernel_launch(void* const* d_in, const int* in_sizes, int n_in,
                              void* d_out, int out_size, void* d_ws, size_t ws_size,
                              hipStream_t stream)
{
    const float* xA  = (const float*)d_in[0];
    const float* xB  = (const float*)d_in[1];
    const float* W1  = (const float*)d_in[2];   // [3][256][256]
    const float* al1 = (const float*)d_in[3];
    const float* ar1 = (const float*)d_in[4];
    const float* b1  = (const float*)d_in[5];
    const float* W2  = (const float*)d_in[6];   // [3][32][256]
    const float* al2 = (const float*)d_in[7];
    const float* ar2 = (const float*)d_in[8];
    const float* b2  = (const float*)d_in[9];
    const int* u0 = (const int*)d_in[10];
    const int* v0 = (const int*)d_in[11];
    const int* u1 = (const int*)d_in[12];
    const int* v1 = (const int*)d_in[13];
    const int* u2 = (const int*)d_in[14];
    const int* v2 = (const int*)d_in[15];
    float* out = (float*)d_out;

    const size_t FSZ = (size_t)N_NODES * HD;       // 5.12M elements
    unsigned short* xAb = (unsigned short*)d_ws;
    unsigned short* xBb = xAb + FSZ;
    unsigned short* Fb  = xBb + FSZ;               // [3][FSZ] contiguous
    unsigned short* F0b = Fb;
    unsigned short* F1b = Fb + FSZ;
    unsigned short* F2b = Fb + 2 * FSZ;
    unsigned short* W1b = Fb + 3 * FSZ;            // 196608
    float* el  = (float*)(W1b + 3 * 65536);        // [3][N*H]
    float* er  = el + 3 * N_NODES * H;
    float* hA  = er + 3 * N_NODES * H;             // [N][32]
    float* hB  = hA + (size_t)N_NODES * D;
    float* wlr = hB + (size_t)N_NODES * D;         // [6][2048] max
    float* bs  = wlr + 6 * 2048;                   // [4][32]
    int* off    = (int*)(bs + 128);                // 3N+1
    int* cursor = off + 3 * N_NODES + 1;
    int* cnt    = cursor + 3 * N_NODES;
    int* loc    = cnt + 3 * N_NODES;
    int* bsum   = loc + 3 * N_NODES;
    int* usort  = bsum + 128;                      // 3NE

    float* el0 = el, *el1 = el + N_NODES * H, *el2 = el + 2 * N_NODES * H;
    float* er0 = er, *er1 = er + N_NODES * H, *er2 = er + 2 * N_NODES * H;
    int* off0 = off, *off1 = off + N_NODES, *off2 = off + 2 * N_NODES;
    float* bsA1 = bs, *bsB1 = bs + 32, *bsA2 = bs + 64, *bsB2 = bs + 96;

    const dim3 GB_MM3(157, 4, 3);
    const int GB_ROW = N_NODES * H / 256;          // 625
    const int GB_ALL = (2 * N_NODES + 3) / 4;      // 10000
    const int GB_3E  = (3 * NE + 255) / 256;

    // ---- CSR build ----
    hipMemsetAsync(cnt, 0, SCAN_NT * sizeof(int), stream);
    hist3<<<GB_3E, 256, 0, stream>>>(v0, v1, v2, cnt);
    scan_blk<<<SCAN_NB, 512, 0, stream>>>(cnt, loc, bsum);
    scan_bsum<<<1, 128, 0, stream>>>(bsum, SCAN_NB);
    scan_add<<<SCAN_NB, 512, 0, stream>>>(loc, bsum, off, cursor);
    fill3<<<GB_3E, 256, 0, stream>>>(u0, v0, u1, v1, u2, v2, cursor, usort);

    bias_sums<<<1, 128, 0, stream>>>(b1, b2, bs);

    // ---- bf16 conversions ----
    cvt_bf16<<<(int)(FSZ / 1024), 256, 0, stream>>>(xA, xAb, (int)FSZ);
    cvt_bf16<<<(int)(FSZ / 1024), 256, 0, stream>>>(xB, xBb, (int)FSZ);
    cvt_bf16<<<3 * 65536 / 1024, 256, 0, stream>>>(W1, W1b, 3 * 65536);

    // ---------------- layer 1 ----------------
    make_wlr3<<<48, 256, 0, stream>>>(W1, al1, ar1, wlr, 256, 65536);
    mfma_gemm3<<<GB_MM3, 256, 0, stream>>>(xAb, xBb, W1b, Fb, N_NODES);
    gemv4<256><<<GB_ROW, 256, 0, stream>>>(xA, wlr + 0 * 2048, wlr + 4 * 2048,
                                           wlr + 2 * 2048, wlr + 5 * 2048,
                                           el0, er1, el2, er2, N_NODES);
    gemv2<256><<<GB_ROW, 256, 0, stream>>>(xB, wlr + 1 * 2048, wlr + 3 * 2048,
                                           el1, er0, N_NODES);
    seg_att_all<1><<<GB_ALL, 256, 0, stream>>>(el0, er0, off0, F0b,
                                               el1, er1, off1, F1b,
                                               el2, er2, off2, F2b,
                                               usort, bsB1, bsA1, hB, hA, N_NODES);

    // ---------------- layer 2 ----------------
    make_wlr3<<<6, 256, 0, stream>>>(W2, al2, ar2, wlr, 32, 8192);
    gemm32_3<<<GB_MM3, 256, 0, stream>>>(hA, hB, W2, Fb, N_NODES);
    gemv4<32><<<GB_ROW, 256, 0, stream>>>(hA, wlr + 0 * 256, wlr + 4 * 256,
                                          wlr + 2 * 256, wlr + 5 * 256,
                                          el0, er1, el2, er2, N_NODES);
    gemv2<32><<<GB_ROW, 256, 0, stream>>>(hB, wlr + 1 * 256, wlr + 3 * 256,
                                          el1, er0, N_NODES);
    seg_att_all<0><<<GB_ALL, 256, 0, stream>>>(el0, er0, off0, F0b,
                                               el1, er1, off1, F1b,
                                               el2, er2, off2, F2b,
                                               usort, bsB2, bsA2,
                                               out + (size_t)N_NODES * D, out, N_NODES);
}

// Round 12
// 362.271 us; speedup vs baseline: 72.6586x; 1.0553x over previous
//
#include <hip/hip_runtime.h>
#include <float.h>

#define NEG_SLOPE 0.2f

constexpr int N_NODES = 20000;
constexpr int NE      = 320000;
constexpr int H       = 8;
constexpr int D       = 32;
constexpr int HD      = 256;   // H*D
constexpr int FIN     = 256;
constexpr int SCAN_NT = 3 * N_NODES;           // 60000
constexpr int SCAN_NB = (SCAN_NT + 511) / 512; // 118

typedef __attribute__((ext_vector_type(8))) short bf16x8;
typedef __attribute__((ext_vector_type(4))) float f32x4;

// ---- bf16 helpers (RNE) ----
__device__ __forceinline__ unsigned short f2bf(float x) {
    unsigned u = __float_as_uint(x);
    unsigned r = 0x7FFFu + ((u >> 16) & 1u);
    return (unsigned short)((u + r) >> 16);
}
__device__ __forceinline__ float bf2f(unsigned short h) {
    return __uint_as_float(((unsigned)h) << 16);
}

// ---- fused fp32 -> bf16 conversion: xA | xB | W1 ----
__global__ __launch_bounds__(256) void cvt_all(
    const float* __restrict__ xA, const float* __restrict__ xB,
    const float* __restrict__ W1, unsigned short* __restrict__ xAb,
    unsigned short* __restrict__ xBb, unsigned short* __restrict__ W1b)
{
    const int FSZi = N_NODES * HD;       // 5,120,000 (mult of 4)
    const int WSZ  = 3 * 65536;          // 196,608  (mult of 4)
    int t = (blockIdx.x * 256 + threadIdx.x) * 4;
    const float* in;
    unsigned short* outp;
    int o;
    if (t < FSZi)            { in = xA; outp = xAb; o = t; }
    else if (t < 2 * FSZi)   { in = xB; outp = xBb; o = t - FSZi; }
    else if (t < 2 * FSZi + WSZ) { in = W1; outp = W1b; o = t - 2 * FSZi; }
    else return;
    float4 v = *(const float4*)(in + o);
    ushort4 ob;
    ob.x = f2bf(v.x); ob.y = f2bf(v.y); ob.z = f2bf(v.z); ob.w = f2bf(v.w);
    *(ushort4*)(outp + o) = ob;
}

// ============ MFMA GEMM (z-batched): F_z[M,256] = X_z[M,256] @ W_z[256,256] ============
__global__ __launch_bounds__(256) void mfma_gemm3(
    const unsigned short* __restrict__ xAb, const unsigned short* __restrict__ xBb,
    const unsigned short* __restrict__ Wb, unsigned short* __restrict__ Fb, int M)
{
    const int z = blockIdx.z;
    const unsigned short* Xb = (z == 1) ? xBb : xAb;
    const unsigned short* Wz = Wb + (size_t)z * 65536;
    unsigned short* F = Fb + (size_t)z * N_NODES * HD;

    __shared__ unsigned short Xs[128][40];
    __shared__ unsigned short WsT[64][40];
    const int tid = threadIdx.x;
    const int wid = tid >> 6, lane = tid & 63;
    const int r0 = blockIdx.x * 128;
    const int c0 = blockIdx.y * 64;
    const int l15 = lane & 15, lg = lane >> 4;

    f32x4 acc[2][4];
#pragma unroll
    for (int i = 0; i < 2; i++)
#pragma unroll
        for (int j = 0; j < 4; j++) acc[i][j] = (f32x4){0.f, 0.f, 0.f, 0.f};

    for (int kc = 0; kc < FIN; kc += 32) {
        for (int i = tid; i < 128 * 4; i += 256) {
            int row = i >> 2, q = i & 3;
            int grow = r0 + row;
            int4 xv = (grow < M) ? *(const int4*)(Xb + (size_t)grow * FIN + kc + q * 8)
                                 : make_int4(0, 0, 0, 0);
            *(int4*)&Xs[row][q * 8] = xv;
        }
        {
            int k = tid >> 3, n8 = (tid & 7) * 8;
            int4 wv = *(const int4*)(Wz + (size_t)(kc + k) * 256 + c0 + n8);
            const unsigned short* wp = (const unsigned short*)&wv;
#pragma unroll
            for (int j = 0; j < 8; j++) WsT[n8 + j][k] = wp[j];
        }
        __syncthreads();
        const int rm = wid * 32;
        bf16x8 a0 = *(const bf16x8*)&Xs[rm + l15][lg * 8];
        bf16x8 a1 = *(const bf16x8*)&Xs[rm + 16 + l15][lg * 8];
#pragma unroll
        for (int j = 0; j < 4; j++) {
            bf16x8 b = *(const bf16x8*)&WsT[j * 16 + l15][lg * 8];
            acc[0][j] = __builtin_amdgcn_mfma_f32_16x16x32_bf16(a0, b, acc[0][j], 0, 0, 0);
            acc[1][j] = __builtin_amdgcn_mfma_f32_16x16x32_bf16(a1, b, acc[1][j], 0, 0, 0);
        }
        __syncthreads();
    }
    const int rm = wid * 32;
#pragma unroll
    for (int i = 0; i < 2; i++)
#pragma unroll
        for (int j = 0; j < 4; j++)
#pragma unroll
            for (int r = 0; r < 4; r++) {
                int row = r0 + rm + i * 16 + lg * 4 + r;
                if (row < M)
                    F[(size_t)row * 256 + c0 + j * 16 + l15] = f2bf(acc[i][j][r]);
            }
}

// ============ layer-2 vector GEMM (z-batched): F_z = X_z[M,32] @ W_z[32,256] ============
__global__ __launch_bounds__(256) void gemm32_3(
    const float* __restrict__ hA, const float* __restrict__ hB,
    const float* __restrict__ W2, unsigned short* __restrict__ Fb, int M)
{
    const int z = blockIdx.z;
    const float* X = (z == 1) ? hB : hA;
    const float* W = W2 + (size_t)z * 8192;
    unsigned short* F = Fb + (size_t)z * N_NODES * HD;

    __shared__ float Xs[128][40];
    __shared__ float Ws[32][64];
    const int tx = threadIdx.x & 15;
    const int ty = threadIdx.x >> 4;
    const int r0 = blockIdx.x * 128;
    const int c0 = blockIdx.y * 64;
    for (int idx = threadIdx.x; idx < 128 * 8; idx += 256) {
        int row = idx >> 3, kq = idx & 7;
        int grow = r0 + row;
        float4 xv = (grow < M) ? *(const float4*)(X + (size_t)grow * 32 + kq * 4)
                               : make_float4(0.f, 0.f, 0.f, 0.f);
        *(float4*)&Xs[row][kq * 4] = xv;
    }
    for (int idx = threadIdx.x; idx < 32 * 16; idx += 256) {
        int k = idx >> 4, cq = idx & 15;
        *(float4*)&Ws[k][cq * 4] = *(const float4*)(W + (size_t)k * 256 + c0 + cq * 4);
    }
    __syncthreads();
    float4 acc[8];
#pragma unroll
    for (int r = 0; r < 8; r++) acc[r] = make_float4(0.f, 0.f, 0.f, 0.f);
#pragma unroll 4
    for (int k = 0; k < 32; k++) {
        float4 wv = *(float4*)&Ws[k][tx * 4];
#pragma unroll
        for (int r = 0; r < 8; r++) {
            float x = Xs[ty + 16 * r][k];
            acc[r].x = fmaf(x, wv.x, acc[r].x);
            acc[r].y = fmaf(x, wv.y, acc[r].y);
            acc[r].z = fmaf(x, wv.z, acc[r].z);
            acc[r].w = fmaf(x, wv.w, acc[r].w);
        }
    }
#pragma unroll
    for (int r = 0; r < 8; r++) {
        int row = r0 + ty + 16 * r;
        if (row < M) {
            ushort4 cb;
            cb.x = f2bf(acc[r].x); cb.y = f2bf(acc[r].y);
            cb.z = f2bf(acc[r].z); cb.w = f2bf(acc[r].w);
            *(ushort4*)(F + (size_t)row * 256 + c0 + tx * 4) = cb;
        }
    }
}

// ---- wlr[half][et][k][h]: half0 = W·al, half1 = W·ar ----
__global__ void make_wlr3(const float* __restrict__ W, const float* __restrict__ al,
                          const float* __restrict__ ar, float* __restrict__ wlr,
                          int K, int wstride)
{
    int t = blockIdx.x * blockDim.x + threadIdx.x;
    if (t >= 6 * K * H) return;
    int half = t / (3 * K * H);
    int rem  = t % (3 * K * H);
    int et = rem / (K * H);
    int rem2 = rem % (K * H);
    int k = rem2 / H, h = rem2 % H;
    const float* av = (half ? ar : al) + et * HD + h * D;
    const float* Wp = W + (size_t)et * wstride + k * HD + h * D;
    float s = 0.f;
#pragma unroll
    for (int d = 0; d < D; d++) s += Wp[d] * av[d];
    wlr[t] = s;
}

// ---- fused GEMVs: grid.y==0: xa -> el0,er1,el2,er2 ; grid.y==1: xb -> el1,er0 ----
template <int K>
__global__ __launch_bounds__(256) void gemv6(
    const float* __restrict__ xa, const float* __restrict__ xb,
    const float* __restrict__ wlr,
    float* __restrict__ el, float* __restrict__ er, int N)
{
    __shared__ float w[4][K * H];
    const int KH = K * H;
    const int NH = N_NODES * H;
    float *o0, *o1, *o2, *o3;
    const float* x;
    if (blockIdx.y == 0) {
        for (int i = threadIdx.x; i < KH; i += 256) {
            w[0][i] = wlr[0 * KH + i];   // l0
            w[1][i] = wlr[4 * KH + i];   // r1
            w[2][i] = wlr[2 * KH + i];   // l2
            w[3][i] = wlr[5 * KH + i];   // r2
        }
        x = xa;
        o0 = el; o1 = er + NH; o2 = el + 2 * NH; o3 = er + 2 * NH;
    } else {
        for (int i = threadIdx.x; i < KH; i += 256) {
            w[0][i] = wlr[1 * KH + i];   // l1
            w[1][i] = wlr[3 * KH + i];   // r0
        }
        x = xb;
        o0 = el + NH; o1 = er; o2 = nullptr; o3 = nullptr;
    }
    __syncthreads();
    int t = blockIdx.x * 256 + threadIdx.x;
    if (t >= N * H) return;
    int n = t >> 3, h = t & 7;
    const float4* xp = (const float4*)(x + (size_t)n * K);
    float s0 = 0.f, s1 = 0.f, s2 = 0.f, s3 = 0.f;
    if (blockIdx.y == 0) {
#pragma unroll 2
        for (int k4 = 0; k4 < K / 4; k4++) {
            float4 xv = xp[k4];
            const float* xe = &xv.x;
#pragma unroll
            for (int e = 0; e < 4; e++) {
                int idx = (4 * k4 + e) * H + h;
                float xx = xe[e];
                s0 = fmaf(xx, w[0][idx], s0);
                s1 = fmaf(xx, w[1][idx], s1);
                s2 = fmaf(xx, w[2][idx], s2);
                s3 = fmaf(xx, w[3][idx], s3);
            }
        }
        o0[t] = s0; o1[t] = s1; o2[t] = s2; o3[t] = s3;
    } else {
#pragma unroll 2
        for (int k4 = 0; k4 < K / 4; k4++) {
            float4 xv = xp[k4];
            const float* xe = &xv.x;
#pragma unroll
            for (int e = 0; e < 4; e++) {
                int idx = (4 * k4 + e) * H + h;
                float xx = xe[e];
                s0 = fmaf(xx, w[0][idx], s0);
                s1 = fmaf(xx, w[1][idx], s1);
            }
        }
        o0[t] = s0; o1[t] = s1;
    }
}

// ---- bias head-sums ----
__global__ void bias_sums(const float* __restrict__ b1, const float* __restrict__ b2,
                          float* __restrict__ bs)
{
    int t = threadIdx.x;            // 128
    int which = t >> 5, d = t & 31;
    const float* b = (which < 2) ? b1 : b2;
    float s = 0.f;
    if (which & 1) {
#pragma unroll
        for (int h = 0; h < H; h++) s += b[0 * 256 + h * D + d];
    } else {
#pragma unroll
        for (int h = 0; h < H; h++) s += b[1 * 256 + h * D + d] + b[2 * 256 + h * D + d];
    }
    bs[t] = s;
}

// ============ CSR build ============

__global__ void hist3(const int* __restrict__ v0, const int* __restrict__ v1,
                      const int* __restrict__ v2, int* __restrict__ cnt)
{
    int t = blockIdx.x * blockDim.x + threadIdx.x;
    if (t >= 3 * NE) return;
    int et = t / NE, i = t - et * NE;
    const int* vp = (et == 0) ? v0 : (et == 1) ? v1 : v2;
    atomicAdd(&cnt[et * N_NODES + vp[i]], 1);
}

__global__ __launch_bounds__(512) void scan_blk(
    const int* __restrict__ cnt, int* __restrict__ loc, int* __restrict__ bsum)
{
    int gid = blockIdx.x * 512 + threadIdx.x;
    int x = (gid < SCAN_NT) ? cnt[gid] : 0;
    int lane = threadIdx.x & 63, w = threadIdx.x >> 6;
    int v = x;
#pragma unroll
    for (int d = 1; d < 64; d <<= 1) {
        int y = __shfl_up(v, d, 64);
        if (lane >= d) v += y;
    }
    __shared__ int wsum[8];
    if (lane == 63) wsum[w] = v;
    __syncthreads();
    if (threadIdx.x == 0) {
        int run = 0;
#pragma unroll
        for (int i = 0; i < 8; i++) { int t2 = wsum[i]; wsum[i] = run; run += t2; }
    }
    __syncthreads();
    int excl = v - x + wsum[w];
    if (gid < SCAN_NT) loc[gid] = excl;
    if (threadIdx.x == 511) bsum[blockIdx.x] = excl + x;
}

__global__ __launch_bounds__(128) void scan_bsum(int* __restrict__ bsum, int nb)
{
    int t = threadIdx.x;
    int x = (t < nb) ? bsum[t] : 0;
    int lane = t & 63, w = t >> 6;
    int v = x;
#pragma unroll
    for (int d = 1; d < 64; d <<= 1) {
        int y = __shfl_up(v, d, 64);
        if (lane >= d) v += y;
    }
    __shared__ int ws2[2];
    if (lane == 63) ws2[w] = v;
    __syncthreads();
    int add = (w == 1) ? ws2[0] : 0;
    if (t < nb) bsum[t] = v + add - x;
}

__global__ __launch_bounds__(512) void scan_add(
    const int* __restrict__ loc, const int* __restrict__ bsum,
    int* __restrict__ off, int* __restrict__ cursor)
{
    int gid = blockIdx.x * 512 + threadIdx.x;
    if (gid < SCAN_NT) {
        int o = loc[gid] + bsum[blockIdx.x];
        off[gid] = o;
        cursor[gid] = o;
    } else if (gid == SCAN_NT) {
        off[gid] = 3 * NE;
    }
}

__global__ void fill3(const int* __restrict__ u0, const int* __restrict__ v0,
                      const int* __restrict__ u1, const int* __restrict__ v1,
                      const int* __restrict__ u2, const int* __restrict__ v2,
                      int* __restrict__ cursor, int* __restrict__ usort)
{
    int t = blockIdx.x * blockDim.x + threadIdx.x;
    if (t >= 3 * NE) return;
    int et = t / NE, i = t - et * NE;
    const int* up = (et == 0) ? u0 : (et == 1) ? u1 : u2;
    const int* vp = (et == 0) ? v0 : (et == 1) ? v1 : v2;
    int pos = atomicAdd(&cursor[et * N_NODES + vp[i]], 1);
    usort[pos] = up[i];
}

// ============ fused edge softmax + gather + head-mean (bf16 F) ============
// 8-wide batches; ONE exp per lane per batch (edge lane&7, head lane>>3),
// weights broadcast across the head group via __shfl.

__device__ __forceinline__ float lrelu(float e) {
    return (e >= 0.f) ? e : NEG_SLOPE * e;
}

__device__ __forceinline__ float4 seg_accum(
    const float* __restrict__ el, float erh,
    const int* __restrict__ us, int lo, int hi,
    const unsigned short* __restrict__ Fs, int lane, int h)
{
    float4 aa = make_float4(0.f, 0.f, 0.f, 0.f);
    if (lo >= hi) return aa;
    const int q = lane & 7;
    const int lbase = lane & 56;   // h*8
    float s = 0.f;
    int j = lo;
    for (; j + 8 <= hi; j += 8) {
        int u[8];
#pragma unroll
        for (int qq = 0; qq < 8; qq++) u[qq] = us[j + qq];
        ushort4 fb[8];
#pragma unroll
        for (int qq = 0; qq < 8; qq++)
            fb[qq] = *(const ushort4*)(Fs + ((size_t)u[qq] << 8) + lane * 4);
        float myw = __expf(lrelu(el[u[q] * H + h] + erh));
#pragma unroll
        for (int qq = 0; qq < 8; qq++) {
            float w = __shfl(myw, lbase + qq, 64);
            s += w;
            aa.x = fmaf(w, bf2f(fb[qq].x), aa.x);
            aa.y = fmaf(w, bf2f(fb[qq].y), aa.y);
            aa.z = fmaf(w, bf2f(fb[qq].z), aa.z);
            aa.w = fmaf(w, bf2f(fb[qq].w), aa.w);
        }
    }
    if (j < hi) {   // one masked batch
        int rem = hi - j;
        int u[8];
#pragma unroll
        for (int qq = 0; qq < 8; qq++) u[qq] = us[(qq < rem) ? j + qq : hi - 1];
        ushort4 fb[8];
#pragma unroll
        for (int qq = 0; qq < 8; qq++)
            fb[qq] = *(const ushort4*)(Fs + ((size_t)u[qq] << 8) + lane * 4);
        float myw = (q < rem) ? __expf(lrelu(el[u[q] * H + h] + erh)) : 0.f;
#pragma unroll
        for (int qq = 0; qq < 8; qq++) {
            float w = __shfl(myw, lbase + qq, 64);   // lanes past rem hold 0
            s += w;
            aa.x = fmaf(w, bf2f(fb[qq].x), aa.x);
            aa.y = fmaf(w, bf2f(fb[qq].y), aa.y);
            aa.z = fmaf(w, bf2f(fb[qq].z), aa.z);
            aa.w = fmaf(w, bf2f(fb[qq].w), aa.w);
        }
    }
    float inv = (s > 0.f) ? 1.f / s : 0.f;
    aa.x *= inv; aa.y *= inv; aa.z *= inv; aa.w *= inv;
    return aa;
}

template <int RELU>
__global__ __launch_bounds__(256) void seg_att_all(
    const float* __restrict__ el0, const float* __restrict__ er0,
    const int* __restrict__ off0, const unsigned short* __restrict__ F0,
    const float* __restrict__ el1, const float* __restrict__ er1,
    const int* __restrict__ off1, const unsigned short* __restrict__ F1,
    const float* __restrict__ el2, const float* __restrict__ er2,
    const int* __restrict__ off2, const unsigned short* __restrict__ F2,
    const int* __restrict__ us, const float* __restrict__ bsB,
    const float* __restrict__ bsA, float* __restrict__ outB,
    float* __restrict__ outA, int N)
{
    int wid = blockIdx.x * 4 + (threadIdx.x >> 6);
    if (wid >= 2 * N) return;
    const int lane = threadIdx.x & 63;
    const int h = lane >> 3;
    float4 tot;
    const float* bs;
    float* out;
    int v;
    if (wid < N) {
        v = wid;
        tot = seg_accum(el0, er0[v * H + h], us, off0[v], off0[v + 1], F0, lane, h);
        bs = bsB; out = outB;
    } else {
        v = wid - N;
        float4 t1 = seg_accum(el1, er1[v * H + h], us, off1[v], off1[v + 1], F1, lane, h);
        float4 t2 = seg_accum(el2, er2[v * H + h], us, off2[v], off2[v + 1], F2, lane, h);
        tot.x = t1.x + t2.x; tot.y = t1.y + t2.y;
        tot.z = t1.z + t2.z; tot.w = t1.w + t2.w;
        bs = bsA; out = outA;
    }
#pragma unroll
    for (int mask = 8; mask <= 32; mask <<= 1) {
        tot.x += __shfl_xor(tot.x, mask, 64);
        tot.y += __shfl_xor(tot.y, mask, 64);
        tot.z += __shfl_xor(tot.z, mask, 64);
        tot.w += __shfl_xor(tot.w, mask, 64);
    }
    if (lane < 8) {
        float4 b = *(const float4*)(bs + lane * 4);
        float4 o;
        o.x = (tot.x + b.x) * 0.125f;
        o.y = (tot.y + b.y) * 0.125f;
        o.z = (tot.z + b.z) * 0.125f;
        o.w = (tot.w + b.w) * 0.125f;
        if (RELU) {
            o.x = fmaxf(o.x, 0.f); o.y = fmaxf(o.y, 0.f);
            o.z = fmaxf(o.z, 0.f); o.w = fmaxf(o.w, 0.f);
        }
        *(float4*)(out + (size_t)v * D + lane * 4) = o;
    }
}

// ================= host =================

extern "C" void kernel_launch(void* const* d_in, const int* in_sizes, int n_in,
                              void* d_out, int out_size, void* d_ws, size_t ws_size,
                              hipStream_t stream)
{
    const float* xA  = (const float*)d_in[0];
    const float* xB  = (const float*)d_in[1];
    const float* W1  = (const float*)d_in[2];   // [3][256][256]
    const float* al1 = (const float*)d_in[3];
    const float* ar1 = (const float*)d_in[4];
    const float* b1  = (const float*)d_in[5];
    const float* W2  = (const float*)d_in[6];   // [3][32][256]
    const float* al2 = (const float*)d_in[7];
    const float* ar2 = (const float*)d_in[8];
    const float* b2  = (const float*)d_in[9];
    const int* u0 = (const int*)d_in[10];
    const int* v0 = (const int*)d_in[11];
    const int* u1 = (const int*)d_in[12];
    const int* v1 = (const int*)d_in[13];
    const int* u2 = (const int*)d_in[14];
    const int* v2 = (const int*)d_in[15];
    float* out = (float*)d_out;

    const size_t FSZ = (size_t)N_NODES * HD;       // 5.12M elements
    unsigned short* xAb = (unsigned short*)d_ws;
    unsigned short* xBb = xAb + FSZ;
    unsigned short* Fb  = xBb + FSZ;               // [3][FSZ]
    unsigned short* F0b = Fb;
    unsigned short* F1b = Fb + FSZ;
    unsigned short* F2b = Fb + 2 * FSZ;
    unsigned short* W1b = Fb + 3 * FSZ;            // 196608
    float* el  = (float*)(W1b + 3 * 65536);        // [3][N*H]
    float* er  = el + 3 * N_NODES * H;
    float* hA  = er + 3 * N_NODES * H;             // [N][32]
    float* hB  = hA + (size_t)N_NODES * D;
    float* wlr = hB + (size_t)N_NODES * D;         // [6][2048] max
    float* bs  = wlr + 6 * 2048;                   // [4][32]
    int* off    = (int*)(bs + 128);                // 3N+1
    int* cursor = off + 3 * N_NODES + 1;
    int* cnt    = cursor + 3 * N_NODES;
    int* loc    = cnt + 3 * N_NODES;
    int* bsum   = loc + 3 * N_NODES;
    int* usort  = bsum + 128;                      // 3NE

    float* el0 = el, *el1 = el + N_NODES * H, *el2 = el + 2 * N_NODES * H;
    float* er0 = er, *er1 = er + N_NODES * H, *er2 = er + 2 * N_NODES * H;
    int* off0 = off, *off1 = off + N_NODES, *off2 = off + 2 * N_NODES;
    float* bsA1 = bs, *bsB1 = bs + 32, *bsA2 = bs + 64, *bsB2 = bs + 96;

    const dim3 GB_MM3(157, 4, 3);
    const dim3 GB_GV(N_NODES * H / 256, 2);        // 625 x 2
    const int GB_ALL = (2 * N_NODES + 3) / 4;      // 10000
    const int GB_3E  = (3 * NE + 255) / 256;
    const int CVT_N  = (2 * (int)FSZ + 3 * 65536) / 4;

    // ---- CSR build ----
    hipMemsetAsync(cnt, 0, SCAN_NT * sizeof(int), stream);
    hist3<<<GB_3E, 256, 0, stream>>>(v0, v1, v2, cnt);
    scan_blk<<<SCAN_NB, 512, 0, stream>>>(cnt, loc, bsum);
    scan_bsum<<<1, 128, 0, stream>>>(bsum, SCAN_NB);
    scan_add<<<SCAN_NB, 512, 0, stream>>>(loc, bsum, off, cursor);
    fill3<<<GB_3E, 256, 0, stream>>>(u0, v0, u1, v1, u2, v2, cursor, usort);

    bias_sums<<<1, 128, 0, stream>>>(b1, b2, bs);
    cvt_all<<<(CVT_N + 255) / 256, 256, 0, stream>>>(xA, xB, W1, xAb, xBb, W1b);

    // ---------------- layer 1 ----------------
    make_wlr3<<<48, 256, 0, stream>>>(W1, al1, ar1, wlr, 256, 65536);
    mfma_gemm3<<<GB_MM3, 256, 0, stream>>>(xAb, xBb, W1b, Fb, N_NODES);
    gemv6<256><<<GB_GV, 256, 0, stream>>>(xA, xB, wlr, el, er, N_NODES);
    seg_att_all<1><<<GB_ALL, 256, 0, stream>>>(el0, er0, off0, F0b,
                                               el1, er1, off1, F1b,
                                               el2, er2, off2, F2b,
                                               usort, bsB1, bsA1, hB, hA, N_NODES);

    // ---------------- layer 2 ----------------
    make_wlr3<<<6, 256, 0, stream>>>(W2, al2, ar2, wlr, 32, 8192);
    gemm32_3<<<GB_MM3, 256, 0, stream>>>(hA, hB, W2, Fb, N_NODES);
    gemv6<32><<<GB_GV, 256, 0, stream>>>(hA, hB, wlr, el, er, N_NODES);
    seg_att_all<0><<<GB_ALL, 256, 0, stream>>>(el0, er0, off0, F0b,
                                               el1, er1, off1, F1b,
                                               el2, er2, off2, F2b,
                                               usort, bsB2, bsA2,
                                               out + (size_t)N_NODES * D, out, N_NODES);
}